// Round 14
// baseline (2380.662 us; speedup 1.0000x reference)
//
#include <hip/hip_runtime.h>

// ---------------------------------------------------------------------------
// Autoformer forward, MI355X. Round 14: boundary-count reduction — top-k folded
// into hgemmAgg prologue (bit-identical), mc-clean folded into decompW, colsum
// parallelized (colpart 512 blocks). Numerics identical to round 13.
// GEMM numerics: C = Ah*Bh [+ Ah*Bl [+ Al*Bh]], operands rows x 2K f16 [hi|lo].
// ---------------------------------------------------------------------------

typedef _Float16 h8 __attribute__((ext_vector_type(8)));
typedef _Float16 h4 __attribute__((ext_vector_type(4)));
typedef float f32x4 __attribute__((ext_vector_type(4)));

struct P12 { const float* p[12]; };
struct P6  { const float* p[6]; };
struct P4  { const float* p[4]; };

__device__ __forceinline__ float gelu_f(float x){
    return 0.5f * x * (1.0f + erff(x * 0.70710678118654752f));
}

__device__ __forceinline__ void gl_lds(const _Float16* gp, _Float16* lp) {
    __builtin_amdgcn_global_load_lds(
        (const __attribute__((address_space(1))) void*)gp,
        (__attribute__((address_space(3))) void*)lp, 16, 0, 0);
}

// ------------------------------ MFMA GEMM ----------------------------------
// A: M x 2K [hi|lo] (lda halfs, lo at +loA). B: N x 2K (ldb, +loB).
// nph phases x (K/64): (Ah,Bh)[,(Ah,Bl)[,(Al,Bh)]]. f32 accum, *osc epilogue.
// OUT=0: f32 C. OUT=1: f16 cat C (loC<0 -> hi only); EPI 0 plain/1 +Rcat/2 gelu.
// OUT=2: diag reduce: atomicAdd mc[bz*sC + (row-col)&511].
template<int EPI, int OUT>
__global__ __launch_bounds__(256)
void hgemm_k(const _Float16* __restrict__ A, int lda, int loA,
             const _Float16* __restrict__ Bm, int ldb, int loB,
             const _Float16* __restrict__ Rc, void* __restrict__ Cv,
             int ldc, int loC, int K, int nph, float osc,
             long sA, long sB, long sC)
{
    __shared__ _Float16 As[128 * 64];
    __shared__ _Float16 Bs[128 * 64];
    const int bz = blockIdx.z;
    const int tid = threadIdx.x, lane = tid & 63, w = tid >> 6;
    const int wr = w >> 1, wc = w & 1;
    const _Float16* Ap = A + bz * sA + (long)(blockIdx.y * 128) * lda;
    const _Float16* Bp = Bm + bz * sB + (long)(blockIdx.x * 128) * ldb;

    const int swz = ((lane & 7) ^ ((lane >> 3) & 7)) * 8;
    const int rsub = w * 32 + (lane >> 3);
    const _Float16* ApT = Ap + (long)rsub * lda + swz;
    const _Float16* BpT = Bp + (long)rsub * ldb + swz;
    _Float16* AsT = As + w * 2048;
    _Float16* BsT = Bs + w * 2048;

    const int tpp = K >> 6;
    const int nkt = tpp * nph;
    f32x4 acc[4][4] = {};

    int p = 0, q = 0;
    for (int kt = 0; kt < nkt; ++kt) {
        const int aoff = q * 64 + (p == 2 ? loA : 0);
        const int boff = q * 64 + (p == 1 ? loB : 0);
        __syncthreads();
#pragma unroll
        for (int i = 0; i < 4; i++) {
            gl_lds(ApT + (long)i * 8 * lda + aoff, AsT + i * 512);
            gl_lds(BpT + (long)i * 8 * ldb + boff, BsT + i * 512);
        }
        __syncthreads();
#pragma unroll
        for (int kk = 0; kk < 2; ++kk) {
            h8 af[4], bf[4];
            const int ks = kk * 4 + (lane >> 4);
#pragma unroll
            for (int m = 0; m < 4; m++) {
                int rowa = wr * 64 + m * 16 + (lane & 15);
                af[m] = *(const h8*)(As + rowa * 64 + ((ks ^ (rowa & 7)) * 8));
                int rowb = wc * 64 + m * 16 + (lane & 15);
                bf[m] = *(const h8*)(Bs + rowb * 64 + ((ks ^ (rowb & 7)) * 8));
            }
#pragma unroll
            for (int m = 0; m < 4; m++)
#pragma unroll
                for (int n = 0; n < 4; n++)
                    acc[m][n] = __builtin_amdgcn_mfma_f32_16x16x32_f16(af[m], bf[n], acc[m][n], 0, 0, 0);
        }
        if (++q == tpp) { q = 0; ++p; }
    }

    const int crow0 = blockIdx.y * 128 + wr * 64 + (lane >> 4) * 4;
    const int ccol0 = blockIdx.x * 128 + wc * 64 + (lane & 15);
    if constexpr (OUT == 0) {
        float* Cp = (float*)Cv + (long)bz * sC;
#pragma unroll
        for (int m = 0; m < 4; m++)
#pragma unroll
            for (int n = 0; n < 4; n++) {
                int col = ccol0 + n * 16;
#pragma unroll
                for (int r2 = 0; r2 < 4; r2++) {
                    long idx = (long)(crow0 + m * 16 + r2) * ldc + col;
                    Cp[idx] = acc[m][n][r2] * osc;
                }
            }
    } else if constexpr (OUT == 1) {
        _Float16* Cp = (_Float16*)Cv + (long)bz * sC;
#pragma unroll
        for (int m = 0; m < 4; m++)
#pragma unroll
            for (int n = 0; n < 4; n++) {
                int col = ccol0 + n * 16;
#pragma unroll
                for (int r2 = 0; r2 < 4; r2++) {
                    int row = crow0 + m * 16 + r2;
                    long base = (long)row * ldc + col;
                    float v = acc[m][n][r2] * osc;
                    if (EPI == 1) {
                        long rb = (long)row * 1024 + col;
                        v += (float)Rc[rb] + (float)Rc[rb + 512];
                    }
                    if (EPI == 2) v = gelu_f(v);
                    _Float16 hi = (_Float16)v;
                    Cp[base] = hi;
                    if (loC >= 0) Cp[base + loC] = (_Float16)(v - (float)hi);
                }
            }
    } else {
        __shared__ float diag[512];
        float* mc = (float*)Cv + (long)bz * sC;
        for (int t = tid; t < 512; t += 256) diag[t] = 0.f;
        __syncthreads();
#pragma unroll
        for (int m = 0; m < 4; m++)
#pragma unroll
            for (int n = 0; n < 4; n++) {
                int col = ccol0 + n * 16;
#pragma unroll
                for (int r2 = 0; r2 < 4; r2++) {
                    int row = crow0 + m * 16 + r2;
                    atomicAdd(&diag[(row - col) & 511], acc[m][n][r2]);
                }
            }
        __syncthreads();
        for (int t = tid; t < 512; t += 256) {
            float v = diag[t];
            if (v != 0.f) atomicAdd(&mc[t], v);
        }
    }
}

// --------------- Wvo GEMM with fused top-k + agg gather --------------------
// Prologue: per-block top-6 + softmax from mc (bit-identical to old topk_k).
// A[row] = sum_k wv[k] * KVcat_hi[(l+dl[k])&511]; B = WvoC hi (nph=1).
// C cat = A@B*osc + Rc residual.
__global__ __launch_bounds__(256)
void hgemmAgg_k(const _Float16* __restrict__ KV, const float* __restrict__ mc,
                const _Float16* __restrict__ Bm,
                const _Float16* __restrict__ Rc, _Float16* __restrict__ Cp,
                float osc)
{
    __shared__ _Float16 As[128 * 64];
    __shared__ _Float16 Bs[128 * 64];
    const int tid = threadIdx.x, lane = tid & 63, w = tid >> 6;
    const int wr = w >> 1, wc = w & 1;
    const int rowblk = blockIdx.y * 128;
    const int b = rowblk >> 9;

    // ---- inline top-6 + softmax (same algorithm/order as topk_k) ----
    int dl[6]; float wv[6];
    {
        float* v  = (float*)As;              // 512 f32
        float* rv = (float*)As + 512;        // 256 f32
        int*   ri = (int*)Bs;                // 256 i32
        const float SCL = 1.f / (512.f * 4096.f);
        v[tid]       = mc[b * 512 + tid]       * SCL;
        v[tid + 256] = mc[b * 512 + tid + 256] * SCL;
        __syncthreads();
        float sv[6];
        for (int p = 0; p < 6; p++) {
            float bv = v[tid]; int bi = tid;
            float v2 = v[tid + 256];
            if (v2 > bv) { bv = v2; bi = tid + 256; }
            rv[tid] = bv; ri[tid] = bi;
            __syncthreads();
            for (int s = 128; s > 0; s >>= 1) {
                if (tid < s) {
                    float ov = rv[tid + s]; int oi = ri[tid + s];
                    if (ov > rv[tid] || (ov == rv[tid] && oi < ri[tid])) {
                        rv[tid] = ov; ri[tid] = oi;
                    }
                }
                __syncthreads();
            }
            sv[p] = rv[0]; dl[p] = ri[0];
            __syncthreads();
            if (tid == 0) v[ri[0]] = -3.4e38f;
            __syncthreads();
        }
        float mx = sv[0];
        for (int p = 1; p < 6; p++) mx = fmaxf(mx, sv[p]);
        float e[6], sum = 0.f;
        for (int p = 0; p < 6; p++) { e[p] = expf(sv[p] - mx); sum += e[p]; }
        for (int p = 0; p < 6; p++) wv[p] = e[p] / sum;
    }

    const _Float16* Bp = Bm + (long)(blockIdx.x * 128) * 1024;
    const int swz = ((lane & 7) ^ ((lane >> 3) & 7)) * 8;
    const int rsub = w * 32 + (lane >> 3);
    const _Float16* BpT = Bp + (long)rsub * 1024 + swz;
    _Float16* BsT = Bs + w * 2048;
    const _Float16* KVb = KV + ((long)b << 19);

    f32x4 acc[4][4] = {};
    for (int q = 0; q < 8; ++q) {
        const int coff = q * 64 + swz;
        __syncthreads();
#pragma unroll
        for (int i = 0; i < 4; i++) {
            int l = (rowblk + rsub + i * 8) & 511;
            float s8[8] = {};
#pragma unroll
            for (int k = 0; k < 6; k++) {
                const h8 v = *(const h8*)(KVb + ((long)((l + dl[k]) & 511) << 10) + coff);
#pragma unroll
                for (int j = 0; j < 8; j++) s8[j] = fmaf(wv[k], (float)v[j], s8[j]);
            }
            h8 hv;
#pragma unroll
            for (int j = 0; j < 8; j++) hv[j] = (_Float16)s8[j];
            *(h8*)(As + w * 2048 + i * 512 + lane * 8) = hv;
            gl_lds(BpT + (long)i * 8 * 1024 + q * 64, BsT + i * 512);
        }
        __syncthreads();
#pragma unroll
        for (int kk = 0; kk < 2; ++kk) {
            h8 af[4], bf[4];
            const int ks = kk * 4 + (lane >> 4);
#pragma unroll
            for (int m = 0; m < 4; m++) {
                int rowa = wr * 64 + m * 16 + (lane & 15);
                af[m] = *(const h8*)(As + rowa * 64 + ((ks ^ (rowa & 7)) * 8));
                int rowb = wc * 64 + m * 16 + (lane & 15);
                bf[m] = *(const h8*)(Bs + rowb * 64 + ((ks ^ (rowb & 7)) * 8));
            }
#pragma unroll
            for (int m = 0; m < 4; m++)
#pragma unroll
                for (int n = 0; n < 4; n++)
                    acc[m][n] = __builtin_amdgcn_mfma_f32_16x16x32_f16(af[m], bf[n], acc[m][n], 0, 0, 0);
        }
    }

    const int crow0 = rowblk + wr * 64 + (lane >> 4) * 4;
    const int ccol0 = blockIdx.x * 128 + wc * 64 + (lane & 15);
#pragma unroll
    for (int m = 0; m < 4; m++)
#pragma unroll
        for (int n = 0; n < 4; n++) {
            int col = ccol0 + n * 16;
#pragma unroll
            for (int r2 = 0; r2 < 4; r2++) {
                int row = crow0 + m * 16 + r2;
                long rb = (long)row * 1024 + col;
                float v = acc[m][n][r2] * osc + (float)Rc[rb] + (float)Rc[rb + 512];
                _Float16 hi = (_Float16)v;
                Cp[rb] = hi;
                Cp[rb + 512] = (_Float16)(v - (float)hi);
            }
        }
}

// ------------------------- weight conversion -------------------------------
__global__ __launch_bounds__(256)
void splitAll_k(P12 ps, _Float16* __restrict__ PA, _Float16* __restrict__ PB)
{
    const int m = blockIdx.y;
    const float* __restrict__ src = ps.p[m];
    _Float16* dst;
    if (m < 4)      dst = PA + (long)(2 * m) * 524288;
    else if (m < 8) dst = PB + (long)(2 * (m - 4)) * 524288;
    else            dst = PB + (long)(2 * (m - 8) + 1) * 524288;
    long t = (long)blockIdx.x * 256 + threadIdx.x;
    long row = t >> 6; int kc = (int)(t & 63) * 8;
    const float4 v0 = *(const float4*)(src + row * 512 + kc);
    const float4 v1 = *(const float4*)(src + row * 512 + kc + 4);
    float vv[8] = {v0.x,v0.y,v0.z,v0.w,v1.x,v1.y,v1.z,v1.w};
    h8 hi, lo;
#pragma unroll
    for (int j = 0; j < 8; j++) {
        float s = vv[j] * 64.f;
        _Float16 h = (_Float16)s;
        hi[j] = h; lo[j] = (_Float16)(s - (float)h);
    }
    *(h8*)(dst + row * 1024 + kc)       = hi;
    *(h8*)(dst + row * 1024 + 512 + kc) = lo;
}

__global__ __launch_bounds__(256)
void convWoAll_k(P4 ps, _Float16* __restrict__ PA)
{
    const int z = blockIdx.z;
    const float* __restrict__ src = ps.p[z];
    _Float16* dst = PA + (long)(2 * z + 1) * 524288;
    __shared__ float t[32][33];
    int k0 = blockIdx.x * 32, n0 = blockIdx.y * 32, tid = threadIdx.x;
#pragma unroll
    for (int i = 0; i < 4; i++) {
        int lin = tid + i * 256; int r = lin >> 5, c = lin & 31;
        t[r][c] = src[(long)(k0 + r) * 512 + n0 + c];
    }
    __syncthreads();
#pragma unroll
    for (int i = 0; i < 4; i++) {
        int lin = tid + i * 256; int n = lin >> 5, k = lin & 31;
        float v = t[k][n] * 64.f;
        _Float16 hi = (_Float16)v;
        long base = (long)(n0 + n) * 1024 + k0 + k;
        dst[base]       = hi;
        dst[base + 512] = (_Float16)(v - (float)hi);
    }
}

__global__ __launch_bounds__(256)
void convW2All_k(P6 ps, _Float16* __restrict__ encW1C, _Float16* __restrict__ encW2C,
                 _Float16* __restrict__ dW1C, _Float16* __restrict__ dW2C)
{
    const int z = blockIdx.z;
    const float* __restrict__ src = ps.p[z];
    _Float16* dst = (z==0) ? encW1C : (z==1) ? encW1C + 2097152 : (z==2) ? dW1C :
                    (z==3) ? encW2C : (z==4) ? encW2C + 2097152 : dW2C;
    const bool isW1 = z < 3;
    const int N = isW1 ? 2048 : 512;
    const int K = isW1 ? 512 : 2048;
    int k0 = (isW1 ? blockIdx.x : blockIdx.y) * 32;
    int n0 = (isW1 ? blockIdx.y : blockIdx.x) * 32;
    __shared__ float t[32][33];
    int tid = threadIdx.x;
#pragma unroll
    for (int i = 0; i < 4; i++) {
        int lin = tid + i * 256; int r = lin >> 5, c = lin & 31;
        t[r][c] = src[(long)(k0 + r) * N + n0 + c];
    }
    __syncthreads();
#pragma unroll
    for (int i = 0; i < 4; i++) {
        int lin = tid + i * 256; int n = lin >> 5, k = lin & 31;
        float v = t[k][n];
        _Float16 hi = (_Float16)v;
        long base = (long)(n0 + n) * 2 * K + k0 + k;
        dst[base]     = hi;
        dst[base + K] = (_Float16)(v - (float)hi);
    }
}

__global__ void convW63_k(const float* __restrict__ W, _Float16* __restrict__ dst)
{
    int i = blockIdx.x * 256 + threadIdx.x;
    int k = i & 511, j = i >> 9;
    float v = (j < 63) ? 64.f * W[(long)(j / 21) * 10752 + (long)k * 21 + (j % 21)] : 0.f;
    _Float16 hi = (_Float16)v;
    dst[(long)j * 1024 + k]       = hi;
    dst[(long)j * 1024 + 512 + k] = (_Float16)(v - (float)hi);
}

// ------------------------- embedding (cat-only out) ------------------------
__global__ __launch_bounds__(256)
void embed_k(const float* __restrict__ x, const float* __restrict__ mark,
             const float* __restrict__ valW, const float* __restrict__ timeW,
             _Float16* __restrict__ cat)
{
    const int lg = blockIdx.x, dh = blockIdx.y, b = blockIdx.z;
    const int tid = threadIdx.x;
    const int dd = dh * 256 + tid;
    const int l0 = lg * 8;
    __shared__ float xs[10][21];
    __shared__ float mk[8][4];
    if (tid < 210) {
        int r = tid / 21, c = tid % 21;
        int ll = (l0 - 1 + r + 512) & 511;
        xs[r][c] = x[((long)b * 512 + ll) * 21 + c];
    }
    if (tid >= 224 && tid < 256) {
        int t2 = tid - 224, il = t2 >> 2, m = t2 & 3;
        mk[il][m] = mark[((long)b * 512 + l0 + il) * 4 + m];
    }
    __syncthreads();
    float acc[8];
#pragma unroll
    for (int il = 0; il < 8; il++) acc[il] = 0.f;
    for (int t = 0; t < 3; t++)
        for (int c = 0; c < 21; c++) {
            float w = valW[(t * 21 + c) * 512 + dd];
#pragma unroll
            for (int il = 0; il < 8; il++)
                acc[il] = fmaf(xs[il + t][c], w, acc[il]);
        }
    for (int m = 0; m < 4; m++) {
        float w = timeW[m * 512 + dd];
#pragma unroll
        for (int il = 0; il < 8; il++)
            acc[il] = fmaf(mk[il][m], w, acc[il]);
    }
    const float freq = expf((float)(dd & ~1) * (-9.210340371976184f / 512.0f));
#pragma unroll
    for (int il = 0; il < 8; il++) {
        float ang = (float)(l0 + il) * freq;
        float pe = (dd & 1) ? cosf(ang) : sinf(ang);
        float v = acc[il] + pe;
        long row = (long)b * 512 + l0 + il;
        _Float16 hi = (_Float16)v;
        cat[row * 1024 + dd]       = hi;
        cat[row * 1024 + 512 + dd] = (_Float16)(v - (float)hi);
    }
}

// ------------------- windowed decomp (cat in, cat out) + mc-clean ----------
template<int TREND>
__global__ __launch_bounds__(256)
void decompW_k(const _Float16* __restrict__ xc, _Float16* __restrict__ outc,
               _Float16* __restrict__ tsc, float* __restrict__ mcz, int nMc)
{
    long t = (long)blockIdx.x * 256 + threadIdx.x;
    if (t < nMc) mcz[t] = 0.f;          // clean mc for the next Scorr
    long rowg = t >> 7; int d4 = (int)(t & 127) * 4;
    int lg = (int)(rowg & 63); long b = rowg >> 6;
    const int l0 = lg * 8;
    const _Float16* xb = xc + (b << 19);
    float s[8][4] = {};
    float xo[8][4];
#pragma unroll
    for (int rr = -12; rr <= 19; rr++) {
        int rc = l0 + rr; rc = rc < 0 ? 0 : (rc > 511 ? 511 : rc);
        h4 vh = *(const h4*)(xb + ((long)rc << 10) + d4);
        h4 vl = *(const h4*)(xb + ((long)rc << 10) + 512 + d4);
        float vv[4];
#pragma unroll
        for (int j = 0; j < 4; j++) vv[j] = (float)vh[j] + (float)vl[j];
#pragma unroll
        for (int i = 0; i < 8; i++) {
            if (i >= rr - 12 && i <= rr + 12) {
#pragma unroll
                for (int j = 0; j < 4; j++) s[i][j] += vv[j];
            }
        }
        if (rr >= 0 && rr < 8) {
#pragma unroll
            for (int j = 0; j < 4; j++) xo[rr][j] = vv[j];
        }
    }
#pragma unroll
    for (int i = 0; i < 8; i++) {
        long row = b * 512 + l0 + i;
        float tr[4], ov[4];
#pragma unroll
        for (int j = 0; j < 4; j++) {
            tr[j] = s[i][j] * (1.f / 25.f);
            ov[j] = xo[i][j] - tr[j];
        }
        h4 hi, lo;
#pragma unroll
        for (int j = 0; j < 4; j++) {
            _Float16 h = (_Float16)ov[j];
            hi[j] = h; lo[j] = (_Float16)(ov[j] - (float)h);
        }
        *(h4*)(outc + row * 1024 + d4)       = hi;
        *(h4*)(outc + row * 1024 + 512 + d4) = lo;
        if (TREND) {
            _Float16* tp = tsc + row * 1024 + d4;
            if (TREND == 1) {
                h4 th = *(h4*)tp, tl = *(h4*)(tp + 512);
#pragma unroll
                for (int j = 0; j < 4; j++) tr[j] += (float)th[j] + (float)tl[j];
            }
            h4 th2, tl2;
#pragma unroll
            for (int j = 0; j < 4; j++) {
                _Float16 h = (_Float16)tr[j];
                th2[j] = h; tl2[j] = (_Float16)(tr[j] - (float)h);
            }
            *(h4*)tp         = th2;
            *(h4*)(tp + 512) = tl2;
        }
    }
}

// ------------------------- prep (mean + zero mc) ---------------------------
__global__ __launch_bounds__(512)
void meanseq2_k(const float* __restrict__ x, float* __restrict__ xm,
                float* __restrict__ mcz)
{
    int b = blockIdx.x, tid = threadIdx.x;
    mcz[b * 512 + tid] = 0.f;
    __shared__ float sd[504];
    if (tid < 504) {
        int c = tid % 21, g = tid / 21;
        int l0 = g * 22, l1 = l0 + 22 > 512 ? 512 : l0 + 22;
        const float* xb = x + (long)b * 10752;
        float s = 0.f;
        for (int l = l0; l < l1; l++) s += xb[l * 21 + c];
        sd[tid] = s;
    }
    __syncthreads();
    if (tid < 21) {
        float t = 0.f;
#pragma unroll
        for (int g = 0; g < 24; g++) t += sd[g * 21 + tid];
        xm[b * 21 + tid] = t * (1.f / 512.f);
    }
}

__global__ void prep_k(const float* __restrict__ x, const float* __restrict__ xm,
                       float* __restrict__ sinit, float* __restrict__ tinit, int total)
{
    int i = blockIdx.x * 256 + threadIdx.x;
    if (i >= total) return;
    int c = i % 21, l = (i / 21) % 512, b = i / 10752;
    if (l < 256) {
        int lc = 256 + l;
        float s = 0.f;
        for (int j = -12; j <= 12; j++) {
            int ll = lc + j; ll = ll > 511 ? 511 : ll;
            s += x[((long)b * 512 + ll) * 21 + c];
        }
        float t = s * (1.f / 25.f);
        tinit[i] = t;
        sinit[i] = x[((long)b * 512 + lc) * 21 + c] - t;
    } else {
        sinit[i] = 0.f;
        tinit[i] = xm[b * 21 + c];
    }
}

// ------------------------- seasonal layernorm (cat in, f32 out) ------------
__global__ __launch_bounds__(256)
void ln_k(const _Float16* __restrict__ xc, const float* __restrict__ g,
          const float* __restrict__ be, float* __restrict__ out)
{
    int row = blockIdx.x, tid = threadIdx.x;
    const _Float16* xr = xc + ((long)row << 10);
    float v0 = (float)xr[tid]       + (float)xr[tid + 512];
    float v1 = (float)xr[tid + 256] + (float)xr[tid + 768];
    __shared__ float rs[256];
    rs[tid] = v0 + v1; __syncthreads();
    for (int s = 128; s > 0; s >>= 1) { if (tid < s) rs[tid] += rs[tid + s]; __syncthreads(); }
    float mu = rs[0] * (1.f / 512.f);
    __syncthreads();
    float d0 = v0 - mu, d1 = v1 - mu;
    rs[tid] = d0 * d0 + d1 * d1; __syncthreads();
    for (int s = 128; s > 0; s >>= 1) { if (tid < s) rs[tid] += rs[tid + s]; __syncthreads(); }
    float rstd = 1.0f / sqrtf(rs[0] * (1.f / 512.f) + 1e-5f);
    out[((long)row << 9) + tid]       = d0 * rstd * g[tid] + be[tid];
    out[((long)row << 9) + tid + 256] = d1 * rstd * g[tid + 256] + be[tid + 256];
}

// per-(b, 64-row chunk, d) partial column sums. grid (2, 8, Bc)
__global__ void colpart_k(const float* __restrict__ x, float* __restrict__ cp)
{
    int d = blockIdx.x * 256 + threadIdx.x;
    int ch = blockIdx.y, b = blockIdx.z;
    const float* xb = x + ((long)b << 18);
    float s = 0.f;
    for (int l = ch * 64; l < ch * 64 + 64; l++) s += xb[((long)l << 9) + d];
    cp[((long)(b * 8 + ch) << 9) + d] = s;
}

// write hi/lo cat of (x - colmean) — encoder tail; reads 8 partials
__global__ __launch_bounds__(256)
void subcolcat_k(const float* __restrict__ x, const float* __restrict__ cp,
                 _Float16* __restrict__ cat)
{
    long t = (long)blockIdx.x * 256 + threadIdx.x;
    long row = t >> 6; int d8 = (int)(t & 63) * 8;
    int b = (int)(row >> 9);
    float m[8] = {};
#pragma unroll
    for (int ch = 0; ch < 8; ch++) {
        const float4* c4 = (const float4*)(cp + ((long)(b * 8 + ch) << 9) + d8);
        float4 c0 = c4[0], c1 = c4[1];
        m[0]+=c0.x; m[1]+=c0.y; m[2]+=c0.z; m[3]+=c0.w;
        m[4]+=c1.x; m[5]+=c1.y; m[6]+=c1.z; m[7]+=c1.w;
    }
    const float4* xp = (const float4*)(x + row * 512 + d8);
    float4 x0 = xp[0], x1 = xp[1];
    float v[8] = {x0.x,x0.y,x0.z,x0.w,x1.x,x1.y,x1.z,x1.w};
    h8 hi, lo;
#pragma unroll
    for (int j = 0; j < 8; j++) {
        float vv = v[j] - m[j] * (1.f / 512.f);
        _Float16 h = (_Float16)vv;
        hi[j] = h; lo[j] = (_Float16)(vv - (float)h);
    }
    *(h8*)(cat + row * 1024 + d8)       = hi;
    *(h8*)(cat + row * 1024 + 512 + d8) = lo;
}

// proj with fused colmean subtract (8 partials) + trend shift-add
__global__ void proj_k(const float* __restrict__ x, const float* __restrict__ cp,
                       const float* __restrict__ pw, const float* __restrict__ pb,
                       const float* __restrict__ tinit, const float* __restrict__ H,
                       float* __restrict__ out, int total)
{
    int i = blockIdx.x * 256 + threadIdx.x;
    if (i >= total) return;
    int c = i % 21, l = (i / 21) % 256 + 256, b = i / 5376;
    const float* xr = x + ((long)(b * 512 + l) << 9);
    float s = 0.f;
    for (int d = 0; d < 512; d++) {
        float m = 0.f;
#pragma unroll
        for (int ch = 0; ch < 8; ch++) m += cp[((long)(b * 8 + ch) << 9) + d];
        s = fmaf(xr[d] - m * (1.f / 512.f), pw[d * 21 + c], s);
    }
    long r = (long)b * 512;
    float trend = tinit[b * 10752 + l * 21 + c]
                + H[(r + ((l + 511) & 511)) * 128 + c]
                + H[(r + l) * 128 + 21 + c]
                + H[(r + ((l + 1) & 511)) * 128 + 42 + c];
    out[i] = s + pb[c] + trend;
}

// ---------------------------------------------------------------------------
// mode: 0 OUT1 plain-cat, 2 OUT1 gelu, 12 OUT1 +Rcat, 11 OUT0 f32, 20 Scorr
static void hgemm(int mode, int nph, float osc,
                  const _Float16* A, int lda, int loA,
                  const _Float16* B, int ldb, int loB,
                  const _Float16* Rc, void* C, int ldc, int loC,
                  int K, int M, int N, int batch,
                  long sA, long sB, long sC, hipStream_t st)
{
    dim3 g(N / 128, M / 128, batch), blk(256);
    switch (mode) {
    case 0:  hgemm_k<0,1><<<g,blk,0,st>>>(A,lda,loA,B,ldb,loB,Rc,C,ldc,loC,K,nph,osc,sA,sB,sC); break;
    case 2:  hgemm_k<2,1><<<g,blk,0,st>>>(A,lda,loA,B,ldb,loB,Rc,C,ldc,loC,K,nph,osc,sA,sB,sC); break;
    case 12: hgemm_k<1,1><<<g,blk,0,st>>>(A,lda,loA,B,ldb,loB,Rc,C,ldc,loC,K,nph,osc,sA,sB,sC); break;
    case 11: hgemm_k<0,0><<<g,blk,0,st>>>(A,lda,loA,B,ldb,loB,Rc,C,ldc,loC,K,nph,osc,sA,sB,sC); break;
    default: hgemm_k<0,2><<<g,blk,0,st>>>(A,lda,loA,B,ldb,loB,Rc,C,ldc,loC,K,nph,osc,sA,sB,sC); break;
    }
}

extern "C" void kernel_launch(void* const* d_in, const int* in_sizes, int n_in,
                              void* d_out, int out_size, void* d_ws, size_t ws_size,
                              hipStream_t stream)
{
    const float* x_enc    = (const float*)d_in[0];
    const float* xm_enc   = (const float*)d_in[1];
    const float* xm_dec   = (const float*)d_in[3];
    const float* enc_valW = (const float*)d_in[4];
    const float* enc_timeW= (const float*)d_in[5];
    const float* enc_Wq   = (const float*)d_in[6];
    const float* enc_Wk   = (const float*)d_in[7];
    const float* enc_Wv   = (const float*)d_in[8];
    const float* enc_Wo   = (const float*)d_in[9];
    const float* enc_W1   = (const float*)d_in[10];
    const float* enc_W2   = (const float*)d_in[11];
    const float* enc_g    = (const float*)d_in[12];
    const float* enc_b    = (const float*)d_in[13];
    const float* dec_valW = (const float*)d_in[14];
    const float* dec_timeW= (const float*)d_in[15];
    const float* sWq = (const float*)d_in[16];
    const float* sWk = (const float*)d_in[17];
    const float* sWv = (const float*)d_in[18];
    const float* sWo = (const float*)d_in[19];
    const float* cWq = (const float*)d_in[20];
    const float* cWk = (const float*)d_in[21];
    const float* cWv = (const float*)d_in[22];
    const float* cWo = (const float*)d_in[23];
    const float* dW1 = (const float*)d_in[24];
    const float* dW2 = (const float*)d_in[25];
    const float* dtW = (const float*)d_in[26];
    const float* dec_g = (const float*)d_in[27];
    const float* dec_b = (const float*)d_in[28];
    const float* projW = (const float*)d_in[29];
    const float* projB = (const float*)d_in[30];

    // ---- batch-chunk sizing (deterministic) ----
    const size_t W_BYTES = 50000000;
    const size_t perB = 8000000;
    int Bc = 32;
    while (Bc > 1 && W_BYTES + (size_t)Bc * perB + (4u << 20) > ws_size) Bc >>= 1;

    char* wp = (char*)d_ws;
    auto alloc = [&](size_t bytes) { char* p = wp; wp += (bytes + 255) & ~(size_t)255; return p; };

    _Float16* Wcat8  = (_Float16*)alloc(8 * 524288 * 2);
    _Float16* encW1C = (_Float16*)alloc(2 * 2097152 * 2);
    _Float16* encW2C = (_Float16*)alloc(2 * 2097152 * 2);
    _Float16* dW1C   = (_Float16*)alloc(2097152 * 2);
    _Float16* dW2C   = (_Float16*)alloc(2097152 * 2);
    _Float16* W63C   = (_Float16*)alloc(131072 * 2);
    _Float16* PA     = (_Float16*)alloc(8 * 524288 * 2);
    _Float16* PB     = (_Float16*)alloc(8 * 524288 * 2);

    const long ROWS = (long)Bc * 512;
    _Float16* cX     = (_Float16*)alloc(ROWS * 1024 * 2);
    _Float16* cO     = (_Float16*)alloc(ROWS * 1024 * 2);
    _Float16* TSc    = (_Float16*)alloc(ROWS * 1024 * 2);
    _Float16* ENCcat = (_Float16*)alloc(ROWS * 1024 * 2);
    _Float16* bigcat = (_Float16*)alloc(ROWS * 2048 * 2);
    float* F       = (float*)alloc(ROWS * 512 * 4);
    float* H       = (float*)alloc(ROWS * 128 * 4);
    float* sinit   = (float*)alloc((long)Bc * 10752 * 4);
    float* tinit   = (float*)alloc((long)Bc * 10752 * 4);
    float* xmean   = (float*)alloc((long)Bc * 21 * 4);
    float* mc      = (float*)alloc((long)Bc * 512 * 4);
    float* cp      = (float*)alloc((long)Bc * 4096 * 4);

    // ---- weight setup ----
    dim3 cb(256);
    P12 sp;
    sp.p[0] = enc_Wk;  sp.p[1] = enc_Wk + 262144;
    sp.p[2] = sWk;     sp.p[3] = cWk;
    sp.p[4] = enc_Wq;  sp.p[5] = enc_Wq + 262144;
    sp.p[6] = sWq;     sp.p[7] = cWq;
    sp.p[8] = enc_Wv;  sp.p[9] = enc_Wv + 262144;
    sp.p[10] = sWv;    sp.p[11] = cWv;
    P4 op;
    op.p[0] = enc_Wo;  op.p[1] = enc_Wo + 262144;
    op.p[2] = sWo;     op.p[3] = cWo;
    P6 fp;
    fp.p[0] = enc_W1;  fp.p[1] = enc_W1 + 1048576; fp.p[2] = dW1;
    fp.p[3] = enc_W2;  fp.p[4] = enc_W2 + 1048576; fp.p[5] = dW2;
    splitAll_k <<<dim3(128,12), cb, 0, stream>>>(sp, PA, PB);
    convWoAll_k<<<dim3(16,16,4), cb, 0, stream>>>(op, PA);
    hgemm(0, 3, 1.f, PA,1024,512, PB,1024,512, nullptr, Wcat8, 1024, 512,
          512, 512, 512, 8, 524288, 524288, 524288, stream);
    convW2All_k<<<dim3(16,64,6), cb, 0, stream>>>(fp, encW1C, encW2C, dW1C, dW2C);
    convW63_k  <<<256, cb, 0, stream>>>(dtW, W63C);

    const int M = (int)ROWS;
    const int t21 = Bc * 10752;
    const int gRows = Bc * 128;
    const int gW = Bc * 32;
    const int nMc = Bc * 512;
    const long sCA = 512 * 1024;
    const float IOS = 1.f / 4096.f;

    // attention: cOut = cIn + agg(KVcat)@Wvo (top-k + agg fused in GEMM)
    auto attn = [&](const _Float16* cIn, _Float16* cOut,
                    const _Float16* KVcat, int slot) {
        const _Float16* WqkC_ = Wcat8 + (long)(2*slot)     * 524288;
        const _Float16* WvoC_ = Wcat8 + (long)(2*slot + 1) * 524288;
        hgemm(0, 3, 1.f, cIn,1024,512, WqkC_,1024,512, nullptr, bigcat, 1024, 512,
              512, M, 512, 1, 0,0,0, stream);                              // T cat
        hgemm(20, 3, 1.f, bigcat,1024,512, KVcat,1024,512, nullptr, mc, 0, 0,
              512, 512, 512, Bc, sCA, sCA, 512, stream);                   // diag(T KV^T)
        hgemmAgg_k<<<dim3(4, M/128), 256, 0, stream>>>(KVcat, mc, WvoC_, cIn, cOut, IOS);
    };
    auto ffn = [&](const _Float16* cIn, _Float16* cOut,
                   const _Float16* W1C, const _Float16* W2C) {
        hgemm(2, 1, 1.f, cIn,1024,512, W1C,1024,512, nullptr, bigcat, 2048, -1,
              512, M, 2048, 1, 0,0,0, stream);
        hgemm(12, 1, 1.f, bigcat,2048,0, W2C,4096,2048, cIn, cOut, 1024, 512,
              2048, M, 512, 1, 0,0,0, stream);
    };

    for (int b0 = 0; b0 < 32; b0 += Bc) {
        const float* xe  = x_enc  + (long)b0 * 10752;
        const float* mke = xm_enc + (long)b0 * 2048;
        const float* mkd = xm_dec + (long)b0 * 2048;
        float* outp = (float*)d_out + (long)b0 * 5376;

        meanseq2_k<<<Bc, 512, 0, stream>>>(xe, xmean, mc);
        prep_k    <<<(t21 + 255)/256, 256, 0, stream>>>(xe, xmean, sinit, tinit, t21);

        // ---------------- encoder ----------------
        embed_k<<<dim3(64,2,Bc), 256, 0, stream>>>(xe, mke, enc_valW, enc_timeW, cX);
        for (int L = 0; L < 2; L++) {
            attn(cX, cO, cX, L);
            decompW_k<0><<<gW, 256, 0, stream>>>(cO, cX, nullptr, mc, nMc);
            ffn(cX, cO, encW1C + (long)L*2097152, encW2C + (long)L*2097152);
            decompW_k<0><<<gW, 256, 0, stream>>>(cO, cX, nullptr, mc, nMc);
        }
        ln_k       <<<Bc*512, 256, 0, stream>>>(cX, enc_g, enc_b, F);
        colpart_k  <<<dim3(2,8,Bc), 256, 0, stream>>>(F, cp);
        subcolcat_k<<<gRows, 256, 0, stream>>>(F, cp, ENCcat);

        // ---------------- decoder ----------------
        embed_k<<<dim3(64,2,Bc), 256, 0, stream>>>(sinit, mkd, dec_valW, dec_timeW, cX);

        attn(cX, cO, cX, 2);                                         // self
        decompW_k<2><<<gW, 256, 0, stream>>>(cO, cX, TSc, mc, nMc);  // TSc = trend
        attn(cX, cO, ENCcat, 3);                                     // cross
        decompW_k<1><<<gW, 256, 0, stream>>>(cO, cX, TSc, mc, nMc);  // TSc += trend
        ffn(cX, cO, dW1C, dW2C);
        decompW_k<1><<<gW, 256, 0, stream>>>(cO, cX, TSc, mc, nMc);

        hgemm(11, 1, 1.f/64.f, TSc,1024,512, W63C,1024,512, nullptr, H, 128, 0,
              512, M, 128, 1, 0,0,0, stream);
        ln_k     <<<Bc*512, 256, 0, stream>>>(cX, dec_g, dec_b, F);
        colpart_k<<<dim3(2,8,Bc), 256, 0, stream>>>(F, cp);
        proj_k   <<<(Bc*5376+255)/256, 256, 0, stream>>>(F, cp, projW, projB,
                                                         tinit, H, outp, Bc*5376);
    }
}

// Round 15
// 2161.554 us; speedup vs baseline: 1.1014x; 1.1014x over previous
//
#include <hip/hip_runtime.h>

// ---------------------------------------------------------------------------
// Autoformer forward, MI355X. Round 15: revert proj/subcolcat to cs-read form
// (round-14 regression fix); keep fused top-k + mc-clean + parallel colpart.
// GEMM numerics: C = Ah*Bh [+ Ah*Bl [+ Al*Bh]], operands rows x 2K f16 [hi|lo].
// ---------------------------------------------------------------------------

typedef _Float16 h8 __attribute__((ext_vector_type(8)));
typedef _Float16 h4 __attribute__((ext_vector_type(4)));
typedef float f32x4 __attribute__((ext_vector_type(4)));

struct P12 { const float* p[12]; };
struct P6  { const float* p[6]; };
struct P4  { const float* p[4]; };

__device__ __forceinline__ float gelu_f(float x){
    return 0.5f * x * (1.0f + erff(x * 0.70710678118654752f));
}

__device__ __forceinline__ void gl_lds(const _Float16* gp, _Float16* lp) {
    __builtin_amdgcn_global_load_lds(
        (const __attribute__((address_space(1))) void*)gp,
        (__attribute__((address_space(3))) void*)lp, 16, 0, 0);
}

// ------------------------------ MFMA GEMM ----------------------------------
// A: M x 2K [hi|lo] (lda halfs, lo at +loA). B: N x 2K (ldb, +loB).
// nph phases x (K/64): (Ah,Bh)[,(Ah,Bl)[,(Al,Bh)]]. f32 accum, *osc epilogue.
// OUT=0: f32 C. OUT=1: f16 cat C (loC<0 -> hi only); EPI 0 plain/1 +Rcat/2 gelu.
// OUT=2: diag reduce: atomicAdd mc[bz*sC + (row-col)&511].
template<int EPI, int OUT>
__global__ __launch_bounds__(256)
void hgemm_k(const _Float16* __restrict__ A, int lda, int loA,
             const _Float16* __restrict__ Bm, int ldb, int loB,
             const _Float16* __restrict__ Rc, void* __restrict__ Cv,
             int ldc, int loC, int K, int nph, float osc,
             long sA, long sB, long sC)
{
    __shared__ _Float16 As[128 * 64];
    __shared__ _Float16 Bs[128 * 64];
    const int bz = blockIdx.z;
    const int tid = threadIdx.x, lane = tid & 63, w = tid >> 6;
    const int wr = w >> 1, wc = w & 1;
    const _Float16* Ap = A + bz * sA + (long)(blockIdx.y * 128) * lda;
    const _Float16* Bp = Bm + bz * sB + (long)(blockIdx.x * 128) * ldb;

    const int swz = ((lane & 7) ^ ((lane >> 3) & 7)) * 8;
    const int rsub = w * 32 + (lane >> 3);
    const _Float16* ApT = Ap + (long)rsub * lda + swz;
    const _Float16* BpT = Bp + (long)rsub * ldb + swz;
    _Float16* AsT = As + w * 2048;
    _Float16* BsT = Bs + w * 2048;

    const int tpp = K >> 6;
    const int nkt = tpp * nph;
    f32x4 acc[4][4] = {};

    int p = 0, q = 0;
    for (int kt = 0; kt < nkt; ++kt) {
        const int aoff = q * 64 + (p == 2 ? loA : 0);
        const int boff = q * 64 + (p == 1 ? loB : 0);
        __syncthreads();
#pragma unroll
        for (int i = 0; i < 4; i++) {
            gl_lds(ApT + (long)i * 8 * lda + aoff, AsT + i * 512);
            gl_lds(BpT + (long)i * 8 * ldb + boff, BsT + i * 512);
        }
        __syncthreads();
#pragma unroll
        for (int kk = 0; kk < 2; ++kk) {
            h8 af[4], bf[4];
            const int ks = kk * 4 + (lane >> 4);
#pragma unroll
            for (int m = 0; m < 4; m++) {
                int rowa = wr * 64 + m * 16 + (lane & 15);
                af[m] = *(const h8*)(As + rowa * 64 + ((ks ^ (rowa & 7)) * 8));
                int rowb = wc * 64 + m * 16 + (lane & 15);
                bf[m] = *(const h8*)(Bs + rowb * 64 + ((ks ^ (rowb & 7)) * 8));
            }
#pragma unroll
            for (int m = 0; m < 4; m++)
#pragma unroll
                for (int n = 0; n < 4; n++)
                    acc[m][n] = __builtin_amdgcn_mfma_f32_16x16x32_f16(af[m], bf[n], acc[m][n], 0, 0, 0);
        }
        if (++q == tpp) { q = 0; ++p; }
    }

    const int crow0 = blockIdx.y * 128 + wr * 64 + (lane >> 4) * 4;
    const int ccol0 = blockIdx.x * 128 + wc * 64 + (lane & 15);
    if constexpr (OUT == 0) {
        float* Cp = (float*)Cv + (long)bz * sC;
#pragma unroll
        for (int m = 0; m < 4; m++)
#pragma unroll
            for (int n = 0; n < 4; n++) {
                int col = ccol0 + n * 16;
#pragma unroll
                for (int r2 = 0; r2 < 4; r2++) {
                    long idx = (long)(crow0 + m * 16 + r2) * ldc + col;
                    Cp[idx] = acc[m][n][r2] * osc;
                }
            }
    } else if constexpr (OUT == 1) {
        _Float16* Cp = (_Float16*)Cv + (long)bz * sC;
#pragma unroll
        for (int m = 0; m < 4; m++)
#pragma unroll
            for (int n = 0; n < 4; n++) {
                int col = ccol0 + n * 16;
#pragma unroll
                for (int r2 = 0; r2 < 4; r2++) {
                    int row = crow0 + m * 16 + r2;
                    long base = (long)row * ldc + col;
                    float v = acc[m][n][r2] * osc;
                    if (EPI == 1) {
                        long rb = (long)row * 1024 + col;
                        v += (float)Rc[rb] + (float)Rc[rb + 512];
                    }
                    if (EPI == 2) v = gelu_f(v);
                    _Float16 hi = (_Float16)v;
                    Cp[base] = hi;
                    if (loC >= 0) Cp[base + loC] = (_Float16)(v - (float)hi);
                }
            }
    } else {
        __shared__ float diag[512];
        float* mc = (float*)Cv + (long)bz * sC;
        for (int t = tid; t < 512; t += 256) diag[t] = 0.f;
        __syncthreads();
#pragma unroll
        for (int m = 0; m < 4; m++)
#pragma unroll
            for (int n = 0; n < 4; n++) {
                int col = ccol0 + n * 16;
#pragma unroll
                for (int r2 = 0; r2 < 4; r2++) {
                    int row = crow0 + m * 16 + r2;
                    atomicAdd(&diag[(row - col) & 511], acc[m][n][r2]);
                }
            }
        __syncthreads();
        for (int t = tid; t < 512; t += 256) {
            float v = diag[t];
            if (v != 0.f) atomicAdd(&mc[t], v);
        }
    }
}

// --------------- Wvo GEMM with fused top-k + agg gather --------------------
__global__ __launch_bounds__(256)
void hgemmAgg_k(const _Float16* __restrict__ KV, const float* __restrict__ mc,
                const _Float16* __restrict__ Bm,
                const _Float16* __restrict__ Rc, _Float16* __restrict__ Cp,
                float osc)
{
    __shared__ _Float16 As[128 * 64];
    __shared__ _Float16 Bs[128 * 64];
    const int tid = threadIdx.x, lane = tid & 63, w = tid >> 6;
    const int wr = w >> 1, wc = w & 1;
    const int rowblk = blockIdx.y * 128;
    const int b = rowblk >> 9;

    int dl[6]; float wv[6];
    {
        float* v  = (float*)As;
        float* rv = (float*)As + 512;
        int*   ri = (int*)Bs;
        const float SCL = 1.f / (512.f * 4096.f);
        v[tid]       = mc[b * 512 + tid]       * SCL;
        v[tid + 256] = mc[b * 512 + tid + 256] * SCL;
        __syncthreads();
        float sv[6];
        for (int p = 0; p < 6; p++) {
            float bv = v[tid]; int bi = tid;
            float v2 = v[tid + 256];
            if (v2 > bv) { bv = v2; bi = tid + 256; }
            rv[tid] = bv; ri[tid] = bi;
            __syncthreads();
            for (int s = 128; s > 0; s >>= 1) {
                if (tid < s) {
                    float ov = rv[tid + s]; int oi = ri[tid + s];
                    if (ov > rv[tid] || (ov == rv[tid] && oi < ri[tid])) {
                        rv[tid] = ov; ri[tid] = oi;
                    }
                }
                __syncthreads();
            }
            sv[p] = rv[0]; dl[p] = ri[0];
            __syncthreads();
            if (tid == 0) v[ri[0]] = -3.4e38f;
            __syncthreads();
        }
        float mx = sv[0];
        for (int p = 1; p < 6; p++) mx = fmaxf(mx, sv[p]);
        float e[6], sum = 0.f;
        for (int p = 0; p < 6; p++) { e[p] = expf(sv[p] - mx); sum += e[p]; }
        for (int p = 0; p < 6; p++) wv[p] = e[p] / sum;
    }

    const _Float16* Bp = Bm + (long)(blockIdx.x * 128) * 1024;
    const int swz = ((lane & 7) ^ ((lane >> 3) & 7)) * 8;
    const int rsub = w * 32 + (lane >> 3);
    const _Float16* BpT = Bp + (long)rsub * 1024 + swz;
    _Float16* BsT = Bs + w * 2048;
    const _Float16* KVb = KV + ((long)b << 19);

    f32x4 acc[4][4] = {};
    for (int q = 0; q < 8; ++q) {
        const int coff = q * 64 + swz;
        __syncthreads();
#pragma unroll
        for (int i = 0; i < 4; i++) {
            int l = (rowblk + rsub + i * 8) & 511;
            float s8[8] = {};
#pragma unroll
            for (int k = 0; k < 6; k++) {
                const h8 v = *(const h8*)(KVb + ((long)((l + dl[k]) & 511) << 10) + coff);
#pragma unroll
                for (int j = 0; j < 8; j++) s8[j] = fmaf(wv[k], (float)v[j], s8[j]);
            }
            h8 hv;
#pragma unroll
            for (int j = 0; j < 8; j++) hv[j] = (_Float16)s8[j];
            *(h8*)(As + w * 2048 + i * 512 + lane * 8) = hv;
            gl_lds(BpT + (long)i * 8 * 1024 + q * 64, BsT + i * 512);
        }
        __syncthreads();
#pragma unroll
        for (int kk = 0; kk < 2; ++kk) {
            h8 af[4], bf[4];
            const int ks = kk * 4 + (lane >> 4);
#pragma unroll
            for (int m = 0; m < 4; m++) {
                int rowa = wr * 64 + m * 16 + (lane & 15);
                af[m] = *(const h8*)(As + rowa * 64 + ((ks ^ (rowa & 7)) * 8));
                int rowb = wc * 64 + m * 16 + (lane & 15);
                bf[m] = *(const h8*)(Bs + rowb * 64 + ((ks ^ (rowb & 7)) * 8));
            }
#pragma unroll
            for (int m = 0; m < 4; m++)
#pragma unroll
                for (int n = 0; n < 4; n++)
                    acc[m][n] = __builtin_amdgcn_mfma_f32_16x16x32_f16(af[m], bf[n], acc[m][n], 0, 0, 0);
        }
    }

    const int crow0 = rowblk + wr * 64 + (lane >> 4) * 4;
    const int ccol0 = blockIdx.x * 128 + wc * 64 + (lane & 15);
#pragma unroll
    for (int m = 0; m < 4; m++)
#pragma unroll
        for (int n = 0; n < 4; n++) {
            int col = ccol0 + n * 16;
#pragma unroll
            for (int r2 = 0; r2 < 4; r2++) {
                int row = crow0 + m * 16 + r2;
                long rb = (long)row * 1024 + col;
                float v = acc[m][n][r2] * osc + (float)Rc[rb] + (float)Rc[rb + 512];
                _Float16 hi = (_Float16)v;
                Cp[rb] = hi;
                Cp[rb + 512] = (_Float16)(v - (float)hi);
            }
        }
}

// ------------------------- weight conversion -------------------------------
__global__ __launch_bounds__(256)
void splitAll_k(P12 ps, _Float16* __restrict__ PA, _Float16* __restrict__ PB)
{
    const int m = blockIdx.y;
    const float* __restrict__ src = ps.p[m];
    _Float16* dst;
    if (m < 4)      dst = PA + (long)(2 * m) * 524288;
    else if (m < 8) dst = PB + (long)(2 * (m - 4)) * 524288;
    else            dst = PB + (long)(2 * (m - 8) + 1) * 524288;
    long t = (long)blockIdx.x * 256 + threadIdx.x;
    long row = t >> 6; int kc = (int)(t & 63) * 8;
    const float4 v0 = *(const float4*)(src + row * 512 + kc);
    const float4 v1 = *(const float4*)(src + row * 512 + kc + 4);
    float vv[8] = {v0.x,v0.y,v0.z,v0.w,v1.x,v1.y,v1.z,v1.w};
    h8 hi, lo;
#pragma unroll
    for (int j = 0; j < 8; j++) {
        float s = vv[j] * 64.f;
        _Float16 h = (_Float16)s;
        hi[j] = h; lo[j] = (_Float16)(s - (float)h);
    }
    *(h8*)(dst + row * 1024 + kc)       = hi;
    *(h8*)(dst + row * 1024 + 512 + kc) = lo;
}

__global__ __launch_bounds__(256)
void convWoAll_k(P4 ps, _Float16* __restrict__ PA)
{
    const int z = blockIdx.z;
    const float* __restrict__ src = ps.p[z];
    _Float16* dst = PA + (long)(2 * z + 1) * 524288;
    __shared__ float t[32][33];
    int k0 = blockIdx.x * 32, n0 = blockIdx.y * 32, tid = threadIdx.x;
#pragma unroll
    for (int i = 0; i < 4; i++) {
        int lin = tid + i * 256; int r = lin >> 5, c = lin & 31;
        t[r][c] = src[(long)(k0 + r) * 512 + n0 + c];
    }
    __syncthreads();
#pragma unroll
    for (int i = 0; i < 4; i++) {
        int lin = tid + i * 256; int n = lin >> 5, k = lin & 31;
        float v = t[k][n] * 64.f;
        _Float16 hi = (_Float16)v;
        long base = (long)(n0 + n) * 1024 + k0 + k;
        dst[base]       = hi;
        dst[base + 512] = (_Float16)(v - (float)hi);
    }
}

__global__ __launch_bounds__(256)
void convW2All_k(P6 ps, _Float16* __restrict__ encW1C, _Float16* __restrict__ encW2C,
                 _Float16* __restrict__ dW1C, _Float16* __restrict__ dW2C)
{
    const int z = blockIdx.z;
    const float* __restrict__ src = ps.p[z];
    _Float16* dst = (z==0) ? encW1C : (z==1) ? encW1C + 2097152 : (z==2) ? dW1C :
                    (z==3) ? encW2C : (z==4) ? encW2C + 2097152 : dW2C;
    const bool isW1 = z < 3;
    const int N = isW1 ? 2048 : 512;
    const int K = isW1 ? 512 : 2048;
    int k0 = (isW1 ? blockIdx.x : blockIdx.y) * 32;
    int n0 = (isW1 ? blockIdx.y : blockIdx.x) * 32;
    __shared__ float t[32][33];
    int tid = threadIdx.x;
#pragma unroll
    for (int i = 0; i < 4; i++) {
        int lin = tid + i * 256; int r = lin >> 5, c = lin & 31;
        t[r][c] = src[(long)(k0 + r) * N + n0 + c];
    }
    __syncthreads();
#pragma unroll
    for (int i = 0; i < 4; i++) {
        int lin = tid + i * 256; int n = lin >> 5, k = lin & 31;
        float v = t[k][n];
        _Float16 hi = (_Float16)v;
        long base = (long)(n0 + n) * 2 * K + k0 + k;
        dst[base]     = hi;
        dst[base + K] = (_Float16)(v - (float)hi);
    }
}

__global__ void convW63_k(const float* __restrict__ W, _Float16* __restrict__ dst)
{
    int i = blockIdx.x * 256 + threadIdx.x;
    int k = i & 511, j = i >> 9;
    float v = (j < 63) ? 64.f * W[(long)(j / 21) * 10752 + (long)k * 21 + (j % 21)] : 0.f;
    _Float16 hi = (_Float16)v;
    dst[(long)j * 1024 + k]       = hi;
    dst[(long)j * 1024 + 512 + k] = (_Float16)(v - (float)hi);
}

// ------------------------- embedding (cat-only out) ------------------------
__global__ __launch_bounds__(256)
void embed_k(const float* __restrict__ x, const float* __restrict__ mark,
             const float* __restrict__ valW, const float* __restrict__ timeW,
             _Float16* __restrict__ cat)
{
    const int lg = blockIdx.x, dh = blockIdx.y, b = blockIdx.z;
    const int tid = threadIdx.x;
    const int dd = dh * 256 + tid;
    const int l0 = lg * 8;
    __shared__ float xs[10][21];
    __shared__ float mk[8][4];
    if (tid < 210) {
        int r = tid / 21, c = tid % 21;
        int ll = (l0 - 1 + r + 512) & 511;
        xs[r][c] = x[((long)b * 512 + ll) * 21 + c];
    }
    if (tid >= 224 && tid < 256) {
        int t2 = tid - 224, il = t2 >> 2, m = t2 & 3;
        mk[il][m] = mark[((long)b * 512 + l0 + il) * 4 + m];
    }
    __syncthreads();
    float acc[8];
#pragma unroll
    for (int il = 0; il < 8; il++) acc[il] = 0.f;
    for (int t = 0; t < 3; t++)
        for (int c = 0; c < 21; c++) {
            float w = valW[(t * 21 + c) * 512 + dd];
#pragma unroll
            for (int il = 0; il < 8; il++)
                acc[il] = fmaf(xs[il + t][c], w, acc[il]);
        }
    for (int m = 0; m < 4; m++) {
        float w = timeW[m * 512 + dd];
#pragma unroll
        for (int il = 0; il < 8; il++)
            acc[il] = fmaf(mk[il][m], w, acc[il]);
    }
    const float freq = expf((float)(dd & ~1) * (-9.210340371976184f / 512.0f));
#pragma unroll
    for (int il = 0; il < 8; il++) {
        float ang = (float)(l0 + il) * freq;
        float pe = (dd & 1) ? cosf(ang) : sinf(ang);
        float v = acc[il] + pe;
        long row = (long)b * 512 + l0 + il;
        _Float16 hi = (_Float16)v;
        cat[row * 1024 + dd]       = hi;
        cat[row * 1024 + 512 + dd] = (_Float16)(v - (float)hi);
    }
}

// ------------------- windowed decomp (cat in/out) + mc-clean ---------------
template<int TREND>
__global__ __launch_bounds__(256)
void decompW_k(const _Float16* __restrict__ xc, _Float16* __restrict__ outc,
               _Float16* __restrict__ tsc, float* __restrict__ mcz, int nMc)
{
    long t = (long)blockIdx.x * 256 + threadIdx.x;
    if (t < nMc) mcz[t] = 0.f;
    long rowg = t >> 7; int d4 = (int)(t & 127) * 4;
    int lg = (int)(rowg & 63); long b = rowg >> 6;
    const int l0 = lg * 8;
    const _Float16* xb = xc + (b << 19);
    float s[8][4] = {};
    float xo[8][4];
#pragma unroll
    for (int rr = -12; rr <= 19; rr++) {
        int rc = l0 + rr; rc = rc < 0 ? 0 : (rc > 511 ? 511 : rc);
        h4 vh = *(const h4*)(xb + ((long)rc << 10) + d4);
        h4 vl = *(const h4*)(xb + ((long)rc << 10) + 512 + d4);
        float vv[4];
#pragma unroll
        for (int j = 0; j < 4; j++) vv[j] = (float)vh[j] + (float)vl[j];
#pragma unroll
        for (int i = 0; i < 8; i++) {
            if (i >= rr - 12 && i <= rr + 12) {
#pragma unroll
                for (int j = 0; j < 4; j++) s[i][j] += vv[j];
            }
        }
        if (rr >= 0 && rr < 8) {
#pragma unroll
            for (int j = 0; j < 4; j++) xo[rr][j] = vv[j];
        }
    }
#pragma unroll
    for (int i = 0; i < 8; i++) {
        long row = b * 512 + l0 + i;
        float tr[4], ov[4];
#pragma unroll
        for (int j = 0; j < 4; j++) {
            tr[j] = s[i][j] * (1.f / 25.f);
            ov[j] = xo[i][j] - tr[j];
        }
        h4 hi, lo;
#pragma unroll
        for (int j = 0; j < 4; j++) {
            _Float16 h = (_Float16)ov[j];
            hi[j] = h; lo[j] = (_Float16)(ov[j] - (float)h);
        }
        *(h4*)(outc + row * 1024 + d4)       = hi;
        *(h4*)(outc + row * 1024 + 512 + d4) = lo;
        if (TREND) {
            _Float16* tp = tsc + row * 1024 + d4;
            if (TREND == 1) {
                h4 th = *(h4*)tp, tl = *(h4*)(tp + 512);
#pragma unroll
                for (int j = 0; j < 4; j++) tr[j] += (float)th[j] + (float)tl[j];
            }
            h4 th2, tl2;
#pragma unroll
            for (int j = 0; j < 4; j++) {
                _Float16 h = (_Float16)tr[j];
                th2[j] = h; tl2[j] = (_Float16)(tr[j] - (float)h);
            }
            *(h4*)tp         = th2;
            *(h4*)(tp + 512) = tl2;
        }
    }
}

// ------------------------- prep (mean + zero mc) ---------------------------
__global__ __launch_bounds__(512)
void meanseq2_k(const float* __restrict__ x, float* __restrict__ xm,
                float* __restrict__ mcz)
{
    int b = blockIdx.x, tid = threadIdx.x;
    mcz[b * 512 + tid] = 0.f;
    __shared__ float sd[504];
    if (tid < 504) {
        int c = tid % 21, g = tid / 21;
        int l0 = g * 22, l1 = l0 + 22 > 512 ? 512 : l0 + 22;
        const float* xb = x + (long)b * 10752;
        float s = 0.f;
        for (int l = l0; l < l1; l++) s += xb[l * 21 + c];
        sd[tid] = s;
    }
    __syncthreads();
    if (tid < 21) {
        float t = 0.f;
#pragma unroll
        for (int g = 0; g < 24; g++) t += sd[g * 21 + tid];
        xm[b * 21 + tid] = t * (1.f / 512.f);
    }
}

__global__ void prep_k(const float* __restrict__ x, const float* __restrict__ xm,
                       float* __restrict__ sinit, float* __restrict__ tinit, int total)
{
    int i = blockIdx.x * 256 + threadIdx.x;
    if (i >= total) return;
    int c = i % 21, l = (i / 21) % 512, b = i / 10752;
    if (l < 256) {
        int lc = 256 + l;
        float s = 0.f;
        for (int j = -12; j <= 12; j++) {
            int ll = lc + j; ll = ll > 511 ? 511 : ll;
            s += x[((long)b * 512 + ll) * 21 + c];
        }
        float t = s * (1.f / 25.f);
        tinit[i] = t;
        sinit[i] = x[((long)b * 512 + lc) * 21 + c] - t;
    } else {
        sinit[i] = 0.f;
        tinit[i] = xm[b * 21 + c];
    }
}

// ------------------------- seasonal layernorm (cat in, f32 out) ------------
__global__ __launch_bounds__(256)
void ln_k(const _Float16* __restrict__ xc, const float* __restrict__ g,
          const float* __restrict__ be, float* __restrict__ out)
{
    int row = blockIdx.x, tid = threadIdx.x;
    const _Float16* xr = xc + ((long)row << 10);
    float v0 = (float)xr[tid]       + (float)xr[tid + 512];
    float v1 = (float)xr[tid + 256] + (float)xr[tid + 768];
    __shared__ float rs[256];
    rs[tid] = v0 + v1; __syncthreads();
    for (int s = 128; s > 0; s >>= 1) { if (tid < s) rs[tid] += rs[tid + s]; __syncthreads(); }
    float mu = rs[0] * (1.f / 512.f);
    __syncthreads();
    float d0 = v0 - mu, d1 = v1 - mu;
    rs[tid] = d0 * d0 + d1 * d1; __syncthreads();
    for (int s = 128; s > 0; s >>= 1) { if (tid < s) rs[tid] += rs[tid + s]; __syncthreads(); }
    float rstd = 1.0f / sqrtf(rs[0] * (1.f / 512.f) + 1e-5f);
    out[((long)row << 9) + tid]       = d0 * rstd * g[tid] + be[tid];
    out[((long)row << 9) + tid + 256] = d1 * rstd * g[tid + 256] + be[tid + 256];
}

// per-(b, 64-row chunk, d) partial column sums. grid (2, 8, Bc)
__global__ void colpart_k(const float* __restrict__ x, float* __restrict__ cp)
{
    int d = blockIdx.x * 256 + threadIdx.x;
    int ch = blockIdx.y, b = blockIdx.z;
    const float* xb = x + ((long)b << 18);
    float s = 0.f;
    for (int l = ch * 64; l < ch * 64 + 64; l++) s += xb[((long)l << 9) + d];
    cp[((long)(b * 8 + ch) << 9) + d] = s;
}

// cs[b][d] = mean over l (from 8 partials). grid (2, Bc)
__global__ void colmean_k(const float* __restrict__ cp, float* __restrict__ cs)
{
    int d = blockIdx.x * 256 + threadIdx.x;
    int b = blockIdx.y;
    float s = 0.f;
#pragma unroll
    for (int ch = 0; ch < 8; ch++) s += cp[((long)(b * 8 + ch) << 9) + d];
    cs[((long)b << 9) + d] = s * (1.f / 512.f);
}

// write hi/lo cat of (x - cs) — encoder tail
__global__ __launch_bounds__(256)
void subcolcat_k(const float* __restrict__ x, const float* __restrict__ cs,
                 _Float16* __restrict__ cat)
{
    long t = (long)blockIdx.x * 256 + threadIdx.x;
    long row = t >> 6; int d8 = (int)(t & 63) * 8;
    int b = (int)(row >> 9);
    const float4* c4 = (const float4*)(cs + ((long)b << 9) + d8);
    float4 m0 = c4[0], m1 = c4[1];
    float m[8] = {m0.x,m0.y,m0.z,m0.w,m1.x,m1.y,m1.z,m1.w};
    const float4* xp = (const float4*)(x + row * 512 + d8);
    float4 x0 = xp[0], x1 = xp[1];
    float v[8] = {x0.x,x0.y,x0.z,x0.w,x1.x,x1.y,x1.z,x1.w};
    h8 hi, lo;
#pragma unroll
    for (int j = 0; j < 8; j++) {
        float vv = v[j] - m[j];
        _Float16 h = (_Float16)vv;
        hi[j] = h; lo[j] = (_Float16)(vv - (float)h);
    }
    *(h8*)(cat + row * 1024 + d8)       = hi;
    *(h8*)(cat + row * 1024 + 512 + d8) = lo;
}

// proj with cs subtract + trend shift-add (decoder tail)
__global__ void proj_k(const float* __restrict__ x, const float* __restrict__ cs,
                       const float* __restrict__ pw, const float* __restrict__ pb,
                       const float* __restrict__ tinit, const float* __restrict__ H,
                       float* __restrict__ out, int total)
{
    int i = blockIdx.x * 256 + threadIdx.x;
    if (i >= total) return;
    int c = i % 21, l = (i / 21) % 256 + 256, b = i / 5376;
    const float* xr = x + ((long)(b * 512 + l) << 9);
    const float* csb = cs + ((long)b << 9);
    float s = 0.f;
    for (int d = 0; d < 512; d++)
        s = fmaf(xr[d] - csb[d], pw[d * 21 + c], s);
    long r = (long)b * 512;
    float trend = tinit[b * 10752 + l * 21 + c]
                + H[(r + ((l + 511) & 511)) * 128 + c]
                + H[(r + l) * 128 + 21 + c]
                + H[(r + ((l + 1) & 511)) * 128 + 42 + c];
    out[i] = s + pb[c] + trend;
}

// ---------------------------------------------------------------------------
// mode: 0 OUT1 plain-cat, 2 OUT1 gelu, 12 OUT1 +Rcat, 11 OUT0 f32, 20 Scorr
static void hgemm(int mode, int nph, float osc,
                  const _Float16* A, int lda, int loA,
                  const _Float16* B, int ldb, int loB,
                  const _Float16* Rc, void* C, int ldc, int loC,
                  int K, int M, int N, int batch,
                  long sA, long sB, long sC, hipStream_t st)
{
    dim3 g(N / 128, M / 128, batch), blk(256);
    switch (mode) {
    case 0:  hgemm_k<0,1><<<g,blk,0,st>>>(A,lda,loA,B,ldb,loB,Rc,C,ldc,loC,K,nph,osc,sA,sB,sC); break;
    case 2:  hgemm_k<2,1><<<g,blk,0,st>>>(A,lda,loA,B,ldb,loB,Rc,C,ldc,loC,K,nph,osc,sA,sB,sC); break;
    case 12: hgemm_k<1,1><<<g,blk,0,st>>>(A,lda,loA,B,ldb,loB,Rc,C,ldc,loC,K,nph,osc,sA,sB,sC); break;
    case 11: hgemm_k<0,0><<<g,blk,0,st>>>(A,lda,loA,B,ldb,loB,Rc,C,ldc,loC,K,nph,osc,sA,sB,sC); break;
    default: hgemm_k<0,2><<<g,blk,0,st>>>(A,lda,loA,B,ldb,loB,Rc,C,ldc,loC,K,nph,osc,sA,sB,sC); break;
    }
}

extern "C" void kernel_launch(void* const* d_in, const int* in_sizes, int n_in,
                              void* d_out, int out_size, void* d_ws, size_t ws_size,
                              hipStream_t stream)
{
    const float* x_enc    = (const float*)d_in[0];
    const float* xm_enc   = (const float*)d_in[1];
    const float* xm_dec   = (const float*)d_in[3];
    const float* enc_valW = (const float*)d_in[4];
    const float* enc_timeW= (const float*)d_in[5];
    const float* enc_Wq   = (const float*)d_in[6];
    const float* enc_Wk   = (const float*)d_in[7];
    const float* enc_Wv   = (const float*)d_in[8];
    const float* enc_Wo   = (const float*)d_in[9];
    const float* enc_W1   = (const float*)d_in[10];
    const float* enc_W2   = (const float*)d_in[11];
    const float* enc_g    = (const float*)d_in[12];
    const float* enc_b    = (const float*)d_in[13];
    const float* dec_valW = (const float*)d_in[14];
    const float* dec_timeW= (const float*)d_in[15];
    const float* sWq = (const float*)d_in[16];
    const float* sWk = (const float*)d_in[17];
    const float* sWv = (const float*)d_in[18];
    const float* sWo = (const float*)d_in[19];
    const float* cWq = (const float*)d_in[20];
    const float* cWk = (const float*)d_in[21];
    const float* cWv = (const float*)d_in[22];
    const float* cWo = (const float*)d_in[23];
    const float* dW1 = (const float*)d_in[24];
    const float* dW2 = (const float*)d_in[25];
    const float* dtW = (const float*)d_in[26];
    const float* dec_g = (const float*)d_in[27];
    const float* dec_b = (const float*)d_in[28];
    const float* projW = (const float*)d_in[29];
    const float* projB = (const float*)d_in[30];

    // ---- batch-chunk sizing (deterministic) ----
    const size_t W_BYTES = 50000000;
    const size_t perB = 8000000;
    int Bc = 32;
    while (Bc > 1 && W_BYTES + (size_t)Bc * perB + (4u << 20) > ws_size) Bc >>= 1;

    char* wp = (char*)d_ws;
    auto alloc = [&](size_t bytes) { char* p = wp; wp += (bytes + 255) & ~(size_t)255; return p; };

    _Float16* Wcat8  = (_Float16*)alloc(8 * 524288 * 2);
    _Float16* encW1C = (_Float16*)alloc(2 * 2097152 * 2);
    _Float16* encW2C = (_Float16*)alloc(2 * 2097152 * 2);
    _Float16* dW1C   = (_Float16*)alloc(2097152 * 2);
    _Float16* dW2C   = (_Float16*)alloc(2097152 * 2);
    _Float16* W63C   = (_Float16*)alloc(131072 * 2);
    _Float16* PA     = (_Float16*)alloc(8 * 524288 * 2);
    _Float16* PB     = (_Float16*)alloc(8 * 524288 * 2);

    const long ROWS = (long)Bc * 512;
    _Float16* cX     = (_Float16*)alloc(ROWS * 1024 * 2);
    _Float16* cO     = (_Float16*)alloc(ROWS * 1024 * 2);
    _Float16* TSc    = (_Float16*)alloc(ROWS * 1024 * 2);
    _Float16* ENCcat = (_Float16*)alloc(ROWS * 1024 * 2);
    _Float16* bigcat = (_Float16*)alloc(ROWS * 2048 * 2);
    float* F       = (float*)alloc(ROWS * 512 * 4);
    float* H       = (float*)alloc(ROWS * 128 * 4);
    float* sinit   = (float*)alloc((long)Bc * 10752 * 4);
    float* tinit   = (float*)alloc((long)Bc * 10752 * 4);
    float* xmean   = (float*)alloc((long)Bc * 21 * 4);
    float* mc      = (float*)alloc((long)Bc * 512 * 4);
    float* cp      = (float*)alloc((long)Bc * 4096 * 4);
    float* cs      = (float*)alloc((long)Bc * 512 * 4);

    // ---- weight setup ----
    dim3 cb(256);
    P12 sp;
    sp.p[0] = enc_Wk;  sp.p[1] = enc_Wk + 262144;
    sp.p[2] = sWk;     sp.p[3] = cWk;
    sp.p[4] = enc_Wq;  sp.p[5] = enc_Wq + 262144;
    sp.p[6] = sWq;     sp.p[7] = cWq;
    sp.p[8] = enc_Wv;  sp.p[9] = enc_Wv + 262144;
    sp.p[10] = sWv;    sp.p[11] = cWv;
    P4 op;
    op.p[0] = enc_Wo;  op.p[1] = enc_Wo + 262144;
    op.p[2] = sWo;     op.p[3] = cWo;
    P6 fp;
    fp.p[0] = enc_W1;  fp.p[1] = enc_W1 + 1048576; fp.p[2] = dW1;
    fp.p[3] = enc_W2;  fp.p[4] = enc_W2 + 1048576; fp.p[5] = dW2;
    splitAll_k <<<dim3(128,12), cb, 0, stream>>>(sp, PA, PB);
    convWoAll_k<<<dim3(16,16,4), cb, 0, stream>>>(op, PA);
    hgemm(0, 3, 1.f, PA,1024,512, PB,1024,512, nullptr, Wcat8, 1024, 512,
          512, 512, 512, 8, 524288, 524288, 524288, stream);
    convW2All_k<<<dim3(16,64,6), cb, 0, stream>>>(fp, encW1C, encW2C, dW1C, dW2C);
    convW63_k  <<<256, cb, 0, stream>>>(dtW, W63C);

    const int M = (int)ROWS;
    const int t21 = Bc * 10752;
    const int gRows = Bc * 128;
    const int gW = Bc * 32;
    const int nMc = Bc * 512;
    const long sCA = 512 * 1024;
    const float IOS = 1.f / 4096.f;

    auto attn = [&](const _Float16* cIn, _Float16* cOut,
                    const _Float16* KVcat, int slot) {
        const _Float16* WqkC_ = Wcat8 + (long)(2*slot)     * 524288;
        const _Float16* WvoC_ = Wcat8 + (long)(2*slot + 1) * 524288;
        hgemm(0, 3, 1.f, cIn,1024,512, WqkC_,1024,512, nullptr, bigcat, 1024, 512,
              512, M, 512, 1, 0,0,0, stream);                              // T cat
        hgemm(20, 3, 1.f, bigcat,1024,512, KVcat,1024,512, nullptr, mc, 0, 0,
              512, 512, 512, Bc, sCA, sCA, 512, stream);                   // diag
        hgemmAgg_k<<<dim3(4, M/128), 256, 0, stream>>>(KVcat, mc, WvoC_, cIn, cOut, IOS);
    };
    auto ffn = [&](const _Float16* cIn, _Float16* cOut,
                   const _Float16* W1C, const _Float16* W2C) {
        hgemm(2, 1, 1.f, cIn,1024,512, W1C,1024,512, nullptr, bigcat, 2048, -1,
              512, M, 2048, 1, 0,0,0, stream);
        hgemm(12, 1, 1.f, bigcat,2048,0, W2C,4096,2048, cIn, cOut, 1024, 512,
              2048, M, 512, 1, 0,0,0, stream);
    };

    for (int b0 = 0; b0 < 32; b0 += Bc) {
        const float* xe  = x_enc  + (long)b0 * 10752;
        const float* mke = xm_enc + (long)b0 * 2048;
        const float* mkd = xm_dec + (long)b0 * 2048;
        float* outp = (float*)d_out + (long)b0 * 5376;

        meanseq2_k<<<Bc, 512, 0, stream>>>(xe, xmean, mc);
        prep_k    <<<(t21 + 255)/256, 256, 0, stream>>>(xe, xmean, sinit, tinit, t21);

        // ---------------- encoder ----------------
        embed_k<<<dim3(64,2,Bc), 256, 0, stream>>>(xe, mke, enc_valW, enc_timeW, cX);
        for (int L = 0; L < 2; L++) {
            attn(cX, cO, cX, L);
            decompW_k<0><<<gW, 256, 0, stream>>>(cO, cX, nullptr, mc, nMc);
            ffn(cX, cO, encW1C + (long)L*2097152, encW2C + (long)L*2097152);
            decompW_k<0><<<gW, 256, 0, stream>>>(cO, cX, nullptr, mc, nMc);
        }
        ln_k       <<<Bc*512, 256, 0, stream>>>(cX, enc_g, enc_b, F);
        colpart_k  <<<dim3(2,8,Bc), 256, 0, stream>>>(F, cp);
        colmean_k  <<<dim3(2,Bc), 256, 0, stream>>>(cp, cs);
        subcolcat_k<<<gRows, 256, 0, stream>>>(F, cs, ENCcat);

        // ---------------- decoder ----------------
        embed_k<<<dim3(64,2,Bc), 256, 0, stream>>>(sinit, mkd, dec_valW, dec_timeW, cX);

        attn(cX, cO, cX, 2);                                         // self
        decompW_k<2><<<gW, 256, 0, stream>>>(cO, cX, TSc, mc, nMc);  // TSc = trend
        attn(cX, cO, ENCcat, 3);                                     // cross
        decompW_k<1><<<gW, 256, 0, stream>>>(cO, cX, TSc, mc, nMc);  // TSc += trend
        ffn(cX, cO, dW1C, dW2C);
        decompW_k<1><<<gW, 256, 0, stream>>>(cO, cX, TSc, mc, nMc);

        hgemm(11, 1, 1.f/64.f, TSc,1024,512, W63C,1024,512, nullptr, H, 128, 0,
              512, M, 128, 1, 0,0,0, stream);
        ln_k     <<<Bc*512, 256, 0, stream>>>(cX, dec_g, dec_b, F);
        colpart_k<<<dim3(2,8,Bc), 256, 0, stream>>>(F, cp);
        colmean_k<<<dim3(2,Bc), 256, 0, stream>>>(cp, cs);
        proj_k   <<<(Bc*5376+255)/256, 256, 0, stream>>>(F, cs, projW, projB,
                                                         tinit, H, outp, Bc*5376);
    }
}

// Round 16
// 2073.338 us; speedup vs baseline: 1.1482x; 1.0425x over previous
//
#include <hip/hip_runtime.h>

// ---------------------------------------------------------------------------
// Autoformer forward, MI355X. Round 16: round-15 + XCD-aware bijective block
// swizzle on all MFMA kernels (L2 locality; chunked remap per m204).
// GEMM numerics: C = Ah*Bh [+ Ah*Bl [+ Al*Bh]], operands rows x 2K f16 [hi|lo].
// ---------------------------------------------------------------------------

typedef _Float16 h8 __attribute__((ext_vector_type(8)));
typedef _Float16 h4 __attribute__((ext_vector_type(4)));
typedef float f32x4 __attribute__((ext_vector_type(4)));

struct P12 { const float* p[12]; };
struct P6  { const float* p[6]; };
struct P4  { const float* p[4]; };

__device__ __forceinline__ float gelu_f(float x){
    return 0.5f * x * (1.0f + erff(x * 0.70710678118654752f));
}

__device__ __forceinline__ void gl_lds(const _Float16* gp, _Float16* lp) {
    __builtin_amdgcn_global_load_lds(
        (const __attribute__((address_space(1))) void*)gp,
        (__attribute__((address_space(3))) void*)lp, 16, 0, 0);
}

// bijective chunked XCD swizzle: consecutive HW-dispatch ids (round-robin over
// 8 XCDs) -> contiguous linear block ranges per XCD. Returns remapped linear.
__device__ __forceinline__ int xcd_swz(int lin, int nwg) {
    const int q = nwg >> 3, r = nwg & 7;
    const int xcd = lin & 7, idx = lin >> 3;
    return (xcd < r) ? xcd * (q + 1) + idx
                     : r * (q + 1) + (xcd - r) * q + idx;
}

// ------------------------------ MFMA GEMM ----------------------------------
// A: M x 2K [hi|lo] (lda halfs, lo at +loA). B: N x 2K (ldb, +loB).
// nph phases x (K/64): (Ah,Bh)[,(Ah,Bl)[,(Al,Bh)]]. f32 accum, *osc epilogue.
// OUT=0: f32 C. OUT=1: f16 cat C (loC<0 -> hi only); EPI 0 plain/1 +Rcat/2 gelu.
// OUT=2: diag reduce: atomicAdd mc[bz*sC + (row-col)&511].
template<int EPI, int OUT>
__global__ __launch_bounds__(256)
void hgemm_k(const _Float16* __restrict__ A, int lda, int loA,
             const _Float16* __restrict__ Bm, int ldb, int loB,
             const _Float16* __restrict__ Rc, void* __restrict__ Cv,
             int ldc, int loC, int K, int nph, float osc,
             long sA, long sB, long sC)
{
    __shared__ _Float16 As[128 * 64];
    __shared__ _Float16 Bs[128 * 64];
    const int gx = gridDim.x, gy = gridDim.y;
    int lin = blockIdx.x + gx * (blockIdx.y + gy * blockIdx.z);
    lin = xcd_swz(lin, gx * gy * gridDim.z);
    const int bxi = lin % gx; lin /= gx;
    const int byi = lin % gy;
    const int bz  = lin / gy;
    const int tid = threadIdx.x, lane = tid & 63, w = tid >> 6;
    const int wr = w >> 1, wc = w & 1;
    const _Float16* Ap = A + bz * sA + (long)(byi * 128) * lda;
    const _Float16* Bp = Bm + bz * sB + (long)(bxi * 128) * ldb;

    const int swz = ((lane & 7) ^ ((lane >> 3) & 7)) * 8;
    const int rsub = w * 32 + (lane >> 3);
    const _Float16* ApT = Ap + (long)rsub * lda + swz;
    const _Float16* BpT = Bp + (long)rsub * ldb + swz;
    _Float16* AsT = As + w * 2048;
    _Float16* BsT = Bs + w * 2048;

    const int tpp = K >> 6;
    const int nkt = tpp * nph;
    f32x4 acc[4][4] = {};

    int p = 0, q = 0;
    for (int kt = 0; kt < nkt; ++kt) {
        const int aoff = q * 64 + (p == 2 ? loA : 0);
        const int boff = q * 64 + (p == 1 ? loB : 0);
        __syncthreads();
#pragma unroll
        for (int i = 0; i < 4; i++) {
            gl_lds(ApT + (long)i * 8 * lda + aoff, AsT + i * 512);
            gl_lds(BpT + (long)i * 8 * ldb + boff, BsT + i * 512);
        }
        __syncthreads();
#pragma unroll
        for (int kk = 0; kk < 2; ++kk) {
            h8 af[4], bf[4];
            const int ks = kk * 4 + (lane >> 4);
#pragma unroll
            for (int m = 0; m < 4; m++) {
                int rowa = wr * 64 + m * 16 + (lane & 15);
                af[m] = *(const h8*)(As + rowa * 64 + ((ks ^ (rowa & 7)) * 8));
                int rowb = wc * 64 + m * 16 + (lane & 15);
                bf[m] = *(const h8*)(Bs + rowb * 64 + ((ks ^ (rowb & 7)) * 8));
            }
#pragma unroll
            for (int m = 0; m < 4; m++)
#pragma unroll
                for (int n = 0; n < 4; n++)
                    acc[m][n] = __builtin_amdgcn_mfma_f32_16x16x32_f16(af[m], bf[n], acc[m][n], 0, 0, 0);
        }
        if (++q == tpp) { q = 0; ++p; }
    }

    const int crow0 = byi * 128 + wr * 64 + (lane >> 4) * 4;
    const int ccol0 = bxi * 128 + wc * 64 + (lane & 15);
    if constexpr (OUT == 0) {
        float* Cp = (float*)Cv + (long)bz * sC;
#pragma unroll
        for (int m = 0; m < 4; m++)
#pragma unroll
            for (int n = 0; n < 4; n++) {
                int col = ccol0 + n * 16;
#pragma unroll
                for (int r2 = 0; r2 < 4; r2++) {
                    long idx = (long)(crow0 + m * 16 + r2) * ldc + col;
                    Cp[idx] = acc[m][n][r2] * osc;
                }
            }
    } else if constexpr (OUT == 1) {
        _Float16* Cp = (_Float16*)Cv + (long)bz * sC;
#pragma unroll
        for (int m = 0; m < 4; m++)
#pragma unroll
            for (int n = 0; n < 4; n++) {
                int col = ccol0 + n * 16;
#pragma unroll
                for (int r2 = 0; r2 < 4; r2++) {
                    int row = crow0 + m * 16 + r2;
                    long base = (long)row * ldc + col;
                    float v = acc[m][n][r2] * osc;
                    if (EPI == 1) {
                        long rb = (long)row * 1024 + col;
                        v += (float)Rc[rb] + (float)Rc[rb + 512];
                    }
                    if (EPI == 2) v = gelu_f(v);
                    _Float16 hi = (_Float16)v;
                    Cp[base] = hi;
                    if (loC >= 0) Cp[base + loC] = (_Float16)(v - (float)hi);
                }
            }
    } else {
        __shared__ float diag[512];
        float* mc = (float*)Cv + (long)bz * sC;
        for (int t = tid; t < 512; t += 256) diag[t] = 0.f;
        __syncthreads();
#pragma unroll
        for (int m = 0; m < 4; m++)
#pragma unroll
            for (int n = 0; n < 4; n++) {
                int col = ccol0 + n * 16;
#pragma unroll
                for (int r2 = 0; r2 < 4; r2++) {
                    int row = crow0 + m * 16 + r2;
                    atomicAdd(&diag[(row - col) & 511], acc[m][n][r2]);
                }
            }
        __syncthreads();
        for (int t = tid; t < 512; t += 256) {
            float v = diag[t];
            if (v != 0.f) atomicAdd(&mc[t], v);
        }
    }
}

// --------------- Wvo GEMM with fused top-k + agg gather --------------------
__global__ __launch_bounds__(256)
void hgemmAgg_k(const _Float16* __restrict__ KV, const float* __restrict__ mc,
                const _Float16* __restrict__ Bm,
                const _Float16* __restrict__ Rc, _Float16* __restrict__ Cp,
                float osc)
{
    __shared__ _Float16 As[128 * 64];
    __shared__ _Float16 Bs[128 * 64];
    const int gx = gridDim.x;
    int lin = blockIdx.x + gx * blockIdx.y;
    lin = xcd_swz(lin, gx * gridDim.y);
    const int bxi = lin % gx;
    const int byi = lin / gx;
    const int tid = threadIdx.x, lane = tid & 63, w = tid >> 6;
    const int wr = w >> 1, wc = w & 1;
    const int rowblk = byi * 128;
    const int b = rowblk >> 9;

    int dl[6]; float wv[6];
    {
        float* v  = (float*)As;
        float* rv = (float*)As + 512;
        int*   ri = (int*)Bs;
        const float SCL = 1.f / (512.f * 4096.f);
        v[tid]       = mc[b * 512 + tid]       * SCL;
        v[tid + 256] = mc[b * 512 + tid + 256] * SCL;
        __syncthreads();
        float sv[6];
        for (int p = 0; p < 6; p++) {
            float bv = v[tid]; int bi = tid;
            float v2 = v[tid + 256];
            if (v2 > bv) { bv = v2; bi = tid + 256; }
            rv[tid] = bv; ri[tid] = bi;
            __syncthreads();
            for (int s = 128; s > 0; s >>= 1) {
                if (tid < s) {
                    float ov = rv[tid + s]; int oi = ri[tid + s];
                    if (ov > rv[tid] || (ov == rv[tid] && oi < ri[tid])) {
                        rv[tid] = ov; ri[tid] = oi;
                    }
                }
                __syncthreads();
            }
            sv[p] = rv[0]; dl[p] = ri[0];
            __syncthreads();
            if (tid == 0) v[ri[0]] = -3.4e38f;
            __syncthreads();
        }
        float mx = sv[0];
        for (int p = 1; p < 6; p++) mx = fmaxf(mx, sv[p]);
        float e[6], sum = 0.f;
        for (int p = 0; p < 6; p++) { e[p] = expf(sv[p] - mx); sum += e[p]; }
        for (int p = 0; p < 6; p++) wv[p] = e[p] / sum;
    }

    const _Float16* Bp = Bm + (long)(bxi * 128) * 1024;
    const int swz = ((lane & 7) ^ ((lane >> 3) & 7)) * 8;
    const int rsub = w * 32 + (lane >> 3);
    const _Float16* BpT = Bp + (long)rsub * 1024 + swz;
    _Float16* BsT = Bs + w * 2048;
    const _Float16* KVb = KV + ((long)b << 19);

    f32x4 acc[4][4] = {};
    for (int q = 0; q < 8; ++q) {
        const int coff = q * 64 + swz;
        __syncthreads();
#pragma unroll
        for (int i = 0; i < 4; i++) {
            int l = (rowblk + rsub + i * 8) & 511;
            float s8[8] = {};
#pragma unroll
            for (int k = 0; k < 6; k++) {
                const h8 v = *(const h8*)(KVb + ((long)((l + dl[k]) & 511) << 10) + coff);
#pragma unroll
                for (int j = 0; j < 8; j++) s8[j] = fmaf(wv[k], (float)v[j], s8[j]);
            }
            h8 hv;
#pragma unroll
            for (int j = 0; j < 8; j++) hv[j] = (_Float16)s8[j];
            *(h8*)(As + w * 2048 + i * 512 + lane * 8) = hv;
            gl_lds(BpT + (long)i * 8 * 1024 + q * 64, BsT + i * 512);
        }
        __syncthreads();
#pragma unroll
        for (int kk = 0; kk < 2; ++kk) {
            h8 af[4], bf[4];
            const int ks = kk * 4 + (lane >> 4);
#pragma unroll
            for (int m = 0; m < 4; m++) {
                int rowa = wr * 64 + m * 16 + (lane & 15);
                af[m] = *(const h8*)(As + rowa * 64 + ((ks ^ (rowa & 7)) * 8));
                int rowb = wc * 64 + m * 16 + (lane & 15);
                bf[m] = *(const h8*)(Bs + rowb * 64 + ((ks ^ (rowb & 7)) * 8));
            }
#pragma unroll
            for (int m = 0; m < 4; m++)
#pragma unroll
                for (int n = 0; n < 4; n++)
                    acc[m][n] = __builtin_amdgcn_mfma_f32_16x16x32_f16(af[m], bf[n], acc[m][n], 0, 0, 0);
        }
    }

    const int crow0 = rowblk + wr * 64 + (lane >> 4) * 4;
    const int ccol0 = bxi * 128 + wc * 64 + (lane & 15);
#pragma unroll
    for (int m = 0; m < 4; m++)
#pragma unroll
        for (int n = 0; n < 4; n++) {
            int col = ccol0 + n * 16;
#pragma unroll
            for (int r2 = 0; r2 < 4; r2++) {
                int row = crow0 + m * 16 + r2;
                long rb = (long)row * 1024 + col;
                float v = acc[m][n][r2] * osc + (float)Rc[rb] + (float)Rc[rb + 512];
                _Float16 hi = (_Float16)v;
                Cp[rb] = hi;
                Cp[rb + 512] = (_Float16)(v - (float)hi);
            }
        }
}

// ------------------------- weight conversion -------------------------------
__global__ __launch_bounds__(256)
void splitAll_k(P12 ps, _Float16* __restrict__ PA, _Float16* __restrict__ PB)
{
    const int m = blockIdx.y;
    const float* __restrict__ src = ps.p[m];
    _Float16* dst;
    if (m < 4)      dst = PA + (long)(2 * m) * 524288;
    else if (m < 8) dst = PB + (long)(2 * (m - 4)) * 524288;
    else            dst = PB + (long)(2 * (m - 8) + 1) * 524288;
    long t = (long)blockIdx.x * 256 + threadIdx.x;
    long row = t >> 6; int kc = (int)(t & 63) * 8;
    const float4 v0 = *(const float4*)(src + row * 512 + kc);
    const float4 v1 = *(const float4*)(src + row * 512 + kc + 4);
    float vv[8] = {v0.x,v0.y,v0.z,v0.w,v1.x,v1.y,v1.z,v1.w};
    h8 hi, lo;
#pragma unroll
    for (int j = 0; j < 8; j++) {
        float s = vv[j] * 64.f;
        _Float16 h = (_Float16)s;
        hi[j] = h; lo[j] = (_Float16)(s - (float)h);
    }
    *(h8*)(dst + row * 1024 + kc)       = hi;
    *(h8*)(dst + row * 1024 + 512 + kc) = lo;
}

__global__ __launch_bounds__(256)
void convWoAll_k(P4 ps, _Float16* __restrict__ PA)
{
    const int z = blockIdx.z;
    const float* __restrict__ src = ps.p[z];
    _Float16* dst = PA + (long)(2 * z + 1) * 524288;
    __shared__ float t[32][33];
    int k0 = blockIdx.x * 32, n0 = blockIdx.y * 32, tid = threadIdx.x;
#pragma unroll
    for (int i = 0; i < 4; i++) {
        int lin = tid + i * 256; int r = lin >> 5, c = lin & 31;
        t[r][c] = src[(long)(k0 + r) * 512 + n0 + c];
    }
    __syncthreads();
#pragma unroll
    for (int i = 0; i < 4; i++) {
        int lin = tid + i * 256; int n = lin >> 5, k = lin & 31;
        float v = t[k][n] * 64.f;
        _Float16 hi = (_Float16)v;
        long base = (long)(n0 + n) * 1024 + k0 + k;
        dst[base]       = hi;
        dst[base + 512] = (_Float16)(v - (float)hi);
    }
}

__global__ __launch_bounds__(256)
void convW2All_k(P6 ps, _Float16* __restrict__ encW1C, _Float16* __restrict__ encW2C,
                 _Float16* __restrict__ dW1C, _Float16* __restrict__ dW2C)
{
    const int z = blockIdx.z;
    const float* __restrict__ src = ps.p[z];
    _Float16* dst = (z==0) ? encW1C : (z==1) ? encW1C + 2097152 : (z==2) ? dW1C :
                    (z==3) ? encW2C : (z==4) ? encW2C + 2097152 : dW2C;
    const bool isW1 = z < 3;
    const int N = isW1 ? 2048 : 512;
    const int K = isW1 ? 512 : 2048;
    int k0 = (isW1 ? blockIdx.x : blockIdx.y) * 32;
    int n0 = (isW1 ? blockIdx.y : blockIdx.x) * 32;
    __shared__ float t[32][33];
    int tid = threadIdx.x;
#pragma unroll
    for (int i = 0; i < 4; i++) {
        int lin = tid + i * 256; int r = lin >> 5, c = lin & 31;
        t[r][c] = src[(long)(k0 + r) * N + n0 + c];
    }
    __syncthreads();
#pragma unroll
    for (int i = 0; i < 4; i++) {
        int lin = tid + i * 256; int n = lin >> 5, k = lin & 31;
        float v = t[k][n];
        _Float16 hi = (_Float16)v;
        long base = (long)(n0 + n) * 2 * K + k0 + k;
        dst[base]     = hi;
        dst[base + K] = (_Float16)(v - (float)hi);
    }
}

__global__ void convW63_k(const float* __restrict__ W, _Float16* __restrict__ dst)
{
    int i = blockIdx.x * 256 + threadIdx.x;
    int k = i & 511, j = i >> 9;
    float v = (j < 63) ? 64.f * W[(long)(j / 21) * 10752 + (long)k * 21 + (j % 21)] : 0.f;
    _Float16 hi = (_Float16)v;
    dst[(long)j * 1024 + k]       = hi;
    dst[(long)j * 1024 + 512 + k] = (_Float16)(v - (float)hi);
}

// ------------------------- embedding (cat-only out) ------------------------
__global__ __launch_bounds__(256)
void embed_k(const float* __restrict__ x, const float* __restrict__ mark,
             const float* __restrict__ valW, const float* __restrict__ timeW,
             _Float16* __restrict__ cat)
{
    const int lg = blockIdx.x, dh = blockIdx.y, b = blockIdx.z;
    const int tid = threadIdx.x;
    const int dd = dh * 256 + tid;
    const int l0 = lg * 8;
    __shared__ float xs[10][21];
    __shared__ float mk[8][4];
    if (tid < 210) {
        int r = tid / 21, c = tid % 21;
        int ll = (l0 - 1 + r + 512) & 511;
        xs[r][c] = x[((long)b * 512 + ll) * 21 + c];
    }
    if (tid >= 224 && tid < 256) {
        int t2 = tid - 224, il = t2 >> 2, m = t2 & 3;
        mk[il][m] = mark[((long)b * 512 + l0 + il) * 4 + m];
    }
    __syncthreads();
    float acc[8];
#pragma unroll
    for (int il = 0; il < 8; il++) acc[il] = 0.f;
    for (int t = 0; t < 3; t++)
        for (int c = 0; c < 21; c++) {
            float w = valW[(t * 21 + c) * 512 + dd];
#pragma unroll
            for (int il = 0; il < 8; il++)
                acc[il] = fmaf(xs[il + t][c], w, acc[il]);
        }
    for (int m = 0; m < 4; m++) {
        float w = timeW[m * 512 + dd];
#pragma unroll
        for (int il = 0; il < 8; il++)
            acc[il] = fmaf(mk[il][m], w, acc[il]);
    }
    const float freq = expf((float)(dd & ~1) * (-9.210340371976184f / 512.0f));
#pragma unroll
    for (int il = 0; il < 8; il++) {
        float ang = (float)(l0 + il) * freq;
        float pe = (dd & 1) ? cosf(ang) : sinf(ang);
        float v = acc[il] + pe;
        long row = (long)b * 512 + l0 + il;
        _Float16 hi = (_Float16)v;
        cat[row * 1024 + dd]       = hi;
        cat[row * 1024 + 512 + dd] = (_Float16)(v - (float)hi);
    }
}

// ------------------- windowed decomp (cat in/out) + mc-clean ---------------
template<int TREND>
__global__ __launch_bounds__(256)
void decompW_k(const _Float16* __restrict__ xc, _Float16* __restrict__ outc,
               _Float16* __restrict__ tsc, float* __restrict__ mcz, int nMc)
{
    long t = (long)blockIdx.x * 256 + threadIdx.x;
    if (t < nMc) mcz[t] = 0.f;
    long rowg = t >> 7; int d4 = (int)(t & 127) * 4;
    int lg = (int)(rowg & 63); long b = rowg >> 6;
    const int l0 = lg * 8;
    const _Float16* xb = xc + (b << 19);
    float s[8][4] = {};
    float xo[8][4];
#pragma unroll
    for (int rr = -12; rr <= 19; rr++) {
        int rc = l0 + rr; rc = rc < 0 ? 0 : (rc > 511 ? 511 : rc);
        h4 vh = *(const h4*)(xb + ((long)rc << 10) + d4);
        h4 vl = *(const h4*)(xb + ((long)rc << 10) + 512 + d4);
        float vv[4];
#pragma unroll
        for (int j = 0; j < 4; j++) vv[j] = (float)vh[j] + (float)vl[j];
#pragma unroll
        for (int i = 0; i < 8; i++) {
            if (i >= rr - 12 && i <= rr + 12) {
#pragma unroll
                for (int j = 0; j < 4; j++) s[i][j] += vv[j];
            }
        }
        if (rr >= 0 && rr < 8) {
#pragma unroll
            for (int j = 0; j < 4; j++) xo[rr][j] = vv[j];
        }
    }
#pragma unroll
    for (int i = 0; i < 8; i++) {
        long row = b * 512 + l0 + i;
        float tr[4], ov[4];
#pragma unroll
        for (int j = 0; j < 4; j++) {
            tr[j] = s[i][j] * (1.f / 25.f);
            ov[j] = xo[i][j] - tr[j];
        }
        h4 hi, lo;
#pragma unroll
        for (int j = 0; j < 4; j++) {
            _Float16 h = (_Float16)ov[j];
            hi[j] = h; lo[j] = (_Float16)(ov[j] - (float)h);
        }
        *(h4*)(outc + row * 1024 + d4)       = hi;
        *(h4*)(outc + row * 1024 + 512 + d4) = lo;
        if (TREND) {
            _Float16* tp = tsc + row * 1024 + d4;
            if (TREND == 1) {
                h4 th = *(h4*)tp, tl = *(h4*)(tp + 512);
#pragma unroll
                for (int j = 0; j < 4; j++) tr[j] += (float)th[j] + (float)tl[j];
            }
            h4 th2, tl2;
#pragma unroll
            for (int j = 0; j < 4; j++) {
                _Float16 h = (_Float16)tr[j];
                th2[j] = h; tl2[j] = (_Float16)(tr[j] - (float)h);
            }
            *(h4*)tp         = th2;
            *(h4*)(tp + 512) = tl2;
        }
    }
}

// ------------------------- prep (mean + zero mc) ---------------------------
__global__ __launch_bounds__(512)
void meanseq2_k(const float* __restrict__ x, float* __restrict__ xm,
                float* __restrict__ mcz)
{
    int b = blockIdx.x, tid = threadIdx.x;
    mcz[b * 512 + tid] = 0.f;
    __shared__ float sd[504];
    if (tid < 504) {
        int c = tid % 21, g = tid / 21;
        int l0 = g * 22, l1 = l0 + 22 > 512 ? 512 : l0 + 22;
        const float* xb = x + (long)b * 10752;
        float s = 0.f;
        for (int l = l0; l < l1; l++) s += xb[l * 21 + c];
        sd[tid] = s;
    }
    __syncthreads();
    if (tid < 21) {
        float t = 0.f;
#pragma unroll
        for (int g = 0; g < 24; g++) t += sd[g * 21 + tid];
        xm[b * 21 + tid] = t * (1.f / 512.f);
    }
}

__global__ void prep_k(const float* __restrict__ x, const float* __restrict__ xm,
                       float* __restrict__ sinit, float* __restrict__ tinit, int total)
{
    int i = blockIdx.x * 256 + threadIdx.x;
    if (i >= total) return;
    int c = i % 21, l = (i / 21) % 512, b = i / 10752;
    if (l < 256) {
        int lc = 256 + l;
        float s = 0.f;
        for (int j = -12; j <= 12; j++) {
            int ll = lc + j; ll = ll > 511 ? 511 : ll;
            s += x[((long)b * 512 + ll) * 21 + c];
        }
        float t = s * (1.f / 25.f);
        tinit[i] = t;
        sinit[i] = x[((long)b * 512 + lc) * 21 + c] - t;
    } else {
        sinit[i] = 0.f;
        tinit[i] = xm[b * 21 + c];
    }
}

// ------------------------- seasonal layernorm (cat in, f32 out) ------------
__global__ __launch_bounds__(256)
void ln_k(const _Float16* __restrict__ xc, const float* __restrict__ g,
          const float* __restrict__ be, float* __restrict__ out)
{
    int row = blockIdx.x, tid = threadIdx.x;
    const _Float16* xr = xc + ((long)row << 10);
    float v0 = (float)xr[tid]       + (float)xr[tid + 512];
    float v1 = (float)xr[tid + 256] + (float)xr[tid + 768];
    __shared__ float rs[256];
    rs[tid] = v0 + v1; __syncthreads();
    for (int s = 128; s > 0; s >>= 1) { if (tid < s) rs[tid] += rs[tid + s]; __syncthreads(); }
    float mu = rs[0] * (1.f / 512.f);
    __syncthreads();
    float d0 = v0 - mu, d1 = v1 - mu;
    rs[tid] = d0 * d0 + d1 * d1; __syncthreads();
    for (int s = 128; s > 0; s >>= 1) { if (tid < s) rs[tid] += rs[tid + s]; __syncthreads(); }
    float rstd = 1.0f / sqrtf(rs[0] * (1.f / 512.f) + 1e-5f);
    out[((long)row << 9) + tid]       = d0 * rstd * g[tid] + be[tid];
    out[((long)row << 9) + tid + 256] = d1 * rstd * g[tid + 256] + be[tid + 256];
}

// per-(b, 64-row chunk, d) partial column sums. grid (2, 8, Bc)
__global__ void colpart_k(const float* __restrict__ x, float* __restrict__ cp)
{
    int d = blockIdx.x * 256 + threadIdx.x;
    int ch = blockIdx.y, b = blockIdx.z;
    const float* xb = x + ((long)b << 18);
    float s = 0.f;
    for (int l = ch * 64; l < ch * 64 + 64; l++) s += xb[((long)l << 9) + d];
    cp[((long)(b * 8 + ch) << 9) + d] = s;
}

// cs[b][d] = mean over l (from 8 partials). grid (2, Bc)
__global__ void colmean_k(const float* __restrict__ cp, float* __restrict__ cs)
{
    int d = blockIdx.x * 256 + threadIdx.x;
    int b = blockIdx.y;
    float s = 0.f;
#pragma unroll
    for (int ch = 0; ch < 8; ch++) s += cp[((long)(b * 8 + ch) << 9) + d];
    cs[((long)b << 9) + d] = s * (1.f / 512.f);
}

// write hi/lo cat of (x - cs) — encoder tail
__global__ __launch_bounds__(256)
void subcolcat_k(const float* __restrict__ x, const float* __restrict__ cs,
                 _Float16* __restrict__ cat)
{
    long t = (long)blockIdx.x * 256 + threadIdx.x;
    long row = t >> 6; int d8 = (int)(t & 63) * 8;
    int b = (int)(row >> 9);
    const float4* c4 = (const float4*)(cs + ((long)b << 9) + d8);
    float4 m0 = c4[0], m1 = c4[1];
    float m[8] = {m0.x,m0.y,m0.z,m0.w,m1.x,m1.y,m1.z,m1.w};
    const float4* xp = (const float4*)(x + row * 512 + d8);
    float4 x0 = xp[0], x1 = xp[1];
    float v[8] = {x0.x,x0.y,x0.z,x0.w,x1.x,x1.y,x1.z,x1.w};
    h8 hi, lo;
#pragma unroll
    for (int j = 0; j < 8; j++) {
        float vv = v[j] - m[j];
        _Float16 h = (_Float16)vv;
        hi[j] = h; lo[j] = (_Float16)(vv - (float)h);
    }
    *(h8*)(cat + row * 1024 + d8)       = hi;
    *(h8*)(cat + row * 1024 + 512 + d8) = lo;
}

// proj with cs subtract + trend shift-add (decoder tail)
__global__ void proj_k(const float* __restrict__ x, const float* __restrict__ cs,
                       const float* __restrict__ pw, const float* __restrict__ pb,
                       const float* __restrict__ tinit, const float* __restrict__ H,
                       float* __restrict__ out, int total)
{
    int i = blockIdx.x * 256 + threadIdx.x;
    if (i >= total) return;
    int c = i % 21, l = (i / 21) % 256 + 256, b = i / 5376;
    const float* xr = x + ((long)(b * 512 + l) << 9);
    const float* csb = cs + ((long)b << 9);
    float s = 0.f;
    for (int d = 0; d < 512; d++)
        s = fmaf(xr[d] - csb[d], pw[d * 21 + c], s);
    long r = (long)b * 512;
    float trend = tinit[b * 10752 + l * 21 + c]
                + H[(r + ((l + 511) & 511)) * 128 + c]
                + H[(r + l) * 128 + 21 + c]
                + H[(r + ((l + 1) & 511)) * 128 + 42 + c];
    out[i] = s + pb[c] + trend;
}

// ---------------------------------------------------------------------------
// mode: 0 OUT1 plain-cat, 2 OUT1 gelu, 12 OUT1 +Rcat, 11 OUT0 f32, 20 Scorr
static void hgemm(int mode, int nph, float osc,
                  const _Float16* A, int lda, int loA,
                  const _Float16* B, int ldb, int loB,
                  const _Float16* Rc, void* C, int ldc, int loC,
                  int K, int M, int N, int batch,
                  long sA, long sB, long sC, hipStream_t st)
{
    dim3 g(N / 128, M / 128, batch), blk(256);
    switch (mode) {
    case 0:  hgemm_k<0,1><<<g,blk,0,st>>>(A,lda,loA,B,ldb,loB,Rc,C,ldc,loC,K,nph,osc,sA,sB,sC); break;
    case 2:  hgemm_k<2,1><<<g,blk,0,st>>>(A,lda,loA,B,ldb,loB,Rc,C,ldc,loC,K,nph,osc,sA,sB,sC); break;
    case 12: hgemm_k<1,1><<<g,blk,0,st>>>(A,lda,loA,B,ldb,loB,Rc,C,ldc,loC,K,nph,osc,sA,sB,sC); break;
    case 11: hgemm_k<0,0><<<g,blk,0,st>>>(A,lda,loA,B,ldb,loB,Rc,C,ldc,loC,K,nph,osc,sA,sB,sC); break;
    default: hgemm_k<0,2><<<g,blk,0,st>>>(A,lda,loA,B,ldb,loB,Rc,C,ldc,loC,K,nph,osc,sA,sB,sC); break;
    }
}

extern "C" void kernel_launch(void* const* d_in, const int* in_sizes, int n_in,
                              void* d_out, int out_size, void* d_ws, size_t ws_size,
                              hipStream_t stream)
{
    const float* x_enc    = (const float*)d_in[0];
    const float* xm_enc   = (const float*)d_in[1];
    const float* xm_dec   = (const float*)d_in[3];
    const float* enc_valW = (const float*)d_in[4];
    const float* enc_timeW= (const float*)d_in[5];
    const float* enc_Wq   = (const float*)d_in[6];
    const float* enc_Wk   = (const float*)d_in[7];
    const float* enc_Wv   = (const float*)d_in[8];
    const float* enc_Wo   = (const float*)d_in[9];
    const float* enc_W1   = (const float*)d_in[10];
    const float* enc_W2   = (const float*)d_in[11];
    const float* enc_g    = (const float*)d_in[12];
    const float* enc_b    = (const float*)d_in[13];
    const float* dec_valW = (const float*)d_in[14];
    const float* dec_timeW= (const float*)d_in[15];
    const float* sWq = (const float*)d_in[16];
    const float* sWk = (const float*)d_in[17];
    const float* sWv = (const float*)d_in[18];
    const float* sWo = (const float*)d_in[19];
    const float* cWq = (const float*)d_in[20];
    const float* cWk = (const float*)d_in[21];
    const float* cWv = (const float*)d_in[22];
    const float* cWo = (const float*)d_in[23];
    const float* dW1 = (const float*)d_in[24];
    const float* dW2 = (const float*)d_in[25];
    const float* dtW = (const float*)d_in[26];
    const float* dec_g = (const float*)d_in[27];
    const float* dec_b = (const float*)d_in[28];
    const float* projW = (const float*)d_in[29];
    const float* projB = (const float*)d_in[30];

    // ---- batch-chunk sizing (deterministic) ----
    const size_t W_BYTES = 50000000;
    const size_t perB = 8000000;
    int Bc = 32;
    while (Bc > 1 && W_BYTES + (size_t)Bc * perB + (4u << 20) > ws_size) Bc >>= 1;

    char* wp = (char*)d_ws;
    auto alloc = [&](size_t bytes) { char* p = wp; wp += (bytes + 255) & ~(size_t)255; return p; };

    _Float16* Wcat8  = (_Float16*)alloc(8 * 524288 * 2);
    _Float16* encW1C = (_Float16*)alloc(2 * 2097152 * 2);
    _Float16* encW2C = (_Float16*)alloc(2 * 2097152 * 2);
    _Float16* dW1C   = (_Float16*)alloc(2097152 * 2);
    _Float16* dW2C   = (_Float16*)alloc(2097152 * 2);
    _Float16* W63C   = (_Float16*)alloc(131072 * 2);
    _Float16* PA     = (_Float16*)alloc(8 * 524288 * 2);
    _Float16* PB     = (_Float16*)alloc(8 * 524288 * 2);

    const long ROWS = (long)Bc * 512;
    _Float16* cX     = (_Float16*)alloc(ROWS * 1024 * 2);
    _Float16* cO     = (_Float16*)alloc(ROWS * 1024 * 2);
    _Float16* TSc    = (_Float16*)alloc(ROWS * 1024 * 2);
    _Float16* ENCcat = (_Float16*)alloc(ROWS * 1024 * 2);
    _Float16* bigcat = (_Float16*)alloc(ROWS * 2048 * 2);
    float* F       = (float*)alloc(ROWS * 512 * 4);
    float* H       = (float*)alloc(ROWS * 128 * 4);
    float* sinit   = (float*)alloc((long)Bc * 10752 * 4);
    float* tinit   = (float*)alloc((long)Bc * 10752 * 4);
    float* xmean   = (float*)alloc((long)Bc * 21 * 4);
    float* mc      = (float*)alloc((long)Bc * 512 * 4);
    float* cp      = (float*)alloc((long)Bc * 4096 * 4);
    float* cs      = (float*)alloc((long)Bc * 512 * 4);

    // ---- weight setup ----
    dim3 cb(256);
    P12 sp;
    sp.p[0] = enc_Wk;  sp.p[1] = enc_Wk + 262144;
    sp.p[2] = sWk;     sp.p[3] = cWk;
    sp.p[4] = enc_Wq;  sp.p[5] = enc_Wq + 262144;
    sp.p[6] = sWq;     sp.p[7] = cWq;
    sp.p[8] = enc_Wv;  sp.p[9] = enc_Wv + 262144;
    sp.p[10] = sWv;    sp.p[11] = cWv;
    P4 op;
    op.p[0] = enc_Wo;  op.p[1] = enc_Wo + 262144;
    op.p[2] = sWo;     op.p[3] = cWo;
    P6 fp;
    fp.p[0] = enc_W1;  fp.p[1] = enc_W1 + 1048576; fp.p[2] = dW1;
    fp.p[3] = enc_W2;  fp.p[4] = enc_W2 + 1048576; fp.p[5] = dW2;
    splitAll_k <<<dim3(128,12), cb, 0, stream>>>(sp, PA, PB);
    convWoAll_k<<<dim3(16,16,4), cb, 0, stream>>>(op, PA);
    hgemm(0, 3, 1.f, PA,1024,512, PB,1024,512, nullptr, Wcat8, 1024, 512,
          512, 512, 512, 8, 524288, 524288, 524288, stream);
    convW2All_k<<<dim3(16,64,6), cb, 0, stream>>>(fp, encW1C, encW2C, dW1C, dW2C);
    convW63_k  <<<256, cb, 0, stream>>>(dtW, W63C);

    const int M = (int)ROWS;
    const int t21 = Bc * 10752;
    const int gRows = Bc * 128;
    const int gW = Bc * 32;
    const int nMc = Bc * 512;
    const long sCA = 512 * 1024;
    const float IOS = 1.f / 4096.f;

    auto attn = [&](const _Float16* cIn, _Float16* cOut,
                    const _Float16* KVcat, int slot) {
        const _Float16* WqkC_ = Wcat8 + (long)(2*slot)     * 524288;
        const _Float16* WvoC_ = Wcat8 + (long)(2*slot + 1) * 524288;
        hgemm(0, 3, 1.f, cIn,1024,512, WqkC_,1024,512, nullptr, bigcat, 1024, 512,
              512, M, 512, 1, 0,0,0, stream);                              // T cat
        hgemm(20, 3, 1.f, bigcat,1024,512, KVcat,1024,512, nullptr, mc, 0, 0,
              512, 512, 512, Bc, sCA, sCA, 512, stream);                   // diag
        hgemmAgg_k<<<dim3(4, M/128), 256, 0, stream>>>(KVcat, mc, WvoC_, cIn, cOut, IOS);
    };
    auto ffn = [&](const _Float16* cIn, _Float16* cOut,
                   const _Float16* W1C, const _Float16* W2C) {
        hgemm(2, 1, 1.f, cIn,1024,512, W1C,1024,512, nullptr, bigcat, 2048, -1,
              512, M, 2048, 1, 0,0,0, stream);
        hgemm(12, 1, 1.f, bigcat,2048,0, W2C,4096,2048, cIn, cOut, 1024, 512,
              2048, M, 512, 1, 0,0,0, stream);
    };

    for (int b0 = 0; b0 < 32; b0 += Bc) {
        const float* xe  = x_enc  + (long)b0 * 10752;
        const float* mke = xm_enc + (long)b0 * 2048;
        const float* mkd = xm_dec + (long)b0 * 2048;
        float* outp = (float*)d_out + (long)b0 * 5376;

        meanseq2_k<<<Bc, 512, 0, stream>>>(xe, xmean, mc);
        prep_k    <<<(t21 + 255)/256, 256, 0, stream>>>(xe, xmean, sinit, tinit, t21);

        // ---------------- encoder ----------------
        embed_k<<<dim3(64,2,Bc), 256, 0, stream>>>(xe, mke, enc_valW, enc_timeW, cX);
        for (int L = 0; L < 2; L++) {
            attn(cX, cO, cX, L);
            decompW_k<0><<<gW, 256, 0, stream>>>(cO, cX, nullptr, mc, nMc);
            ffn(cX, cO, encW1C + (long)L*2097152, encW2C + (long)L*2097152);
            decompW_k<0><<<gW, 256, 0, stream>>>(cO, cX, nullptr, mc, nMc);
        }
        ln_k       <<<Bc*512, 256, 0, stream>>>(cX, enc_g, enc_b, F);
        colpart_k  <<<dim3(2,8,Bc), 256, 0, stream>>>(F, cp);
        colmean_k  <<<dim3(2,Bc), 256, 0, stream>>>(cp, cs);
        subcolcat_k<<<gRows, 256, 0, stream>>>(F, cs, ENCcat);

        // ---------------- decoder ----------------
        embed_k<<<dim3(64,2,Bc), 256, 0, stream>>>(sinit, mkd, dec_valW, dec_timeW, cX);

        attn(cX, cO, cX, 2);                                         // self
        decompW_k<2><<<gW, 256, 0, stream>>>(cO, cX, TSc, mc, nMc);  // TSc = trend
        attn(cX, cO, ENCcat, 3);                                     // cross
        decompW_k<1><<<gW, 256, 0, stream>>>(cO, cX, TSc, mc, nMc);  // TSc += trend
        ffn(cX, cO, dW1C, dW2C);
        decompW_k<1><<<gW, 256, 0, stream>>>(cO, cX, TSc, mc, nMc);

        hgemm(11, 1, 1.f/64.f, TSc,1024,512, W63C,1024,512, nullptr, H, 128, 0,
              512, M, 128, 1, 0,0,0, stream);
        ln_k     <<<Bc*512, 256, 0, stream>>>(cX, dec_g, dec_b, F);
        colpart_k<<<dim3(2,8,Bc), 256, 0, stream>>>(F, cp);
        colmean_k<<<dim3(2,Bc), 256, 0, stream>>>(cp, cs);
        proj_k   <<<(Bc*5376+255)/256, 256, 0, stream>>>(F, cs, projW, projB,
                                                         tinit, H, outp, Bc*5376);
    }
}

// Round 17
// 1893.564 us; speedup vs baseline: 1.2572x; 1.0949x over previous
//
#include <hip/hip_runtime.h>

// ---------------------------------------------------------------------------
// Autoformer forward, MI355X. Round 17: round-16 + BN=64 tile variant for
// skinny (N<=512) GEMMs (2x block count, better latency hiding). Numerics
// bit-identical. GEMM: C = Ah*Bh [+ Ah*Bl [+ Al*Bh]], rows x 2K f16 [hi|lo].
// ---------------------------------------------------------------------------

typedef _Float16 h8 __attribute__((ext_vector_type(8)));
typedef _Float16 h4 __attribute__((ext_vector_type(4)));
typedef float f32x4 __attribute__((ext_vector_type(4)));

struct P12 { const float* p[12]; };
struct P6  { const float* p[6]; };
struct P4  { const float* p[4]; };

__device__ __forceinline__ float gelu_f(float x){
    return 0.5f * x * (1.0f + erff(x * 0.70710678118654752f));
}

__device__ __forceinline__ void gl_lds(const _Float16* gp, _Float16* lp) {
    __builtin_amdgcn_global_load_lds(
        (const __attribute__((address_space(1))) void*)gp,
        (__attribute__((address_space(3))) void*)lp, 16, 0, 0);
}

// bijective chunked XCD swizzle (m204)
__device__ __forceinline__ int xcd_swz(int lin, int nwg) {
    const int q = nwg >> 3, r = nwg & 7;
    const int xcd = lin & 7, idx = lin >> 3;
    return (xcd < r) ? xcd * (q + 1) + idx
                     : r * (q + 1) + (xcd - r) * q + idx;
}

// ------------------------------ MFMA GEMM ----------------------------------
// Tile 128 x BN (BN in {64,128}), BK=64, 256 thr (4 waves 2x2).
// A: M x 2K [hi|lo] (lda halfs, lo at +loA). B: N x 2K (ldb, +loB).
// nph phases x (K/64): (Ah,Bh)[,(Ah,Bl)[,(Al,Bh)]]. f32 accum, *osc epilogue.
// OUT=0: f32 C. OUT=1: f16 cat C (loC<0 -> hi only); EPI 0 plain/1 +Rcat/2 gelu.
// OUT=2: diag reduce: atomicAdd mc[bz*sC + (row-col)&511].
template<int EPI, int OUT, int BN>
__global__ __launch_bounds__(256)
void hgemm_k(const _Float16* __restrict__ A, int lda, int loA,
             const _Float16* __restrict__ Bm, int ldb, int loB,
             const _Float16* __restrict__ Rc, void* __restrict__ Cv,
             int ldc, int loC, int K, int nph, float osc,
             long sA, long sB, long sC)
{
    constexpr int NN = BN / 32;            // n-fragments per wave
    __shared__ _Float16 As[128 * 64];
    __shared__ _Float16 Bs[BN * 64];
    const int gx = gridDim.x, gy = gridDim.y;
    int lin = blockIdx.x + gx * (blockIdx.y + gy * blockIdx.z);
    lin = xcd_swz(lin, gx * gy * gridDim.z);
    const int bxi = lin % gx; lin /= gx;
    const int byi = lin % gy;
    const int bz  = lin / gy;
    const int tid = threadIdx.x, lane = tid & 63, w = tid >> 6;
    const int wr = w >> 1, wc = w & 1;
    const _Float16* Ap = A + bz * sA + (long)(byi * 128) * lda;
    const _Float16* Bp = Bm + bz * sB + (long)(bxi * BN) * ldb;

    const int swz = ((lane & 7) ^ ((lane >> 3) & 7)) * 8;
    const int rsubA = w * 32 + (lane >> 3);
    const int rsubB = w * (BN / 4) + (lane >> 3);
    const _Float16* ApT = Ap + (long)rsubA * lda + swz;
    const _Float16* BpT = Bp + (long)rsubB * ldb + swz;
    _Float16* AsT = As + w * 2048;
    _Float16* BsT = Bs + w * (BN * 16);

    const int tpp = K >> 6;
    const int nkt = tpp * nph;
    f32x4 acc[4][NN] = {};

    int p = 0, q = 0;
    for (int kt = 0; kt < nkt; ++kt) {
        const int aoff = q * 64 + (p == 2 ? loA : 0);
        const int boff = q * 64 + (p == 1 ? loB : 0);
        __syncthreads();
#pragma unroll
        for (int i = 0; i < 4; i++)
            gl_lds(ApT + (long)i * 8 * lda + aoff, AsT + i * 512);
#pragma unroll
        for (int i = 0; i < BN / 32; i++)
            gl_lds(BpT + (long)i * 8 * ldb + boff, BsT + i * 512);
        __syncthreads();
#pragma unroll
        for (int kk = 0; kk < 2; ++kk) {
            h8 af[4], bf[NN];
            const int ks = kk * 4 + (lane >> 4);
#pragma unroll
            for (int m = 0; m < 4; m++) {
                int rowa = wr * 64 + m * 16 + (lane & 15);
                af[m] = *(const h8*)(As + rowa * 64 + ((ks ^ (rowa & 7)) * 8));
            }
#pragma unroll
            for (int n = 0; n < NN; n++) {
                int rowb = wc * (BN / 2) + n * 16 + (lane & 15);
                bf[n] = *(const h8*)(Bs + rowb * 64 + ((ks ^ (rowb & 7)) * 8));
            }
#pragma unroll
            for (int m = 0; m < 4; m++)
#pragma unroll
                for (int n = 0; n < NN; n++)
                    acc[m][n] = __builtin_amdgcn_mfma_f32_16x16x32_f16(af[m], bf[n], acc[m][n], 0, 0, 0);
        }
        if (++q == tpp) { q = 0; ++p; }
    }

    const int crow0 = byi * 128 + wr * 64 + (lane >> 4) * 4;
    const int ccol0 = bxi * BN + wc * (BN / 2) + (lane & 15);
    if constexpr (OUT == 0) {
        float* Cp = (float*)Cv + (long)bz * sC;
#pragma unroll
        for (int m = 0; m < 4; m++)
#pragma unroll
            for (int n = 0; n < NN; n++) {
                int col = ccol0 + n * 16;
#pragma unroll
                for (int r2 = 0; r2 < 4; r2++) {
                    long idx = (long)(crow0 + m * 16 + r2) * ldc + col;
                    Cp[idx] = acc[m][n][r2] * osc;
                }
            }
    } else if constexpr (OUT == 1) {
        _Float16* Cp = (_Float16*)Cv + (long)bz * sC;
#pragma unroll
        for (int m = 0; m < 4; m++)
#pragma unroll
            for (int n = 0; n < NN; n++) {
                int col = ccol0 + n * 16;
#pragma unroll
                for (int r2 = 0; r2 < 4; r2++) {
                    int row = crow0 + m * 16 + r2;
                    long base = (long)row * ldc + col;
                    float v = acc[m][n][r2] * osc;
                    if (EPI == 1) {
                        long rb = (long)row * 1024 + col;
                        v += (float)Rc[rb] + (float)Rc[rb + 512];
                    }
                    if (EPI == 2) v = gelu_f(v);
                    _Float16 hi = (_Float16)v;
                    Cp[base] = hi;
                    if (loC >= 0) Cp[base + loC] = (_Float16)(v - (float)hi);
                }
            }
    } else {
        __shared__ float diag[512];
        float* mc = (float*)Cv + (long)bz * sC;
        for (int t = tid; t < 512; t += 256) diag[t] = 0.f;
        __syncthreads();
#pragma unroll
        for (int m = 0; m < 4; m++)
#pragma unroll
            for (int n = 0; n < NN; n++) {
                int col = ccol0 + n * 16;
#pragma unroll
                for (int r2 = 0; r2 < 4; r2++) {
                    int row = crow0 + m * 16 + r2;
                    atomicAdd(&diag[(row - col) & 511], acc[m][n][r2]);
                }
            }
        __syncthreads();
        for (int t = tid; t < 512; t += 256) {
            float v = diag[t];
            if (v != 0.f) atomicAdd(&mc[t], v);
        }
    }
}

// --------------- Wvo GEMM with fused top-k + agg gather --------------------
__global__ __launch_bounds__(256)
void hgemmAgg_k(const _Float16* __restrict__ KV, const float* __restrict__ mc,
                const _Float16* __restrict__ Bm,
                const _Float16* __restrict__ Rc, _Float16* __restrict__ Cp,
                float osc)
{
    __shared__ _Float16 As[128 * 64];
    __shared__ _Float16 Bs[128 * 64];
    const int gx = gridDim.x;
    int lin = blockIdx.x + gx * blockIdx.y;
    lin = xcd_swz(lin, gx * gridDim.y);
    const int bxi = lin % gx;
    const int byi = lin / gx;
    const int tid = threadIdx.x, lane = tid & 63, w = tid >> 6;
    const int wr = w >> 1, wc = w & 1;
    const int rowblk = byi * 128;
    const int b = rowblk >> 9;

    int dl[6]; float wv[6];
    {
        float* v  = (float*)As;
        float* rv = (float*)As + 512;
        int*   ri = (int*)Bs;
        const float SCL = 1.f / (512.f * 4096.f);
        v[tid]       = mc[b * 512 + tid]       * SCL;
        v[tid + 256] = mc[b * 512 + tid + 256] * SCL;
        __syncthreads();
        float sv[6];
        for (int p = 0; p < 6; p++) {
            float bv = v[tid]; int bi = tid;
            float v2 = v[tid + 256];
            if (v2 > bv) { bv = v2; bi = tid + 256; }
            rv[tid] = bv; ri[tid] = bi;
            __syncthreads();
            for (int s = 128; s > 0; s >>= 1) {
                if (tid < s) {
                    float ov = rv[tid + s]; int oi = ri[tid + s];
                    if (ov > rv[tid] || (ov == rv[tid] && oi < ri[tid])) {
                        rv[tid] = ov; ri[tid] = oi;
                    }
                }
                __syncthreads();
            }
            sv[p] = rv[0]; dl[p] = ri[0];
            __syncthreads();
            if (tid == 0) v[ri[0]] = -3.4e38f;
            __syncthreads();
        }
        float mx = sv[0];
        for (int p = 1; p < 6; p++) mx = fmaxf(mx, sv[p]);
        float e[6], sum = 0.f;
        for (int p = 0; p < 6; p++) { e[p] = expf(sv[p] - mx); sum += e[p]; }
        for (int p = 0; p < 6; p++) wv[p] = e[p] / sum;
    }

    const _Float16* Bp = Bm + (long)(bxi * 128) * 1024;
    const int swz = ((lane & 7) ^ ((lane >> 3) & 7)) * 8;
    const int rsub = w * 32 + (lane >> 3);
    const _Float16* BpT = Bp + (long)rsub * 1024 + swz;
    _Float16* BsT = Bs + w * 2048;
    const _Float16* KVb = KV + ((long)b << 19);

    f32x4 acc[4][4] = {};
    for (int q = 0; q < 8; ++q) {
        const int coff = q * 64 + swz;
        __syncthreads();
#pragma unroll
        for (int i = 0; i < 4; i++) {
            int l = (rowblk + rsub + i * 8) & 511;
            float s8[8] = {};
#pragma unroll
            for (int k = 0; k < 6; k++) {
                const h8 v = *(const h8*)(KVb + ((long)((l + dl[k]) & 511) << 10) + coff);
#pragma unroll
                for (int j = 0; j < 8; j++) s8[j] = fmaf(wv[k], (float)v[j], s8[j]);
            }
            h8 hv;
#pragma unroll
            for (int j = 0; j < 8; j++) hv[j] = (_Float16)s8[j];
            *(h8*)(As + w * 2048 + i * 512 + lane * 8) = hv;
            gl_lds(BpT + (long)i * 8 * 1024 + q * 64, BsT + i * 512);
        }
        __syncthreads();
#pragma unroll
        for (int kk = 0; kk < 2; ++kk) {
            h8 af[4], bf[4];
            const int ks = kk * 4 + (lane >> 4);
#pragma unroll
            for (int m = 0; m < 4; m++) {
                int rowa = wr * 64 + m * 16 + (lane & 15);
                af[m] = *(const h8*)(As + rowa * 64 + ((ks ^ (rowa & 7)) * 8));
                int rowb = wc * 64 + m * 16 + (lane & 15);
                bf[m] = *(const h8*)(Bs + rowb * 64 + ((ks ^ (rowb & 7)) * 8));
            }
#pragma unroll
            for (int m = 0; m < 4; m++)
#pragma unroll
                for (int n = 0; n < 4; n++)
                    acc[m][n] = __builtin_amdgcn_mfma_f32_16x16x32_f16(af[m], bf[n], acc[m][n], 0, 0, 0);
        }
    }

    const int crow0 = rowblk + wr * 64 + (lane >> 4) * 4;
    const int ccol0 = bxi * 128 + wc * 64 + (lane & 15);
#pragma unroll
    for (int m = 0; m < 4; m++)
#pragma unroll
        for (int n = 0; n < 4; n++) {
            int col = ccol0 + n * 16;
#pragma unroll
            for (int r2 = 0; r2 < 4; r2++) {
                int row = crow0 + m * 16 + r2;
                long rb = (long)row * 1024 + col;
                float v = acc[m][n][r2] * osc + (float)Rc[rb] + (float)Rc[rb + 512];
                _Float16 hi = (_Float16)v;
                Cp[rb] = hi;
                Cp[rb + 512] = (_Float16)(v - (float)hi);
            }
        }
}

// ------------------------- weight conversion -------------------------------
__global__ __launch_bounds__(256)
void splitAll_k(P12 ps, _Float16* __restrict__ PA, _Float16* __restrict__ PB)
{
    const int m = blockIdx.y;
    const float* __restrict__ src = ps.p[m];
    _Float16* dst;
    if (m < 4)      dst = PA + (long)(2 * m) * 524288;
    else if (m < 8) dst = PB + (long)(2 * (m - 4)) * 524288;
    else            dst = PB + (long)(2 * (m - 8) + 1) * 524288;
    long t = (long)blockIdx.x * 256 + threadIdx.x;
    long row = t >> 6; int kc = (int)(t & 63) * 8;
    const float4 v0 = *(const float4*)(src + row * 512 + kc);
    const float4 v1 = *(const float4*)(src + row * 512 + kc + 4);
    float vv[8] = {v0.x,v0.y,v0.z,v0.w,v1.x,v1.y,v1.z,v1.w};
    h8 hi, lo;
#pragma unroll
    for (int j = 0; j < 8; j++) {
        float s = vv[j] * 64.f;
        _Float16 h = (_Float16)s;
        hi[j] = h; lo[j] = (_Float16)(s - (float)h);
    }
    *(h8*)(dst + row * 1024 + kc)       = hi;
    *(h8*)(dst + row * 1024 + 512 + kc) = lo;
}

__global__ __launch_bounds__(256)
void convWoAll_k(P4 ps, _Float16* __restrict__ PA)
{
    const int z = blockIdx.z;
    const float* __restrict__ src = ps.p[z];
    _Float16* dst = PA + (long)(2 * z + 1) * 524288;
    __shared__ float t[32][33];
    int k0 = blockIdx.x * 32, n0 = blockIdx.y * 32, tid = threadIdx.x;
#pragma unroll
    for (int i = 0; i < 4; i++) {
        int lin = tid + i * 256; int r = lin >> 5, c = lin & 31;
        t[r][c] = src[(long)(k0 + r) * 512 + n0 + c];
    }
    __syncthreads();
#pragma unroll
    for (int i = 0; i < 4; i++) {
        int lin = tid + i * 256; int n = lin >> 5, k = lin & 31;
        float v = t[k][n] * 64.f;
        _Float16 hi = (_Float16)v;
        long base = (long)(n0 + n) * 1024 + k0 + k;
        dst[base]       = hi;
        dst[base + 512] = (_Float16)(v - (float)hi);
    }
}

__global__ __launch_bounds__(256)
void convW2All_k(P6 ps, _Float16* __restrict__ encW1C, _Float16* __restrict__ encW2C,
                 _Float16* __restrict__ dW1C, _Float16* __restrict__ dW2C)
{
    const int z = blockIdx.z;
    const float* __restrict__ src = ps.p[z];
    _Float16* dst = (z==0) ? encW1C : (z==1) ? encW1C + 2097152 : (z==2) ? dW1C :
                    (z==3) ? encW2C : (z==4) ? encW2C + 2097152 : dW2C;
    const bool isW1 = z < 3;
    const int N = isW1 ? 2048 : 512;
    const int K = isW1 ? 512 : 2048;
    int k0 = (isW1 ? blockIdx.x : blockIdx.y) * 32;
    int n0 = (isW1 ? blockIdx.y : blockIdx.x) * 32;
    __shared__ float t[32][33];
    int tid = threadIdx.x;
#pragma unroll
    for (int i = 0; i < 4; i++) {
        int lin = tid + i * 256; int r = lin >> 5, c = lin & 31;
        t[r][c] = src[(long)(k0 + r) * N + n0 + c];
    }
    __syncthreads();
#pragma unroll
    for (int i = 0; i < 4; i++) {
        int lin = tid + i * 256; int n = lin >> 5, k = lin & 31;
        float v = t[k][n];
        _Float16 hi = (_Float16)v;
        long base = (long)(n0 + n) * 2 * K + k0 + k;
        dst[base]     = hi;
        dst[base + K] = (_Float16)(v - (float)hi);
    }
}

__global__ void convW63_k(const float* __restrict__ W, _Float16* __restrict__ dst)
{
    int i = blockIdx.x * 256 + threadIdx.x;
    int k = i & 511, j = i >> 9;
    float v = (j < 63) ? 64.f * W[(long)(j / 21) * 10752 + (long)k * 21 + (j % 21)] : 0.f;
    _Float16 hi = (_Float16)v;
    dst[(long)j * 1024 + k]       = hi;
    dst[(long)j * 1024 + 512 + k] = (_Float16)(v - (float)hi);
}

// ------------------------- embedding (cat-only out) ------------------------
__global__ __launch_bounds__(256)
void embed_k(const float* __restrict__ x, const float* __restrict__ mark,
             const float* __restrict__ valW, const float* __restrict__ timeW,
             _Float16* __restrict__ cat)
{
    const int lg = blockIdx.x, dh = blockIdx.y, b = blockIdx.z;
    const int tid = threadIdx.x;
    const int dd = dh * 256 + tid;
    const int l0 = lg * 8;
    __shared__ float xs[10][21];
    __shared__ float mk[8][4];
    if (tid < 210) {
        int r = tid / 21, c = tid % 21;
        int ll = (l0 - 1 + r + 512) & 511;
        xs[r][c] = x[((long)b * 512 + ll) * 21 + c];
    }
    if (tid >= 224 && tid < 256) {
        int t2 = tid - 224, il = t2 >> 2, m = t2 & 3;
        mk[il][m] = mark[((long)b * 512 + l0 + il) * 4 + m];
    }
    __syncthreads();
    float acc[8];
#pragma unroll
    for (int il = 0; il < 8; il++) acc[il] = 0.f;
    for (int t = 0; t < 3; t++)
        for (int c = 0; c < 21; c++) {
            float w = valW[(t * 21 + c) * 512 + dd];
#pragma unroll
            for (int il = 0; il < 8; il++)
                acc[il] = fmaf(xs[il + t][c], w, acc[il]);
        }
    for (int m = 0; m < 4; m++) {
        float w = timeW[m * 512 + dd];
#pragma unroll
        for (int il = 0; il < 8; il++)
            acc[il] = fmaf(mk[il][m], w, acc[il]);
    }
    const float freq = expf((float)(dd & ~1) * (-9.210340371976184f / 512.0f));
#pragma unroll
    for (int il = 0; il < 8; il++) {
        float ang = (float)(l0 + il) * freq;
        float pe = (dd & 1) ? cosf(ang) : sinf(ang);
        float v = acc[il] + pe;
        long row = (long)b * 512 + l0 + il;
        _Float16 hi = (_Float16)v;
        cat[row * 1024 + dd]       = hi;
        cat[row * 1024 + 512 + dd] = (_Float16)(v - (float)hi);
    }
}

// ------------------- windowed decomp (cat in/out) + mc-clean ---------------
template<int TREND>
__global__ __launch_bounds__(256)
void decompW_k(const _Float16* __restrict__ xc, _Float16* __restrict__ outc,
               _Float16* __restrict__ tsc, float* __restrict__ mcz, int nMc)
{
    long t = (long)blockIdx.x * 256 + threadIdx.x;
    if (t < nMc) mcz[t] = 0.f;
    long rowg = t >> 7; int d4 = (int)(t & 127) * 4;
    int lg = (int)(rowg & 63); long b = rowg >> 6;
    const int l0 = lg * 8;
    const _Float16* xb = xc + (b << 19);
    float s[8][4] = {};
    float xo[8][4];
#pragma unroll
    for (int rr = -12; rr <= 19; rr++) {
        int rc = l0 + rr; rc = rc < 0 ? 0 : (rc > 511 ? 511 : rc);
        h4 vh = *(const h4*)(xb + ((long)rc << 10) + d4);
        h4 vl = *(const h4*)(xb + ((long)rc << 10) + 512 + d4);
        float vv[4];
#pragma unroll
        for (int j = 0; j < 4; j++) vv[j] = (float)vh[j] + (float)vl[j];
#pragma unroll
        for (int i = 0; i < 8; i++) {
            if (i >= rr - 12 && i <= rr + 12) {
#pragma unroll
                for (int j = 0; j < 4; j++) s[i][j] += vv[j];
            }
        }
        if (rr >= 0 && rr < 8) {
#pragma unroll
            for (int j = 0; j < 4; j++) xo[rr][j] = vv[j];
        }
    }
#pragma unroll
    for (int i = 0; i < 8; i++) {
        long row = b * 512 + l0 + i;
        float tr[4], ov[4];
#pragma unroll
        for (int j = 0; j < 4; j++) {
            tr[j] = s[i][j] * (1.f / 25.f);
            ov[j] = xo[i][j] - tr[j];
        }
        h4 hi, lo;
#pragma unroll
        for (int j = 0; j < 4; j++) {
            _Float16 h = (_Float16)ov[j];
            hi[j] = h; lo[j] = (_Float16)(ov[j] - (float)h);
        }
        *(h4*)(outc + row * 1024 + d4)       = hi;
        *(h4*)(outc + row * 1024 + 512 + d4) = lo;
        if (TREND) {
            _Float16* tp = tsc + row * 1024 + d4;
            if (TREND == 1) {
                h4 th = *(h4*)tp, tl = *(h4*)(tp + 512);
#pragma unroll
                for (int j = 0; j < 4; j++) tr[j] += (float)th[j] + (float)tl[j];
            }
            h4 th2, tl2;
#pragma unroll
            for (int j = 0; j < 4; j++) {
                _Float16 h = (_Float16)tr[j];
                th2[j] = h; tl2[j] = (_Float16)(tr[j] - (float)h);
            }
            *(h4*)tp         = th2;
            *(h4*)(tp + 512) = tl2;
        }
    }
}

// ------------------------- prep (mean + zero mc) ---------------------------
__global__ __launch_bounds__(512)
void meanseq2_k(const float* __restrict__ x, float* __restrict__ xm,
                float* __restrict__ mcz)
{
    int b = blockIdx.x, tid = threadIdx.x;
    mcz[b * 512 + tid] = 0.f;
    __shared__ float sd[504];
    if (tid < 504) {
        int c = tid % 21, g = tid / 21;
        int l0 = g * 22, l1 = l0 + 22 > 512 ? 512 : l0 + 22;
        const float* xb = x + (long)b * 10752;
        float s = 0.f;
        for (int l = l0; l < l1; l++) s += xb[l * 21 + c];
        sd[tid] = s;
    }
    __syncthreads();
    if (tid < 21) {
        float t = 0.f;
#pragma unroll
        for (int g = 0; g < 24; g++) t += sd[g * 21 + tid];
        xm[b * 21 + tid] = t * (1.f / 512.f);
    }
}

__global__ void prep_k(const float* __restrict__ x, const float* __restrict__ xm,
                       float* __restrict__ sinit, float* __restrict__ tinit, int total)
{
    int i = blockIdx.x * 256 + threadIdx.x;
    if (i >= total) return;
    int c = i % 21, l = (i / 21) % 512, b = i / 10752;
    if (l < 256) {
        int lc = 256 + l;
        float s = 0.f;
        for (int j = -12; j <= 12; j++) {
            int ll = lc + j; ll = ll > 511 ? 511 : ll;
            s += x[((long)b * 512 + ll) * 21 + c];
        }
        float t = s * (1.f / 25.f);
        tinit[i] = t;
        sinit[i] = x[((long)b * 512 + lc) * 21 + c] - t;
    } else {
        sinit[i] = 0.f;
        tinit[i] = xm[b * 21 + c];
    }
}

// ------------------------- seasonal layernorm (cat in, f32 out) ------------
__global__ __launch_bounds__(256)
void ln_k(const _Float16* __restrict__ xc, const float* __restrict__ g,
          const float* __restrict__ be, float* __restrict__ out)
{
    int row = blockIdx.x, tid = threadIdx.x;
    const _Float16* xr = xc + ((long)row << 10);
    float v0 = (float)xr[tid]       + (float)xr[tid + 512];
    float v1 = (float)xr[tid + 256] + (float)xr[tid + 768];
    __shared__ float rs[256];
    rs[tid] = v0 + v1; __syncthreads();
    for (int s = 128; s > 0; s >>= 1) { if (tid < s) rs[tid] += rs[tid + s]; __syncthreads(); }
    float mu = rs[0] * (1.f / 512.f);
    __syncthreads();
    float d0 = v0 - mu, d1 = v1 - mu;
    rs[tid] = d0 * d0 + d1 * d1; __syncthreads();
    for (int s = 128; s > 0; s >>= 1) { if (tid < s) rs[tid] += rs[tid + s]; __syncthreads(); }
    float rstd = 1.0f / sqrtf(rs[0] * (1.f / 512.f) + 1e-5f);
    out[((long)row << 9) + tid]       = d0 * rstd * g[tid] + be[tid];
    out[((long)row << 9) + tid + 256] = d1 * rstd * g[tid + 256] + be[tid + 256];
}

// per-(b, 64-row chunk, d) partial column sums. grid (2, 8, Bc)
__global__ void colpart_k(const float* __restrict__ x, float* __restrict__ cp)
{
    int d = blockIdx.x * 256 + threadIdx.x;
    int ch = blockIdx.y, b = blockIdx.z;
    const float* xb = x + ((long)b << 18);
    float s = 0.f;
    for (int l = ch * 64; l < ch * 64 + 64; l++) s += xb[((long)l << 9) + d];
    cp[((long)(b * 8 + ch) << 9) + d] = s;
}

// cs[b][d] = mean over l (from 8 partials). grid (2, Bc)
__global__ void colmean_k(const float* __restrict__ cp, float* __restrict__ cs)
{
    int d = blockIdx.x * 256 + threadIdx.x;
    int b = blockIdx.y;
    float s = 0.f;
#pragma unroll
    for (int ch = 0; ch < 8; ch++) s += cp[((long)(b * 8 + ch) << 9) + d];
    cs[((long)b << 9) + d] = s * (1.f / 512.f);
}

// write hi/lo cat of (x - cs) — encoder tail
__global__ __launch_bounds__(256)
void subcolcat_k(const float* __restrict__ x, const float* __restrict__ cs,
                 _Float16* __restrict__ cat)
{
    long t = (long)blockIdx.x * 256 + threadIdx.x;
    long row = t >> 6; int d8 = (int)(t & 63) * 8;
    int b = (int)(row >> 9);
    const float4* c4 = (const float4*)(cs + ((long)b << 9) + d8);
    float4 m0 = c4[0], m1 = c4[1];
    float m[8] = {m0.x,m0.y,m0.z,m0.w,m1.x,m1.y,m1.z,m1.w};
    const float4* xp = (const float4*)(x + row * 512 + d8);
    float4 x0 = xp[0], x1 = xp[1];
    float v[8] = {x0.x,x0.y,x0.z,x0.w,x1.x,x1.y,x1.z,x1.w};
    h8 hi, lo;
#pragma unroll
    for (int j = 0; j < 8; j++) {
        float vv = v[j] - m[j];
        _Float16 h = (_Float16)vv;
        hi[j] = h; lo[j] = (_Float16)(vv - (float)h);
    }
    *(h8*)(cat + row * 1024 + d8)       = hi;
    *(h8*)(cat + row * 1024 + 512 + d8) = lo;
}

// proj with cs subtract + trend shift-add (decoder tail)
__global__ void proj_k(const float* __restrict__ x, const float* __restrict__ cs,
                       const float* __restrict__ pw, const float* __restrict__ pb,
                       const float* __restrict__ tinit, const float* __restrict__ H,
                       float* __restrict__ out, int total)
{
    int i = blockIdx.x * 256 + threadIdx.x;
    if (i >= total) return;
    int c = i % 21, l = (i / 21) % 256 + 256, b = i / 5376;
    const float* xr = x + ((long)(b * 512 + l) << 9);
    const float* csb = cs + ((long)b << 9);
    float s = 0.f;
    for (int d = 0; d < 512; d++)
        s = fmaf(xr[d] - csb[d], pw[d * 21 + c], s);
    long r = (long)b * 512;
    float trend = tinit[b * 10752 + l * 21 + c]
                + H[(r + ((l + 511) & 511)) * 128 + c]
                + H[(r + l) * 128 + 21 + c]
                + H[(r + ((l + 1) & 511)) * 128 + 42 + c];
    out[i] = s + pb[c] + trend;
}

// ---------------------------------------------------------------------------
// mode: 0 OUT1 plain-cat, 2 OUT1 gelu, 12 OUT1 +Rcat, 11 OUT0 f32, 20 Scorr
static void hgemm(int mode, int bn, int nph, float osc,
                  const _Float16* A, int lda, int loA,
                  const _Float16* B, int ldb, int loB,
                  const _Float16* Rc, void* C, int ldc, int loC,
                  int K, int M, int N, int batch,
                  long sA, long sB, long sC, hipStream_t st)
{
    dim3 g(N / bn, M / 128, batch), blk(256);
    if (bn == 64) {
        switch (mode) {
        case 0:  hgemm_k<0,1,64><<<g,blk,0,st>>>(A,lda,loA,B,ldb,loB,Rc,C,ldc,loC,K,nph,osc,sA,sB,sC); break;
        case 2:  hgemm_k<2,1,64><<<g,blk,0,st>>>(A,lda,loA,B,ldb,loB,Rc,C,ldc,loC,K,nph,osc,sA,sB,sC); break;
        case 12: hgemm_k<1,1,64><<<g,blk,0,st>>>(A,lda,loA,B,ldb,loB,Rc,C,ldc,loC,K,nph,osc,sA,sB,sC); break;
        case 11: hgemm_k<0,0,64><<<g,blk,0,st>>>(A,lda,loA,B,ldb,loB,Rc,C,ldc,loC,K,nph,osc,sA,sB,sC); break;
        default: hgemm_k<0,2,64><<<g,blk,0,st>>>(A,lda,loA,B,ldb,loB,Rc,C,ldc,loC,K,nph,osc,sA,sB,sC); break;
        }
    } else {
        switch (mode) {
        case 0:  hgemm_k<0,1,128><<<g,blk,0,st>>>(A,lda,loA,B,ldb,loB,Rc,C,ldc,loC,K,nph,osc,sA,sB,sC); break;
        case 2:  hgemm_k<2,1,128><<<g,blk,0,st>>>(A,lda,loA,B,ldb,loB,Rc,C,ldc,loC,K,nph,osc,sA,sB,sC); break;
        case 12: hgemm_k<1,1,128><<<g,blk,0,st>>>(A,lda,loA,B,ldb,loB,Rc,C,ldc,loC,K,nph,osc,sA,sB,sC); break;
        case 11: hgemm_k<0,0,128><<<g,blk,0,st>>>(A,lda,loA,B,ldb,loB,Rc,C,ldc,loC,K,nph,osc,sA,sB,sC); break;
        default: hgemm_k<0,2,128><<<g,blk,0,st>>>(A,lda,loA,B,ldb,loB,Rc,C,ldc,loC,K,nph,osc,sA,sB,sC); break;
        }
    }
}

extern "C" void kernel_launch(void* const* d_in, const int* in_sizes, int n_in,
                              void* d_out, int out_size, void* d_ws, size_t ws_size,
                              hipStream_t stream)
{
    const float* x_enc    = (const float*)d_in[0];
    const float* xm_enc   = (const float*)d_in[1];
    const float* xm_dec   = (const float*)d_in[3];
    const float* enc_valW = (const float*)d_in[4];
    const float* enc_timeW= (const float*)d_in[5];
    const float* enc_Wq   = (const float*)d_in[6];
    const float* enc_Wk   = (const float*)d_in[7];
    const float* enc_Wv   = (const float*)d_in[8];
    const float* enc_Wo   = (const float*)d_in[9];
    const float* enc_W1   = (const float*)d_in[10];
    const float* enc_W2   = (const float*)d_in[11];
    const float* enc_g    = (const float*)d_in[12];
    const float* enc_b    = (const float*)d_in[13];
    const float* dec_valW = (const float*)d_in[14];
    const float* dec_timeW= (const float*)d_in[15];
    const float* sWq = (const float*)d_in[16];
    const float* sWk = (const float*)d_in[17];
    const float* sWv = (const float*)d_in[18];
    const float* sWo = (const float*)d_in[19];
    const float* cWq = (const float*)d_in[20];
    const float* cWk = (const float*)d_in[21];
    const float* cWv = (const float*)d_in[22];
    const float* cWo = (const float*)d_in[23];
    const float* dW1 = (const float*)d_in[24];
    const float* dW2 = (const float*)d_in[25];
    const float* dtW = (const float*)d_in[26];
    const float* dec_g = (const float*)d_in[27];
    const float* dec_b = (const float*)d_in[28];
    const float* projW = (const float*)d_in[29];
    const float* projB = (const float*)d_in[30];

    // ---- batch-chunk sizing (deterministic) ----
    const size_t W_BYTES = 50000000;
    const size_t perB = 8000000;
    int Bc = 32;
    while (Bc > 1 && W_BYTES + (size_t)Bc * perB + (4u << 20) > ws_size) Bc >>= 1;

    char* wp = (char*)d_ws;
    auto alloc = [&](size_t bytes) { char* p = wp; wp += (bytes + 255) & ~(size_t)255; return p; };

    _Float16* Wcat8  = (_Float16*)alloc(8 * 524288 * 2);
    _Float16* encW1C = (_Float16*)alloc(2 * 2097152 * 2);
    _Float16* encW2C = (_Float16*)alloc(2 * 2097152 * 2);
    _Float16* dW1C   = (_Float16*)alloc(2097152 * 2);
    _Float16* dW2C   = (_Float16*)alloc(2097152 * 2);
    _Float16* W63C   = (_Float16*)alloc(131072 * 2);
    _Float16* PA     = (_Float16*)alloc(8 * 524288 * 2);
    _Float16* PB     = (_Float16*)alloc(8 * 524288 * 2);

    const long ROWS = (long)Bc * 512;
    _Float16* cX     = (_Float16*)alloc(ROWS * 1024 * 2);
    _Float16* cO     = (_Float16*)alloc(ROWS * 1024 * 2);
    _Float16* TSc    = (_Float16*)alloc(ROWS * 1024 * 2);
    _Float16* ENCcat = (_Float16*)alloc(ROWS * 1024 * 2);
    _Float16* bigcat = (_Float16*)alloc(ROWS * 2048 * 2);
    float* F       = (float*)alloc(ROWS * 512 * 4);
    float* H       = (float*)alloc(ROWS * 128 * 4);
    float* sinit   = (float*)alloc((long)Bc * 10752 * 4);
    float* tinit   = (float*)alloc((long)Bc * 10752 * 4);
    float* xmean   = (float*)alloc((long)Bc * 21 * 4);
    float* mc      = (float*)alloc((long)Bc * 512 * 4);
    float* cp      = (float*)alloc((long)Bc * 4096 * 4);
    float* cs      = (float*)alloc((long)Bc * 512 * 4);

    // ---- weight setup ----
    dim3 cb(256);
    P12 sp;
    sp.p[0] = enc_Wk;  sp.p[1] = enc_Wk + 262144;
    sp.p[2] = sWk;     sp.p[3] = cWk;
    sp.p[4] = enc_Wq;  sp.p[5] = enc_Wq + 262144;
    sp.p[6] = sWq;     sp.p[7] = cWq;
    sp.p[8] = enc_Wv;  sp.p[9] = enc_Wv + 262144;
    sp.p[10] = sWv;    sp.p[11] = cWv;
    P4 op;
    op.p[0] = enc_Wo;  op.p[1] = enc_Wo + 262144;
    op.p[2] = sWo;     op.p[3] = cWo;
    P6 fp;
    fp.p[0] = enc_W1;  fp.p[1] = enc_W1 + 1048576; fp.p[2] = dW1;
    fp.p[3] = enc_W2;  fp.p[4] = enc_W2 + 1048576; fp.p[5] = dW2;
    splitAll_k <<<dim3(128,12), cb, 0, stream>>>(sp, PA, PB);
    convWoAll_k<<<dim3(16,16,4), cb, 0, stream>>>(op, PA);
    hgemm(0, 64, 3, 1.f, PA,1024,512, PB,1024,512, nullptr, Wcat8, 1024, 512,
          512, 512, 512, 8, 524288, 524288, 524288, stream);
    convW2All_k<<<dim3(16,64,6), cb, 0, stream>>>(fp, encW1C, encW2C, dW1C, dW2C);
    convW63_k  <<<256, cb, 0, stream>>>(dtW, W63C);

    const int M = (int)ROWS;
    const int t21 = Bc * 10752;
    const int gRows = Bc * 128;
    const int gW = Bc * 32;
    const int nMc = Bc * 512;
    const long sCA = 512 * 1024;
    const float IOS = 1.f / 4096.f;

    auto attn = [&](const _Float16* cIn, _Float16* cOut,
                    const _Float16* KVcat, int slot) {
        const _Float16* WqkC_ = Wcat8 + (long)(2*slot)     * 524288;
        const _Float16* WvoC_ = Wcat8 + (long)(2*slot + 1) * 524288;
        hgemm(0, 64, 3, 1.f, cIn,1024,512, WqkC_,1024,512, nullptr, bigcat, 1024, 512,
              512, M, 512, 1, 0,0,0, stream);                              // T cat
        hgemm(20, 64, 3, 1.f, bigcat,1024,512, KVcat,1024,512, nullptr, mc, 0, 0,
              512, 512, 512, Bc, sCA, sCA, 512, stream);                   // diag
        hgemmAgg_k<<<dim3(4, M/128), 256, 0, stream>>>(KVcat, mc, WvoC_, cIn, cOut, IOS);
    };
    auto ffn = [&](const _Float16* cIn, _Float16* cOut,
                   const _Float16* W1C, const _Float16* W2C) {
        hgemm(2, 128, 1, 1.f, cIn,1024,512, W1C,1024,512, nullptr, bigcat, 2048, -1,
              512, M, 2048, 1, 0,0,0, stream);
        hgemm(12, 64, 1, 1.f, bigcat,2048,0, W2C,4096,2048, cIn, cOut, 1024, 512,
              2048, M, 512, 1, 0,0,0, stream);
    };

    for (int b0 = 0; b0 < 32; b0 += Bc) {
        const float* xe  = x_enc  + (long)b0 * 10752;
        const float* mke = xm_enc + (long)b0 * 2048;
        const float* mkd = xm_dec + (long)b0 * 2048;
        float* outp = (float*)d_out + (long)b0 * 5376;

        meanseq2_k<<<Bc, 512, 0, stream>>>(xe, xmean, mc);
        prep_k    <<<(t21 + 255)/256, 256, 0, stream>>>(xe, xmean, sinit, tinit, t21);

        // ---------------- encoder ----------------
        embed_k<<<dim3(64,2,Bc), 256, 0, stream>>>(xe, mke, enc_valW, enc_timeW, cX);
        for (int L = 0; L < 2; L++) {
            attn(cX, cO, cX, L);
            decompW_k<0><<<gW, 256, 0, stream>>>(cO, cX, nullptr, mc, nMc);
            ffn(cX, cO, encW1C + (long)L*2097152, encW2C + (long)L*2097152);
            decompW_k<0><<<gW, 256, 0, stream>>>(cO, cX, nullptr, mc, nMc);
        }
        ln_k       <<<Bc*512, 256, 0, stream>>>(cX, enc_g, enc_b, F);
        colpart_k  <<<dim3(2,8,Bc), 256, 0, stream>>>(F, cp);
        colmean_k  <<<dim3(2,Bc), 256, 0, stream>>>(cp, cs);
        subcolcat_k<<<gRows, 256, 0, stream>>>(F, cs, ENCcat);

        // ---------------- decoder ----------------
        embed_k<<<dim3(64,2,Bc), 256, 0, stream>>>(sinit, mkd, dec_valW, dec_timeW, cX);

        attn(cX, cO, cX, 2);                                         // self
        decompW_k<2><<<gW, 256, 0, stream>>>(cO, cX, TSc, mc, nMc);  // TSc = trend
        attn(cX, cO, ENCcat, 3);                                     // cross
        decompW_k<1><<<gW, 256, 0, stream>>>(cO, cX, TSc, mc, nMc);  // TSc += trend
        ffn(cX, cO, dW1C, dW2C);
        decompW_k<1><<<gW, 256, 0, stream>>>(cO, cX, TSc, mc, nMc);

        hgemm(11, 64, 1, 1.f/64.f, TSc,1024,512, W63C,1024,512, nullptr, H, 128, 0,
              512, M, 128, 1, 0,0,0, stream);
        ln_k     <<<Bc*512, 256, 0, stream>>>(cX, dec_g, dec_b, F);
        colpart_k<<<dim3(2,8,Bc), 256, 0, stream>>>(F, cp);
        colmean_k<<<dim3(2,Bc), 256, 0, stream>>>(cp, cs);
        proj_k   <<<(Bc*5376+255)/256, 256, 0, stream>>>(F, cs, projW, projB,
                                                         tinit, H, outp, Bc*5376);
    }
}

// Round 18
// 1797.869 us; speedup vs baseline: 1.3242x; 1.0532x over previous
//
#include <hip/hip_runtime.h>

// ---------------------------------------------------------------------------
// Autoformer forward, MI355X. Round 18: round-17 + precomputed positional-
// encoding table (kills per-element trig in embed). Numerics bit-identical.
// GEMM: C = Ah*Bh [+ Ah*Bl [+ Al*Bh]], operands rows x 2K f16 [hi|lo].
// ---------------------------------------------------------------------------

typedef _Float16 h8 __attribute__((ext_vector_type(8)));
typedef _Float16 h4 __attribute__((ext_vector_type(4)));
typedef float f32x4 __attribute__((ext_vector_type(4)));

struct P12 { const float* p[12]; };
struct P6  { const float* p[6]; };
struct P4  { const float* p[4]; };

__device__ __forceinline__ float gelu_f(float x){
    return 0.5f * x * (1.0f + erff(x * 0.70710678118654752f));
}

__device__ __forceinline__ void gl_lds(const _Float16* gp, _Float16* lp) {
    __builtin_amdgcn_global_load_lds(
        (const __attribute__((address_space(1))) void*)gp,
        (__attribute__((address_space(3))) void*)lp, 16, 0, 0);
}

// bijective chunked XCD swizzle (m204)
__device__ __forceinline__ int xcd_swz(int lin, int nwg) {
    const int q = nwg >> 3, r = nwg & 7;
    const int xcd = lin & 7, idx = lin >> 3;
    return (xcd < r) ? xcd * (q + 1) + idx
                     : r * (q + 1) + (xcd - r) * q + idx;
}

// ------------------------------ MFMA GEMM ----------------------------------
// Tile 128 x BN (BN in {64,128}), BK=64, 256 thr (4 waves 2x2).
// A: M x 2K [hi|lo] (lda halfs, lo at +loA). B: N x 2K (ldb, +loB).
// nph phases x (K/64): (Ah,Bh)[,(Ah,Bl)[,(Al,Bh)]]. f32 accum, *osc epilogue.
// OUT=0: f32 C. OUT=1: f16 cat C (loC<0 -> hi only); EPI 0 plain/1 +Rcat/2 gelu.
// OUT=2: diag reduce: atomicAdd mc[bz*sC + (row-col)&511].
template<int EPI, int OUT, int BN>
__global__ __launch_bounds__(256)
void hgemm_k(const _Float16* __restrict__ A, int lda, int loA,
             const _Float16* __restrict__ Bm, int ldb, int loB,
             const _Float16* __restrict__ Rc, void* __restrict__ Cv,
             int ldc, int loC, int K, int nph, float osc,
             long sA, long sB, long sC)
{
    constexpr int NN = BN / 32;            // n-fragments per wave
    __shared__ _Float16 As[128 * 64];
    __shared__ _Float16 Bs[BN * 64];
    const int gx = gridDim.x, gy = gridDim.y;
    int lin = blockIdx.x + gx * (blockIdx.y + gy * blockIdx.z);
    lin = xcd_swz(lin, gx * gy * gridDim.z);
    const int bxi = lin % gx; lin /= gx;
    const int byi = lin % gy;
    const int bz  = lin / gy;
    const int tid = threadIdx.x, lane = tid & 63, w = tid >> 6;
    const int wr = w >> 1, wc = w & 1;
    const _Float16* Ap = A + bz * sA + (long)(byi * 128) * lda;
    const _Float16* Bp = Bm + bz * sB + (long)(bxi * BN) * ldb;

    const int swz = ((lane & 7) ^ ((lane >> 3) & 7)) * 8;
    const int rsubA = w * 32 + (lane >> 3);
    const int rsubB = w * (BN / 4) + (lane >> 3);
    const _Float16* ApT = Ap + (long)rsubA * lda + swz;
    const _Float16* BpT = Bp + (long)rsubB * ldb + swz;
    _Float16* AsT = As + w * 2048;
    _Float16* BsT = Bs + w * (BN * 16);

    const int tpp = K >> 6;
    const int nkt = tpp * nph;
    f32x4 acc[4][NN] = {};

    int p = 0, q = 0;
    for (int kt = 0; kt < nkt; ++kt) {
        const int aoff = q * 64 + (p == 2 ? loA : 0);
        const int boff = q * 64 + (p == 1 ? loB : 0);
        __syncthreads();
#pragma unroll
        for (int i = 0; i < 4; i++)
            gl_lds(ApT + (long)i * 8 * lda + aoff, AsT + i * 512);
#pragma unroll
        for (int i = 0; i < BN / 32; i++)
            gl_lds(BpT + (long)i * 8 * ldb + boff, BsT + i * 512);
        __syncthreads();
#pragma unroll
        for (int kk = 0; kk < 2; ++kk) {
            h8 af[4], bf[NN];
            const int ks = kk * 4 + (lane >> 4);
#pragma unroll
            for (int m = 0; m < 4; m++) {
                int rowa = wr * 64 + m * 16 + (lane & 15);
                af[m] = *(const h8*)(As + rowa * 64 + ((ks ^ (rowa & 7)) * 8));
            }
#pragma unroll
            for (int n = 0; n < NN; n++) {
                int rowb = wc * (BN / 2) + n * 16 + (lane & 15);
                bf[n] = *(const h8*)(Bs + rowb * 64 + ((ks ^ (rowb & 7)) * 8));
            }
#pragma unroll
            for (int m = 0; m < 4; m++)
#pragma unroll
                for (int n = 0; n < NN; n++)
                    acc[m][n] = __builtin_amdgcn_mfma_f32_16x16x32_f16(af[m], bf[n], acc[m][n], 0, 0, 0);
        }
        if (++q == tpp) { q = 0; ++p; }
    }

    const int crow0 = byi * 128 + wr * 64 + (lane >> 4) * 4;
    const int ccol0 = bxi * BN + wc * (BN / 2) + (lane & 15);
    if constexpr (OUT == 0) {
        float* Cp = (float*)Cv + (long)bz * sC;
#pragma unroll
        for (int m = 0; m < 4; m++)
#pragma unroll
            for (int n = 0; n < NN; n++) {
                int col = ccol0 + n * 16;
#pragma unroll
                for (int r2 = 0; r2 < 4; r2++) {
                    long idx = (long)(crow0 + m * 16 + r2) * ldc + col;
                    Cp[idx] = acc[m][n][r2] * osc;
                }
            }
    } else if constexpr (OUT == 1) {
        _Float16* Cp = (_Float16*)Cv + (long)bz * sC;
#pragma unroll
        for (int m = 0; m < 4; m++)
#pragma unroll
            for (int n = 0; n < NN; n++) {
                int col = ccol0 + n * 16;
#pragma unroll
                for (int r2 = 0; r2 < 4; r2++) {
                    int row = crow0 + m * 16 + r2;
                    long base = (long)row * ldc + col;
                    float v = acc[m][n][r2] * osc;
                    if (EPI == 1) {
                        long rb = (long)row * 1024 + col;
                        v += (float)Rc[rb] + (float)Rc[rb + 512];
                    }
                    if (EPI == 2) v = gelu_f(v);
                    _Float16 hi = (_Float16)v;
                    Cp[base] = hi;
                    if (loC >= 0) Cp[base + loC] = (_Float16)(v - (float)hi);
                }
            }
    } else {
        __shared__ float diag[512];
        float* mc = (float*)Cv + (long)bz * sC;
        for (int t = tid; t < 512; t += 256) diag[t] = 0.f;
        __syncthreads();
#pragma unroll
        for (int m = 0; m < 4; m++)
#pragma unroll
            for (int n = 0; n < NN; n++) {
                int col = ccol0 + n * 16;
#pragma unroll
                for (int r2 = 0; r2 < 4; r2++) {
                    int row = crow0 + m * 16 + r2;
                    atomicAdd(&diag[(row - col) & 511], acc[m][n][r2]);
                }
            }
        __syncthreads();
        for (int t = tid; t < 512; t += 256) {
            float v = diag[t];
            if (v != 0.f) atomicAdd(&mc[t], v);
        }
    }
}

// --------------- Wvo GEMM with fused top-k + agg gather --------------------
__global__ __launch_bounds__(256)
void hgemmAgg_k(const _Float16* __restrict__ KV, const float* __restrict__ mc,
                const _Float16* __restrict__ Bm,
                const _Float16* __restrict__ Rc, _Float16* __restrict__ Cp,
                float osc)
{
    __shared__ _Float16 As[128 * 64];
    __shared__ _Float16 Bs[128 * 64];
    const int gx = gridDim.x;
    int lin = blockIdx.x + gx * blockIdx.y;
    lin = xcd_swz(lin, gx * gridDim.y);
    const int bxi = lin % gx;
    const int byi = lin / gx;
    const int tid = threadIdx.x, lane = tid & 63, w = tid >> 6;
    const int wr = w >> 1, wc = w & 1;
    const int rowblk = byi * 128;
    const int b = rowblk >> 9;

    int dl[6]; float wv[6];
    {
        float* v  = (float*)As;
        float* rv = (float*)As + 512;
        int*   ri = (int*)Bs;
        const float SCL = 1.f / (512.f * 4096.f);
        v[tid]       = mc[b * 512 + tid]       * SCL;
        v[tid + 256] = mc[b * 512 + tid + 256] * SCL;
        __syncthreads();
        float sv[6];
        for (int p = 0; p < 6; p++) {
            float bv = v[tid]; int bi = tid;
            float v2 = v[tid + 256];
            if (v2 > bv) { bv = v2; bi = tid + 256; }
            rv[tid] = bv; ri[tid] = bi;
            __syncthreads();
            for (int s = 128; s > 0; s >>= 1) {
                if (tid < s) {
                    float ov = rv[tid + s]; int oi = ri[tid + s];
                    if (ov > rv[tid] || (ov == rv[tid] && oi < ri[tid])) {
                        rv[tid] = ov; ri[tid] = oi;
                    }
                }
                __syncthreads();
            }
            sv[p] = rv[0]; dl[p] = ri[0];
            __syncthreads();
            if (tid == 0) v[ri[0]] = -3.4e38f;
            __syncthreads();
        }
        float mx = sv[0];
        for (int p = 1; p < 6; p++) mx = fmaxf(mx, sv[p]);
        float e[6], sum = 0.f;
        for (int p = 0; p < 6; p++) { e[p] = expf(sv[p] - mx); sum += e[p]; }
        for (int p = 0; p < 6; p++) wv[p] = e[p] / sum;
    }

    const _Float16* Bp = Bm + (long)(bxi * 128) * 1024;
    const int swz = ((lane & 7) ^ ((lane >> 3) & 7)) * 8;
    const int rsub = w * 32 + (lane >> 3);
    const _Float16* BpT = Bp + (long)rsub * 1024 + swz;
    _Float16* BsT = Bs + w * 2048;
    const _Float16* KVb = KV + ((long)b << 19);

    f32x4 acc[4][4] = {};
    for (int q = 0; q < 8; ++q) {
        const int coff = q * 64 + swz;
        __syncthreads();
#pragma unroll
        for (int i = 0; i < 4; i++) {
            int l = (rowblk + rsub + i * 8) & 511;
            float s8[8] = {};
#pragma unroll
            for (int k = 0; k < 6; k++) {
                const h8 v = *(const h8*)(KVb + ((long)((l + dl[k]) & 511) << 10) + coff);
#pragma unroll
                for (int j = 0; j < 8; j++) s8[j] = fmaf(wv[k], (float)v[j], s8[j]);
            }
            h8 hv;
#pragma unroll
            for (int j = 0; j < 8; j++) hv[j] = (_Float16)s8[j];
            *(h8*)(As + w * 2048 + i * 512 + lane * 8) = hv;
            gl_lds(BpT + (long)i * 8 * 1024 + q * 64, BsT + i * 512);
        }
        __syncthreads();
#pragma unroll
        for (int kk = 0; kk < 2; ++kk) {
            h8 af[4], bf[4];
            const int ks = kk * 4 + (lane >> 4);
#pragma unroll
            for (int m = 0; m < 4; m++) {
                int rowa = wr * 64 + m * 16 + (lane & 15);
                af[m] = *(const h8*)(As + rowa * 64 + ((ks ^ (rowa & 7)) * 8));
                int rowb = wc * 64 + m * 16 + (lane & 15);
                bf[m] = *(const h8*)(Bs + rowb * 64 + ((ks ^ (rowb & 7)) * 8));
            }
#pragma unroll
            for (int m = 0; m < 4; m++)
#pragma unroll
                for (int n = 0; n < 4; n++)
                    acc[m][n] = __builtin_amdgcn_mfma_f32_16x16x32_f16(af[m], bf[n], acc[m][n], 0, 0, 0);
        }
    }

    const int crow0 = rowblk + wr * 64 + (lane >> 4) * 4;
    const int ccol0 = bxi * 128 + wc * 64 + (lane & 15);
#pragma unroll
    for (int m = 0; m < 4; m++)
#pragma unroll
        for (int n = 0; n < 4; n++) {
            int col = ccol0 + n * 16;
#pragma unroll
            for (int r2 = 0; r2 < 4; r2++) {
                int row = crow0 + m * 16 + r2;
                long rb = (long)row * 1024 + col;
                float v = acc[m][n][r2] * osc + (float)Rc[rb] + (float)Rc[rb + 512];
                _Float16 hi = (_Float16)v;
                Cp[rb] = hi;
                Cp[rb + 512] = (_Float16)(v - (float)hi);
            }
        }
}

// ------------------------- weight conversion -------------------------------
__global__ __launch_bounds__(256)
void splitAll_k(P12 ps, _Float16* __restrict__ PA, _Float16* __restrict__ PB)
{
    const int m = blockIdx.y;
    const float* __restrict__ src = ps.p[m];
    _Float16* dst;
    if (m < 4)      dst = PA + (long)(2 * m) * 524288;
    else if (m < 8) dst = PB + (long)(2 * (m - 4)) * 524288;
    else            dst = PB + (long)(2 * (m - 8) + 1) * 524288;
    long t = (long)blockIdx.x * 256 + threadIdx.x;
    long row = t >> 6; int kc = (int)(t & 63) * 8;
    const float4 v0 = *(const float4*)(src + row * 512 + kc);
    const float4 v1 = *(const float4*)(src + row * 512 + kc + 4);
    float vv[8] = {v0.x,v0.y,v0.z,v0.w,v1.x,v1.y,v1.z,v1.w};
    h8 hi, lo;
#pragma unroll
    for (int j = 0; j < 8; j++) {
        float s = vv[j] * 64.f;
        _Float16 h = (_Float16)s;
        hi[j] = h; lo[j] = (_Float16)(s - (float)h);
    }
    *(h8*)(dst + row * 1024 + kc)       = hi;
    *(h8*)(dst + row * 1024 + 512 + kc) = lo;
}

__global__ __launch_bounds__(256)
void convWoAll_k(P4 ps, _Float16* __restrict__ PA)
{
    const int z = blockIdx.z;
    const float* __restrict__ src = ps.p[z];
    _Float16* dst = PA + (long)(2 * z + 1) * 524288;
    __shared__ float t[32][33];
    int k0 = blockIdx.x * 32, n0 = blockIdx.y * 32, tid = threadIdx.x;
#pragma unroll
    for (int i = 0; i < 4; i++) {
        int lin = tid + i * 256; int r = lin >> 5, c = lin & 31;
        t[r][c] = src[(long)(k0 + r) * 512 + n0 + c];
    }
    __syncthreads();
#pragma unroll
    for (int i = 0; i < 4; i++) {
        int lin = tid + i * 256; int n = lin >> 5, k = lin & 31;
        float v = t[k][n] * 64.f;
        _Float16 hi = (_Float16)v;
        long base = (long)(n0 + n) * 1024 + k0 + k;
        dst[base]       = hi;
        dst[base + 512] = (_Float16)(v - (float)hi);
    }
}

__global__ __launch_bounds__(256)
void convW2All_k(P6 ps, _Float16* __restrict__ encW1C, _Float16* __restrict__ encW2C,
                 _Float16* __restrict__ dW1C, _Float16* __restrict__ dW2C)
{
    const int z = blockIdx.z;
    const float* __restrict__ src = ps.p[z];
    _Float16* dst = (z==0) ? encW1C : (z==1) ? encW1C + 2097152 : (z==2) ? dW1C :
                    (z==3) ? encW2C : (z==4) ? encW2C + 2097152 : dW2C;
    const bool isW1 = z < 3;
    const int N = isW1 ? 2048 : 512;
    const int K = isW1 ? 512 : 2048;
    int k0 = (isW1 ? blockIdx.x : blockIdx.y) * 32;
    int n0 = (isW1 ? blockIdx.y : blockIdx.x) * 32;
    __shared__ float t[32][33];
    int tid = threadIdx.x;
#pragma unroll
    for (int i = 0; i < 4; i++) {
        int lin = tid + i * 256; int r = lin >> 5, c = lin & 31;
        t[r][c] = src[(long)(k0 + r) * N + n0 + c];
    }
    __syncthreads();
#pragma unroll
    for (int i = 0; i < 4; i++) {
        int lin = tid + i * 256; int n = lin >> 5, k = lin & 31;
        float v = t[k][n];
        _Float16 hi = (_Float16)v;
        long base = (long)(n0 + n) * 2 * K + k0 + k;
        dst[base]     = hi;
        dst[base + K] = (_Float16)(v - (float)hi);
    }
}

__global__ void convW63_k(const float* __restrict__ W, _Float16* __restrict__ dst)
{
    int i = blockIdx.x * 256 + threadIdx.x;
    int k = i & 511, j = i >> 9;
    float v = (j < 63) ? 64.f * W[(long)(j / 21) * 10752 + (long)k * 21 + (j % 21)] : 0.f;
    _Float16 hi = (_Float16)v;
    dst[(long)j * 1024 + k]       = hi;
    dst[(long)j * 1024 + 512 + k] = (_Float16)(v - (float)hi);
}

// positional-encoding table: PE[l][d], identical trig to original embed.
__global__ void pe_k(float* __restrict__ PE)
{
    int l = blockIdx.x, tid = threadIdx.x;
#pragma unroll
    for (int h = 0; h < 2; h++) {
        int dd = h * 256 + tid;
        const float freq = expf((float)(dd & ~1) * (-9.210340371976184f / 512.0f));
        float ang = (float)l * freq;
        PE[(long)l * 512 + dd] = (dd & 1) ? cosf(ang) : sinf(ang);
    }
}

// ------------------------- embedding (cat-only out, table PE) --------------
__global__ __launch_bounds__(256)
void embed_k(const float* __restrict__ x, const float* __restrict__ mark,
             const float* __restrict__ valW, const float* __restrict__ timeW,
             const float* __restrict__ PE, _Float16* __restrict__ cat)
{
    const int lg = blockIdx.x, dh = blockIdx.y, b = blockIdx.z;
    const int tid = threadIdx.x;
    const int dd = dh * 256 + tid;
    const int l0 = lg * 8;
    __shared__ float xs[10][21];
    __shared__ float mk[8][4];
    if (tid < 210) {
        int r = tid / 21, c = tid % 21;
        int ll = (l0 - 1 + r + 512) & 511;
        xs[r][c] = x[((long)b * 512 + ll) * 21 + c];
    }
    if (tid >= 224 && tid < 256) {
        int t2 = tid - 224, il = t2 >> 2, m = t2 & 3;
        mk[il][m] = mark[((long)b * 512 + l0 + il) * 4 + m];
    }
    __syncthreads();
    float acc[8];
#pragma unroll
    for (int il = 0; il < 8; il++) acc[il] = 0.f;
    for (int t = 0; t < 3; t++)
        for (int c = 0; c < 21; c++) {
            float w = valW[(t * 21 + c) * 512 + dd];
#pragma unroll
            for (int il = 0; il < 8; il++)
                acc[il] = fmaf(xs[il + t][c], w, acc[il]);
        }
    for (int m = 0; m < 4; m++) {
        float w = timeW[m * 512 + dd];
#pragma unroll
        for (int il = 0; il < 8; il++)
            acc[il] = fmaf(mk[il][m], w, acc[il]);
    }
#pragma unroll
    for (int il = 0; il < 8; il++) {
        float pe = PE[(long)(l0 + il) * 512 + dd];
        float v = acc[il] + pe;
        long row = (long)b * 512 + l0 + il;
        _Float16 hi = (_Float16)v;
        cat[row * 1024 + dd]       = hi;
        cat[row * 1024 + 512 + dd] = (_Float16)(v - (float)hi);
    }
}

// ------------------- windowed decomp (cat in/out) + mc-clean ---------------
template<int TREND>
__global__ __launch_bounds__(256)
void decompW_k(const _Float16* __restrict__ xc, _Float16* __restrict__ outc,
               _Float16* __restrict__ tsc, float* __restrict__ mcz, int nMc)
{
    long t = (long)blockIdx.x * 256 + threadIdx.x;
    if (t < nMc) mcz[t] = 0.f;
    long rowg = t >> 7; int d4 = (int)(t & 127) * 4;
    int lg = (int)(rowg & 63); long b = rowg >> 6;
    const int l0 = lg * 8;
    const _Float16* xb = xc + (b << 19);
    float s[8][4] = {};
    float xo[8][4];
#pragma unroll
    for (int rr = -12; rr <= 19; rr++) {
        int rc = l0 + rr; rc = rc < 0 ? 0 : (rc > 511 ? 511 : rc);
        h4 vh = *(const h4*)(xb + ((long)rc << 10) + d4);
        h4 vl = *(const h4*)(xb + ((long)rc << 10) + 512 + d4);
        float vv[4];
#pragma unroll
        for (int j = 0; j < 4; j++) vv[j] = (float)vh[j] + (float)vl[j];
#pragma unroll
        for (int i = 0; i < 8; i++) {
            if (i >= rr - 12 && i <= rr + 12) {
#pragma unroll
                for (int j = 0; j < 4; j++) s[i][j] += vv[j];
            }
        }
        if (rr >= 0 && rr < 8) {
#pragma unroll
            for (int j = 0; j < 4; j++) xo[rr][j] = vv[j];
        }
    }
#pragma unroll
    for (int i = 0; i < 8; i++) {
        long row = b * 512 + l0 + i;
        float tr[4], ov[4];
#pragma unroll
        for (int j = 0; j < 4; j++) {
            tr[j] = s[i][j] * (1.f / 25.f);
            ov[j] = xo[i][j] - tr[j];
        }
        h4 hi, lo;
#pragma unroll
        for (int j = 0; j < 4; j++) {
            _Float16 h = (_Float16)ov[j];
            hi[j] = h; lo[j] = (_Float16)(ov[j] - (float)h);
        }
        *(h4*)(outc + row * 1024 + d4)       = hi;
        *(h4*)(outc + row * 1024 + 512 + d4) = lo;
        if (TREND) {
            _Float16* tp = tsc + row * 1024 + d4;
            if (TREND == 1) {
                h4 th = *(h4*)tp, tl = *(h4*)(tp + 512);
#pragma unroll
                for (int j = 0; j < 4; j++) tr[j] += (float)th[j] + (float)tl[j];
            }
            h4 th2, tl2;
#pragma unroll
            for (int j = 0; j < 4; j++) {
                _Float16 h = (_Float16)tr[j];
                th2[j] = h; tl2[j] = (_Float16)(tr[j] - (float)h);
            }
            *(h4*)tp         = th2;
            *(h4*)(tp + 512) = tl2;
        }
    }
}

// ------------------------- prep (mean + zero mc) ---------------------------
__global__ __launch_bounds__(512)
void meanseq2_k(const float* __restrict__ x, float* __restrict__ xm,
                float* __restrict__ mcz)
{
    int b = blockIdx.x, tid = threadIdx.x;
    mcz[b * 512 + tid] = 0.f;
    __shared__ float sd[504];
    if (tid < 504) {
        int c = tid % 21, g = tid / 21;
        int l0 = g * 22, l1 = l0 + 22 > 512 ? 512 : l0 + 22;
        const float* xb = x + (long)b * 10752;
        float s = 0.f;
        for (int l = l0; l < l1; l++) s += xb[l * 21 + c];
        sd[tid] = s;
    }
    __syncthreads();
    if (tid < 21) {
        float t = 0.f;
#pragma unroll
        for (int g = 0; g < 24; g++) t += sd[g * 21 + tid];
        xm[b * 21 + tid] = t * (1.f / 512.f);
    }
}

__global__ void prep_k(const float* __restrict__ x, const float* __restrict__ xm,
                       float* __restrict__ sinit, float* __restrict__ tinit, int total)
{
    int i = blockIdx.x * 256 + threadIdx.x;
    if (i >= total) return;
    int c = i % 21, l = (i / 21) % 512, b = i / 10752;
    if (l < 256) {
        int lc = 256 + l;
        float s = 0.f;
        for (int j = -12; j <= 12; j++) {
            int ll = lc + j; ll = ll > 511 ? 511 : ll;
            s += x[((long)b * 512 + ll) * 21 + c];
        }
        float t = s * (1.f / 25.f);
        tinit[i] = t;
        sinit[i] = x[((long)b * 512 + lc) * 21 + c] - t;
    } else {
        sinit[i] = 0.f;
        tinit[i] = xm[b * 21 + c];
    }
}

// ------------------------- seasonal layernorm (cat in, f32 out) ------------
__global__ __launch_bounds__(256)
void ln_k(const _Float16* __restrict__ xc, const float* __restrict__ g,
          const float* __restrict__ be, float* __restrict__ out)
{
    int row = blockIdx.x, tid = threadIdx.x;
    const _Float16* xr = xc + ((long)row << 10);
    float v0 = (float)xr[tid]       + (float)xr[tid + 512];
    float v1 = (float)xr[tid + 256] + (float)xr[tid + 768];
    __shared__ float rs[256];
    rs[tid] = v0 + v1; __syncthreads();
    for (int s = 128; s > 0; s >>= 1) { if (tid < s) rs[tid] += rs[tid + s]; __syncthreads(); }
    float mu = rs[0] * (1.f / 512.f);
    __syncthreads();
    float d0 = v0 - mu, d1 = v1 - mu;
    rs[tid] = d0 * d0 + d1 * d1; __syncthreads();
    for (int s = 128; s > 0; s >>= 1) { if (tid < s) rs[tid] += rs[tid + s]; __syncthreads(); }
    float rstd = 1.0f / sqrtf(rs[0] * (1.f / 512.f) + 1e-5f);
    out[((long)row << 9) + tid]       = d0 * rstd * g[tid] + be[tid];
    out[((long)row << 9) + tid + 256] = d1 * rstd * g[tid + 256] + be[tid + 256];
}

// per-(b, 64-row chunk, d) partial column sums. grid (2, 8, Bc)
__global__ void colpart_k(const float* __restrict__ x, float* __restrict__ cp)
{
    int d = blockIdx.x * 256 + threadIdx.x;
    int ch = blockIdx.y, b = blockIdx.z;
    const float* xb = x + ((long)b << 18);
    float s = 0.f;
    for (int l = ch * 64; l < ch * 64 + 64; l++) s += xb[((long)l << 9) + d];
    cp[((long)(b * 8 + ch) << 9) + d] = s;
}

// cs[b][d] = mean over l (from 8 partials). grid (2, Bc)
__global__ void colmean_k(const float* __restrict__ cp, float* __restrict__ cs)
{
    int d = blockIdx.x * 256 + threadIdx.x;
    int b = blockIdx.y;
    float s = 0.f;
#pragma unroll
    for (int ch = 0; ch < 8; ch++) s += cp[((long)(b * 8 + ch) << 9) + d];
    cs[((long)b << 9) + d] = s * (1.f / 512.f);
}

// write hi/lo cat of (x - cs) — encoder tail
__global__ __launch_bounds__(256)
void subcolcat_k(const float* __restrict__ x, const float* __restrict__ cs,
                 _Float16* __restrict__ cat)
{
    long t = (long)blockIdx.x * 256 + threadIdx.x;
    long row = t >> 6; int d8 = (int)(t & 63) * 8;
    int b = (int)(row >> 9);
    const float4* c4 = (const float4*)(cs + ((long)b << 9) + d8);
    float4 m0 = c4[0], m1 = c4[1];
    float m[8] = {m0.x,m0.y,m0.z,m0.w,m1.x,m1.y,m1.z,m1.w};
    const float4* xp = (const float4*)(x + row * 512 + d8);
    float4 x0 = xp[0], x1 = xp[1];
    float v[8] = {x0.x,x0.y,x0.z,x0.w,x1.x,x1.y,x1.z,x1.w};
    h8 hi, lo;
#pragma unroll
    for (int j = 0; j < 8; j++) {
        float vv = v[j] - m[j];
        _Float16 h = (_Float16)vv;
        hi[j] = h; lo[j] = (_Float16)(vv - (float)h);
    }
    *(h8*)(cat + row * 1024 + d8)       = hi;
    *(h8*)(cat + row * 1024 + 512 + d8) = lo;
}

// proj with cs subtract + trend shift-add (decoder tail)
__global__ void proj_k(const float* __restrict__ x, const float* __restrict__ cs,
                       const float* __restrict__ pw, const float* __restrict__ pb,
                       const float* __restrict__ tinit, const float* __restrict__ H,
                       float* __restrict__ out, int total)
{
    int i = blockIdx.x * 256 + threadIdx.x;
    if (i >= total) return;
    int c = i % 21, l = (i / 21) % 256 + 256, b = i / 5376;
    const float* xr = x + ((long)(b * 512 + l) << 9);
    const float* csb = cs + ((long)b << 9);
    float s = 0.f;
    for (int d = 0; d < 512; d++)
        s = fmaf(xr[d] - csb[d], pw[d * 21 + c], s);
    long r = (long)b * 512;
    float trend = tinit[b * 10752 + l * 21 + c]
                + H[(r + ((l + 511) & 511)) * 128 + c]
                + H[(r + l) * 128 + 21 + c]
                + H[(r + ((l + 1) & 511)) * 128 + 42 + c];
    out[i] = s + pb[c] + trend;
}

// ---------------------------------------------------------------------------
// mode: 0 OUT1 plain-cat, 2 OUT1 gelu, 12 OUT1 +Rcat, 11 OUT0 f32, 20 Scorr
static void hgemm(int mode, int bn, int nph, float osc,
                  const _Float16* A, int lda, int loA,
                  const _Float16* B, int ldb, int loB,
                  const _Float16* Rc, void* C, int ldc, int loC,
                  int K, int M, int N, int batch,
                  long sA, long sB, long sC, hipStream_t st)
{
    dim3 g(N / bn, M / 128, batch), blk(256);
    if (bn == 64) {
        switch (mode) {
        case 0:  hgemm_k<0,1,64><<<g,blk,0,st>>>(A,lda,loA,B,ldb,loB,Rc,C,ldc,loC,K,nph,osc,sA,sB,sC); break;
        case 2:  hgemm_k<2,1,64><<<g,blk,0,st>>>(A,lda,loA,B,ldb,loB,Rc,C,ldc,loC,K,nph,osc,sA,sB,sC); break;
        case 12: hgemm_k<1,1,64><<<g,blk,0,st>>>(A,lda,loA,B,ldb,loB,Rc,C,ldc,loC,K,nph,osc,sA,sB,sC); break;
        case 11: hgemm_k<0,0,64><<<g,blk,0,st>>>(A,lda,loA,B,ldb,loB,Rc,C,ldc,loC,K,nph,osc,sA,sB,sC); break;
        default: hgemm_k<0,2,64><<<g,blk,0,st>>>(A,lda,loA,B,ldb,loB,Rc,C,ldc,loC,K,nph,osc,sA,sB,sC); break;
        }
    } else {
        switch (mode) {
        case 0:  hgemm_k<0,1,128><<<g,blk,0,st>>>(A,lda,loA,B,ldb,loB,Rc,C,ldc,loC,K,nph,osc,sA,sB,sC); break;
        case 2:  hgemm_k<2,1,128><<<g,blk,0,st>>>(A,lda,loA,B,ldb,loB,Rc,C,ldc,loC,K,nph,osc,sA,sB,sC); break;
        case 12: hgemm_k<1,1,128><<<g,blk,0,st>>>(A,lda,loA,B,ldb,loB,Rc,C,ldc,loC,K,nph,osc,sA,sB,sC); break;
        case 11: hgemm_k<0,0,128><<<g,blk,0,st>>>(A,lda,loA,B,ldb,loB,Rc,C,ldc,loC,K,nph,osc,sA,sB,sC); break;
        default: hgemm_k<0,2,128><<<g,blk,0,st>>>(A,lda,loA,B,ldb,loB,Rc,C,ldc,loC,K,nph,osc,sA,sB,sC); break;
        }
    }
}

extern "C" void kernel_launch(void* const* d_in, const int* in_sizes, int n_in,
                              void* d_out, int out_size, void* d_ws, size_t ws_size,
                              hipStream_t stream)
{
    const float* x_enc    = (const float*)d_in[0];
    const float* xm_enc   = (const float*)d_in[1];
    const float* xm_dec   = (const float*)d_in[3];
    const float* enc_valW = (const float*)d_in[4];
    const float* enc_timeW= (const float*)d_in[5];
    const float* enc_Wq   = (const float*)d_in[6];
    const float* enc_Wk   = (const float*)d_in[7];
    const float* enc_Wv   = (const float*)d_in[8];
    const float* enc_Wo   = (const float*)d_in[9];
    const float* enc_W1   = (const float*)d_in[10];
    const float* enc_W2   = (const float*)d_in[11];
    const float* enc_g    = (const float*)d_in[12];
    const float* enc_b    = (const float*)d_in[13];
    const float* dec_valW = (const float*)d_in[14];
    const float* dec_timeW= (const float*)d_in[15];
    const float* sWq = (const float*)d_in[16];
    const float* sWk = (const float*)d_in[17];
    const float* sWv = (const float*)d_in[18];
    const float* sWo = (const float*)d_in[19];
    const float* cWq = (const float*)d_in[20];
    const float* cWk = (const float*)d_in[21];
    const float* cWv = (const float*)d_in[22];
    const float* cWo = (const float*)d_in[23];
    const float* dW1 = (const float*)d_in[24];
    const float* dW2 = (const float*)d_in[25];
    const float* dtW = (const float*)d_in[26];
    const float* dec_g = (const float*)d_in[27];
    const float* dec_b = (const float*)d_in[28];
    const float* projW = (const float*)d_in[29];
    const float* projB = (const float*)d_in[30];

    // ---- batch-chunk sizing (deterministic) ----
    const size_t W_BYTES = 52000000;
    const size_t perB = 8000000;
    int Bc = 32;
    while (Bc > 1 && W_BYTES + (size_t)Bc * perB + (4u << 20) > ws_size) Bc >>= 1;

    char* wp = (char*)d_ws;
    auto alloc = [&](size_t bytes) { char* p = wp; wp += (bytes + 255) & ~(size_t)255; return p; };

    _Float16* Wcat8  = (_Float16*)alloc(8 * 524288 * 2);
    _Float16* encW1C = (_Float16*)alloc(2 * 2097152 * 2);
    _Float16* encW2C = (_Float16*)alloc(2 * 2097152 * 2);
    _Float16* dW1C   = (_Float16*)alloc(2097152 * 2);
    _Float16* dW2C   = (_Float16*)alloc(2097152 * 2);
    _Float16* W63C   = (_Float16*)alloc(131072 * 2);
    float*    PE     = (float*)alloc(512 * 512 * 4);
    _Float16* PA     = (_Float16*)alloc(8 * 524288 * 2);
    _Float16* PB     = (_Float16*)alloc(8 * 524288 * 2);

    const long ROWS = (long)Bc * 512;
    _Float16* cX     = (_Float16*)alloc(ROWS * 1024 * 2);
    _Float16* cO     = (_Float16*)alloc(ROWS * 1024 * 2);
    _Float16* TSc    = (_Float16*)alloc(ROWS * 1024 * 2);
    _Float16* ENCcat = (_Float16*)alloc(ROWS * 1024 * 2);
    _Float16* bigcat = (_Float16*)alloc(ROWS * 2048 * 2);
    float* F       = (float*)alloc(ROWS * 512 * 4);
    float* H       = (float*)alloc(ROWS * 128 * 4);
    float* sinit   = (float*)alloc((long)Bc * 10752 * 4);
    float* tinit   = (float*)alloc((long)Bc * 10752 * 4);
    float* xmean   = (float*)alloc((long)Bc * 21 * 4);
    float* mc      = (float*)alloc((long)Bc * 512 * 4);
    float* cp      = (float*)alloc((long)Bc * 4096 * 4);
    float* cs      = (float*)alloc((long)Bc * 512 * 4);

    // ---- weight setup ----
    dim3 cb(256);
    P12 sp;
    sp.p[0] = enc_Wk;  sp.p[1] = enc_Wk + 262144;
    sp.p[2] = sWk;     sp.p[3] = cWk;
    sp.p[4] = enc_Wq;  sp.p[5] = enc_Wq + 262144;
    sp.p[6] = sWq;     sp.p[7] = cWq;
    sp.p[8] = enc_Wv;  sp.p[9] = enc_Wv + 262144;
    sp.p[10] = sWv;    sp.p[11] = cWv;
    P4 op;
    op.p[0] = enc_Wo;  op.p[1] = enc_Wo + 262144;
    op.p[2] = sWo;     op.p[3] = cWo;
    P6 fp;
    fp.p[0] = enc_W1;  fp.p[1] = enc_W1 + 1048576; fp.p[2] = dW1;
    fp.p[3] = enc_W2;  fp.p[4] = enc_W2 + 1048576; fp.p[5] = dW2;
    splitAll_k <<<dim3(128,12), cb, 0, stream>>>(sp, PA, PB);
    convWoAll_k<<<dim3(16,16,4), cb, 0, stream>>>(op, PA);
    hgemm(0, 64, 3, 1.f, PA,1024,512, PB,1024,512, nullptr, Wcat8, 1024, 512,
          512, 512, 512, 8, 524288, 524288, 524288, stream);
    convW2All_k<<<dim3(16,64,6), cb, 0, stream>>>(fp, encW1C, encW2C, dW1C, dW2C);
    convW63_k  <<<256, cb, 0, stream>>>(dtW, W63C);
    pe_k       <<<512, cb, 0, stream>>>(PE);

    const int M = (int)ROWS;
    const int t21 = Bc * 10752;
    const int gRows = Bc * 128;
    const int gW = Bc * 32;
    const int nMc = Bc * 512;
    const long sCA = 512 * 1024;
    const float IOS = 1.f / 4096.f;

    auto attn = [&](const _Float16* cIn, _Float16* cOut,
                    const _Float16* KVcat, int slot) {
        const _Float16* WqkC_ = Wcat8 + (long)(2*slot)     * 524288;
        const _Float16* WvoC_ = Wcat8 + (long)(2*slot + 1) * 524288;
        hgemm(0, 64, 3, 1.f, cIn,1024,512, WqkC_,1024,512, nullptr, bigcat, 1024, 512,
              512, M, 512, 1, 0,0,0, stream);                              // T cat
        hgemm(20, 64, 3, 1.f, bigcat,1024,512, KVcat,1024,512, nullptr, mc, 0, 0,
              512, 512, 512, Bc, sCA, sCA, 512, stream);                   // diag
        hgemmAgg_k<<<dim3(4, M/128), 256, 0, stream>>>(KVcat, mc, WvoC_, cIn, cOut, IOS);
    };
    auto ffn = [&](const _Float16* cIn, _Float16* cOut,
                   const _Float16* W1C, const _Float16* W2C) {
        hgemm(2, 128, 1, 1.f, cIn,1024,512, W1C,1024,512, nullptr, bigcat, 2048, -1,
              512, M, 2048, 1, 0,0,0, stream);
        hgemm(12, 64, 1, 1.f, bigcat,2048,0, W2C,4096,2048, cIn, cOut, 1024, 512,
              2048, M, 512, 1, 0,0,0, stream);
    };

    for (int b0 = 0; b0 < 32; b0 += Bc) {
        const float* xe  = x_enc  + (long)b0 * 10752;
        const float* mke = xm_enc + (long)b0 * 2048;
        const float* mkd = xm_dec + (long)b0 * 2048;
        float* outp = (float*)d_out + (long)b0 * 5376;

        meanseq2_k<<<Bc, 512, 0, stream>>>(xe, xmean, mc);
        prep_k    <<<(t21 + 255)/256, 256, 0, stream>>>(xe, xmean, sinit, tinit, t21);

        // ---------------- encoder ----------------
        embed_k<<<dim3(64,2,Bc), 256, 0, stream>>>(xe, mke, enc_valW, enc_timeW, PE, cX);
        for (int L = 0; L < 2; L++) {
            attn(cX, cO, cX, L);
            decompW_k<0><<<gW, 256, 0, stream>>>(cO, cX, nullptr, mc, nMc);
            ffn(cX, cO, encW1C + (long)L*2097152, encW2C + (long)L*2097152);
            decompW_k<0><<<gW, 256, 0, stream>>>(cO, cX, nullptr, mc, nMc);
        }
        ln_k       <<<Bc*512, 256, 0, stream>>>(cX, enc_g, enc_b, F);
        colpart_k  <<<dim3(2,8,Bc), 256, 0, stream>>>(F, cp);
        colmean_k  <<<dim3(2,Bc), 256, 0, stream>>>(cp, cs);
        subcolcat_k<<<gRows, 256, 0, stream>>>(F, cs, ENCcat);

        // ---------------- decoder ----------------
        embed_k<<<dim3(64,2,Bc), 256, 0, stream>>>(sinit, mkd, dec_valW, dec_timeW, PE, cX);

        attn(cX, cO, cX, 2);                                         // self
        decompW_k<2><<<gW, 256, 0, stream>>>(cO, cX, TSc, mc, nMc);  // TSc = trend
        attn(cX, cO, ENCcat, 3);                                     // cross
        decompW_k<1><<<gW, 256, 0, stream>>>(cO, cX, TSc, mc, nMc);  // TSc += trend
        ffn(cX, cO, dW1C, dW2C);
        decompW_k<1><<<gW, 256, 0, stream>>>(cO, cX, TSc, mc, nMc);

        hgemm(11, 64, 1, 1.f/64.f, TSc,1024,512, W63C,1024,512, nullptr, H, 128, 0,
              512, M, 128, 1, 0,0,0, stream);
        ln_k     <<<Bc*512, 256, 0, stream>>>(cX, dec_g, dec_b, F);
        colpart_k<<<dim3(2,8,Bc), 256, 0, stream>>>(F, cp);
        colmean_k<<<dim3(2,Bc), 256, 0, stream>>>(cp, cs);
        proj_k   <<<(Bc*5376+255)/256, 256, 0, stream>>>(F, cs, projW, projB,
                                                         tinit, H, outp, Bc*5376);
    }
}